// Round 2
// baseline (4952.304 us; speedup 1.0000x reference)
//
#include <hip/hip_runtime.h>
#include <hip/hip_bf16.h>

// ============================================================================
// EstVAEStudent forward, round 2: fp32 compute, bf16 storage for big tensors.
// Root-cause fix vs round 1: workspace shrunk 307MB -> ~140MiB (the silent
// ws_size bail was skipping all work). No early return anymore.
// ============================================================================

#define BATCH 4096
typedef unsigned short u16;

__device__ __forceinline__ float silu_f(float v) { return v / (1.f + __expf(-v)); }

__device__ __forceinline__ float b2f(u16 u) {
  union { unsigned int i; float f; } c; c.i = ((unsigned int)u) << 16; return c.f;
}
__device__ __forceinline__ u16 f2b(float f) {
  union { float f; unsigned int i; } c; c.f = f;
  unsigned int r = c.i + 0x7FFFu + ((c.i >> 16) & 1u);
  return (u16)(r >> 16);
}
__device__ __forceinline__ float4 ld4(const float* p) { return *(const float4*)p; }
__device__ __forceinline__ float4 ld4(const u16* p) {
  ushort4 v = *(const ushort4*)p;
  return make_float4(b2f(v.x), b2f(v.y), b2f(v.z), b2f(v.w));
}
__device__ __forceinline__ float ld1(const float* p) { return *p; }
__device__ __forceinline__ float ld1(const u16* p) { return b2f(*p); }
__device__ __forceinline__ void st4b(u16* p, float a, float b, float c, float d) {
  *(ushort4*)p = make_ushort4(f2b(a), f2b(b), f2b(c), f2b(d));
}

// ---------------- workspace layout (units: float elements) ----------------
// REGION A [0, 14,680,064): y1(bf16) then y3(bf16) then {t_moe(bf16), s_t(bf16), h2(f32)}
static constexpr size_t A_OFF     = 0;
static constexpr size_t TMOE_FE   = 8388608;    // 16,777,216 bf16
static constexpr size_t ST_FE     = 4194304;    // 8,388,608 bf16
static constexpr size_t H2_OFF    = A_OFF + TMOE_FE + ST_FE;        // f32 2,097,152
static constexpr size_t A_SIZE    = 14680064;   // = y3 as bf16 (29,360,128 el / 2)
// REGION B [A_SIZE, A_SIZE+17,301,504): y2(bf16) then {h,hist1,e1,e2,e3} then {o1,o2}
static constexpr size_t B_OFF     = A_SIZE;
static constexpr size_t H_OFF     = B_OFF;
static constexpr size_t HIST1_OFF = B_OFF + 4194304;
static constexpr size_t E1_OFF    = B_OFF + 8388608;
static constexpr size_t E2_OFF    = B_OFF + 12582912;
static constexpr size_t E3_OFF    = B_OFF + 16777216;
static constexpr size_t O1_OFF    = B_OFF;                // reuse h (dead)
static constexpr size_t O2_OFF    = B_OFF + 4194304;      // reuse hist1 (dead)
static constexpr size_t B_SIZE    = 17301504;
// REGION C: persistent small buffers
static constexpr size_t C_OFF     = B_OFF + B_SIZE;       // 31,981,568
static constexpr size_t HLAT_OFF  = C_OFF;
static constexpr size_t Z_OFF     = C_OFF + 262144;
static constexpr size_t X_OFF     = C_OFF + 524288;
static constexpr size_t LOG_OFF   = C_OFF + 2621440;
static constexpr size_t TID_OFF   = C_OFF + 2686976;
static constexpr size_t TW_OFF    = C_OFF + 2703360;
static constexpr size_t POS_OFF   = C_OFF + 2719744;
static constexpr size_t CNT_OFF   = C_OFF + 2736128;
static constexpr size_t OFS_OFF   = C_OFF + 2736160;
static constexpr size_t ROWL_OFF  = C_OFF + 2736192;
static constexpr size_t WL_OFF    = C_OFF + 2752576;
static constexpr size_t WT1_OFF   = C_OFF + 2768960;      // 73,728
static constexpr size_t WT2_OFF   = C_OFF + 2842688;      // 393,216
static constexpr size_t WT3_OFF   = C_OFF + 3235904;      // 1,572,864
static constexpr size_t WS_END    = C_OFF + 4808768;      // 36,790,336 fe ~ 140.4 MiB

// ---------------- utility kernels ----------------
__global__ void k_zero_i(int* __restrict__ p, int n) {
  int i = blockIdx.x * 64 + threadIdx.x;
  if (i < n) p[i] = 0;
}

// conv weight transpose: [O][I][3] -> [(k*CIN+i)][O]
__global__ __launch_bounds__(256) void k_transpose_w(const float* __restrict__ w,
                                                     float* __restrict__ wt,
                                                     int CIN, int COUT) {
  int idx = blockIdx.x * 256 + threadIdx.x;
  int total = COUT * CIN * 3;
  if (idx >= total) return;
  int o = idx % COUT;
  int c = idx / COUT;        // c = k*CIN + i
  int i = c % CIN;
  int k = c / CIN;
  wt[idx] = w[(size_t)o * CIN * 3 + i * 3 + k];
}

// ---------------- plain GEMM: C[M,N] = act(A[M,K] @ W[K,N] + bias), C fp32 ----------------
// M multiple of 64, K multiple of 16. NG guards N. TA in {float, u16}.
template<int ACT, bool NG, typename TA>
__global__ __launch_bounds__(256) void k_gemm(const TA* __restrict__ A,
                                              const float* __restrict__ W,
                                              const float* __restrict__ bias,
                                              float* __restrict__ C,
                                              int N, int K) {
  __shared__ float As[16][64];
  __shared__ float Bs[16][64];
  const int tid = threadIdx.x;
  const int m0 = blockIdx.x * 64;
  const int n0 = blockIdx.y * 64;
  const int tr = tid >> 4, tc = tid & 15;
  const int lm = tid >> 2, lk = (tid & 3) * 4;
  const int ln = tid & 63, lkb = (tid >> 6) * 4;
  float acc[4][4] = {};
  for (int k0 = 0; k0 < K; k0 += 16) {
    float4 av = ld4(A + (size_t)(m0 + lm) * K + k0 + lk);
    As[lk + 0][lm] = av.x; As[lk + 1][lm] = av.y;
    As[lk + 2][lm] = av.z; As[lk + 3][lm] = av.w;
#pragma unroll
    for (int s = 0; s < 4; ++s) {
      int kk = lkb + s;
      float v = 0.f;
      if (!NG || (n0 + ln) < N) v = W[(size_t)(k0 + kk) * N + n0 + ln];
      Bs[kk][ln] = v;
    }
    __syncthreads();
#pragma unroll
    for (int kk = 0; kk < 16; ++kk) {
      float4 a4 = *(const float4*)&As[kk][tr * 4];
      float4 b4 = *(const float4*)&Bs[kk][tc * 4];
      float a[4] = {a4.x, a4.y, a4.z, a4.w};
      float b[4] = {b4.x, b4.y, b4.z, b4.w};
#pragma unroll
      for (int i = 0; i < 4; ++i)
#pragma unroll
        for (int j = 0; j < 4; ++j) acc[i][j] = fmaf(a[i], b[j], acc[i][j]);
    }
    __syncthreads();
  }
#pragma unroll
  for (int i = 0; i < 4; ++i) {
    int m = m0 + tr * 4 + i;
#pragma unroll
    for (int j = 0; j < 4; ++j) {
      int n = n0 + tc * 4 + j;
      if (NG && n >= N) continue;
      float v = acc[i][j] + bias[n];
      if (ACT == 1) v = silu_f(v);
      C[(size_t)m * N + n] = v;
    }
  }
}

// ---------------- dual GEMM: C = silu(A@Wg+bg) * (A@Wu+bu), C bf16 ----------------
__global__ __launch_bounds__(256) void k_gemm_dual(const float* __restrict__ A,
                                                   const float* __restrict__ Wg,
                                                   const float* __restrict__ Wu,
                                                   const float* __restrict__ bg,
                                                   const float* __restrict__ bu,
                                                   u16* __restrict__ C,
                                                   int N, int K) {
  __shared__ float As[16][64];
  __shared__ float Bg[16][64];
  __shared__ float Bu[16][64];
  const int tid = threadIdx.x;
  const int m0 = blockIdx.x * 64;
  const int n0 = blockIdx.y * 64;
  const int tr = tid >> 4, tc = tid & 15;
  const int lm = tid >> 2, lk = (tid & 3) * 4;
  const int ln = tid & 63, lkb = (tid >> 6) * 4;
  float ag[4][4] = {};
  float au[4][4] = {};
  for (int k0 = 0; k0 < K; k0 += 16) {
    float4 av = ld4(A + (size_t)(m0 + lm) * K + k0 + lk);
    As[lk + 0][lm] = av.x; As[lk + 1][lm] = av.y;
    As[lk + 2][lm] = av.z; As[lk + 3][lm] = av.w;
#pragma unroll
    for (int s = 0; s < 4; ++s) {
      int kk = lkb + s;
      Bg[kk][ln] = Wg[(size_t)(k0 + kk) * N + n0 + ln];
      Bu[kk][ln] = Wu[(size_t)(k0 + kk) * N + n0 + ln];
    }
    __syncthreads();
#pragma unroll
    for (int kk = 0; kk < 16; ++kk) {
      float4 a4 = *(const float4*)&As[kk][tr * 4];
      float4 g4 = *(const float4*)&Bg[kk][tc * 4];
      float4 u4 = *(const float4*)&Bu[kk][tc * 4];
      float a[4] = {a4.x, a4.y, a4.z, a4.w};
      float g[4] = {g4.x, g4.y, g4.z, g4.w};
      float u[4] = {u4.x, u4.y, u4.z, u4.w};
#pragma unroll
      for (int i = 0; i < 4; ++i)
#pragma unroll
        for (int j = 0; j < 4; ++j) {
          ag[i][j] = fmaf(a[i], g[j], ag[i][j]);
          au[i][j] = fmaf(a[i], u[j], au[i][j]);
        }
    }
    __syncthreads();
  }
#pragma unroll
  for (int i = 0; i < 4; ++i) {
    int m = m0 + tr * 4 + i;
    float r[4];
#pragma unroll
    for (int j = 0; j < 4; ++j) {
      int n = n0 + tc * 4 + j;
      r[j] = silu_f(ag[i][j] + bg[n]) * (au[i][j] + bu[n]);
    }
    st4b(C + (size_t)m * N + n0 + tc * 4, r[0], r[1], r[2], r[3]);
  }
}

// ---------------- conv as implicit-im2col GEMM, output bf16 ----------------
// X: [B, TIN, CIN]; Wt: [(k*CIN+i)][COUT]; C: [B, TOUT, COUT] = silu(conv+bias)
template<int CIN, int TIN, int TOUT, int STRIDE, typename TX>
__global__ __launch_bounds__(256) void k_conv_gemm(const TX* __restrict__ X,
                                                   const float* __restrict__ Wt,
                                                   const float* __restrict__ bias,
                                                   u16* __restrict__ C,
                                                   int COUT) {
  __shared__ float As[16][64];
  __shared__ float Bs[16][64];
  const int tid = threadIdx.x;
  const int m0 = blockIdx.x * 64;
  const int n0 = blockIdx.y * 64;
  const int tr = tid >> 4, tc = tid & 15;
  const int lm = tid >> 2, lk = (tid & 3) * 4;
  const int ln = tid & 63, lkb = (tid >> 6) * 4;
  const int m = m0 + lm;
  const int b = m / TOUT;
  const int t = m - b * TOUT;
  const int tbase = t * STRIDE - 1;
  const int K = CIN * 3;
  float acc[4][4] = {};
  for (int k0 = 0; k0 < K; k0 += 16) {
#pragma unroll
    for (int j = 0; j < 4; ++j) {
      int c = k0 + lk + j;
      int k = c / CIN;
      int i = c - k * CIN;
      int tp = tbase + k;
      float v = 0.f;
      if (tp >= 0 && tp < TIN) v = ld1(X + ((size_t)b * TIN + tp) * CIN + i);
      As[lk + j][lm] = v;
    }
#pragma unroll
    for (int s = 0; s < 4; ++s) {
      int kk = lkb + s;
      Bs[kk][ln] = Wt[(size_t)(k0 + kk) * COUT + n0 + ln];
    }
    __syncthreads();
#pragma unroll
    for (int kk = 0; kk < 16; ++kk) {
      float4 a4 = *(const float4*)&As[kk][tr * 4];
      float4 b4 = *(const float4*)&Bs[kk][tc * 4];
      float a[4] = {a4.x, a4.y, a4.z, a4.w};
      float bb[4] = {b4.x, b4.y, b4.z, b4.w};
#pragma unroll
      for (int i = 0; i < 4; ++i)
#pragma unroll
        for (int j = 0; j < 4; ++j) acc[i][j] = fmaf(a[i], bb[j], acc[i][j]);
    }
    __syncthreads();
  }
#pragma unroll
  for (int i = 0; i < 4; ++i) {
    int mo = m0 + tr * 4 + i;
    float r[4];
#pragma unroll
    for (int j = 0; j < 4; ++j) {
      int n = n0 + tc * 4 + j;
      r[j] = silu_f(acc[i][j] + bias[n]);
    }
    st4b(C + (size_t)mo * COUT + n0 + tc * 4, r[0], r[1], r[2], r[3]);
  }
}

// ---------------- concat projection GEMM: A = [cur_obs | hist_lat | z] ----------------
__global__ __launch_bounds__(256) void k_gemm_proj(const float* __restrict__ obs,
                                                   const float* __restrict__ hl,
                                                   const float* __restrict__ z,
                                                   const float* __restrict__ W,
                                                   const float* __restrict__ bias,
                                                   float* __restrict__ C) {
  const int N = 512, K = 384;
  __shared__ float As[16][64];
  __shared__ float Bs[16][64];
  const int tid = threadIdx.x;
  const int m0 = blockIdx.x * 64;
  const int n0 = blockIdx.y * 64;
  const int tr = tid >> 4, tc = tid & 15;
  const int lm = tid >> 2, lk = (tid & 3) * 4;
  const int ln = tid & 63, lkb = (tid >> 6) * 4;
  const int m = m0 + lm;
  float acc[4][4] = {};
  for (int k0 = 0; k0 < K; k0 += 16) {
#pragma unroll
    for (int j = 0; j < 4; ++j) {
      int c = k0 + lk + j;
      float v;
      if (c < 256)       v = obs[(size_t)m * 256 + c];
      else if (c < 320)  v = hl[(size_t)m * 64 + (c - 256)];
      else               v = z[(size_t)m * 64 + (c - 320)];
      As[lk + j][lm] = v;
    }
#pragma unroll
    for (int s = 0; s < 4; ++s) {
      int kk = lkb + s;
      Bs[kk][ln] = W[(size_t)(k0 + kk) * N + n0 + ln];
    }
    __syncthreads();
#pragma unroll
    for (int kk = 0; kk < 16; ++kk) {
      float4 a4 = *(const float4*)&As[kk][tr * 4];
      float4 b4 = *(const float4*)&Bs[kk][tc * 4];
      float a[4] = {a4.x, a4.y, a4.z, a4.w};
      float b[4] = {b4.x, b4.y, b4.z, b4.w};
#pragma unroll
      for (int i = 0; i < 4; ++i)
#pragma unroll
        for (int j = 0; j < 4; ++j) acc[i][j] = fmaf(a[i], b[j], acc[i][j]);
    }
    __syncthreads();
  }
#pragma unroll
  for (int i = 0; i < 4; ++i) {
    int mo = m0 + tr * 4 + i;
#pragma unroll
    for (int j = 0; j < 4; ++j) {
      int n = n0 + tc * 4 + j;
      C[(size_t)mo * N + n] = acc[i][j] + bias[n];
    }
  }
}

// ---------------- MoE up: gathered dual GEMM -> t_moe(bf16) = silu(g)*u ----------------
__global__ __launch_bounds__(256) void k_moe_up(const float* __restrict__ x,
                                                const float* __restrict__ Wg,
                                                const float* __restrict__ Wu,
                                                const float* __restrict__ bg,
                                                const float* __restrict__ bu,
                                                const int* __restrict__ rowlist,
                                                const int* __restrict__ counts,
                                                const int* __restrict__ offs,
                                                u16* __restrict__ t_moe) {
  const int e = blockIdx.z;
  const int ne = counts[e];
  const int m0 = blockIdx.x * 64;
  if (m0 >= ne) return;
  const int base = offs[e];
  const int N = 1024, K = 512;
  const float* Wge = Wg + (size_t)e * K * N;
  const float* Wue = Wu + (size_t)e * K * N;
  const float* bge = bg + (size_t)e * N;
  const float* bue = bu + (size_t)e * N;
  __shared__ int rs[64];
  __shared__ float As[16][64];
  __shared__ float Bg[16][64];
  __shared__ float Bu[16][64];
  const int tid = threadIdx.x;
  if (tid < 64) rs[tid] = (m0 + tid < ne) ? rowlist[base + m0 + tid] : -1;
  __syncthreads();
  const int n0 = blockIdx.y * 64;
  const int tr = tid >> 4, tc = tid & 15;
  const int lm = tid >> 2, lk = (tid & 3) * 4;
  const int ln = tid & 63, lkb = (tid >> 6) * 4;
  float ag[4][4] = {};
  float au[4][4] = {};
  for (int k0 = 0; k0 < K; k0 += 16) {
    int r = rs[lm];
    float4 av = make_float4(0.f, 0.f, 0.f, 0.f);
    if (r >= 0) av = ld4(x + (size_t)r * K + k0 + lk);
    As[lk + 0][lm] = av.x; As[lk + 1][lm] = av.y;
    As[lk + 2][lm] = av.z; As[lk + 3][lm] = av.w;
#pragma unroll
    for (int s = 0; s < 4; ++s) {
      int kk = lkb + s;
      Bg[kk][ln] = Wge[(size_t)(k0 + kk) * N + n0 + ln];
      Bu[kk][ln] = Wue[(size_t)(k0 + kk) * N + n0 + ln];
    }
    __syncthreads();
#pragma unroll
    for (int kk = 0; kk < 16; ++kk) {
      float4 a4 = *(const float4*)&As[kk][tr * 4];
      float4 g4 = *(const float4*)&Bg[kk][tc * 4];
      float4 u4 = *(const float4*)&Bu[kk][tc * 4];
      float a[4] = {a4.x, a4.y, a4.z, a4.w};
      float g[4] = {g4.x, g4.y, g4.z, g4.w};
      float u[4] = {u4.x, u4.y, u4.z, u4.w};
#pragma unroll
      for (int i = 0; i < 4; ++i)
#pragma unroll
        for (int j = 0; j < 4; ++j) {
          ag[i][j] = fmaf(a[i], g[j], ag[i][j]);
          au[i][j] = fmaf(a[i], u[j], au[i][j]);
        }
    }
    __syncthreads();
  }
#pragma unroll
  for (int i = 0; i < 4; ++i) {
    int mi = m0 + tr * 4 + i;
    if (mi >= ne) continue;
    float r[4];
#pragma unroll
    for (int j = 0; j < 4; ++j) {
      int n = n0 + tc * 4 + j;
      r[j] = silu_f(ag[i][j] + bge[n]) * (au[i][j] + bue[n]);
    }
    st4b(t_moe + (size_t)(base + mi) * N + n0 + tc * 4, r[0], r[1], r[2], r[3]);
  }
}

// ---------------- MoE down: t_moe(bf16) @ Wd_e, weighted scatter-add into h2 ----------------
__global__ __launch_bounds__(256) void k_moe_down(const u16* __restrict__ t_moe,
                                                  const float* __restrict__ Wd,
                                                  const float* __restrict__ bd,
                                                  const int* __restrict__ rowlist,
                                                  const float* __restrict__ wlist,
                                                  const int* __restrict__ counts,
                                                  const int* __restrict__ offs,
                                                  float* __restrict__ h2) {
  const int e = blockIdx.z;
  const int ne = counts[e];
  const int m0 = blockIdx.x * 64;
  if (m0 >= ne) return;
  const int base = offs[e];
  const int N = 512, K = 1024;
  const float* Wde = Wd + (size_t)e * K * N;
  const float* bde = bd + (size_t)e * N;
  __shared__ float As[16][64];
  __shared__ float Bs[16][64];
  const int tid = threadIdx.x;
  const int n0 = blockIdx.y * 64;
  const int tr = tid >> 4, tc = tid & 15;
  const int lm = tid >> 2, lk = (tid & 3) * 4;
  const int ln = tid & 63, lkb = (tid >> 6) * 4;
  float acc[4][4] = {};
  for (int k0 = 0; k0 < K; k0 += 16) {
    float4 av = make_float4(0.f, 0.f, 0.f, 0.f);
    if (m0 + lm < ne)
      av = ld4(t_moe + (size_t)(base + m0 + lm) * K + k0 + lk);
    As[lk + 0][lm] = av.x; As[lk + 1][lm] = av.y;
    As[lk + 2][lm] = av.z; As[lk + 3][lm] = av.w;
#pragma unroll
    for (int s = 0; s < 4; ++s) {
      int kk = lkb + s;
      Bs[kk][ln] = Wde[(size_t)(k0 + kk) * N + n0 + ln];
    }
    __syncthreads();
#pragma unroll
    for (int kk = 0; kk < 16; ++kk) {
      float4 a4 = *(const float4*)&As[kk][tr * 4];
      float4 b4 = *(const float4*)&Bs[kk][tc * 4];
      float a[4] = {a4.x, a4.y, a4.z, a4.w};
      float b[4] = {b4.x, b4.y, b4.z, b4.w};
#pragma unroll
      for (int i = 0; i < 4; ++i)
#pragma unroll
        for (int j = 0; j < 4; ++j) acc[i][j] = fmaf(a[i], b[j], acc[i][j]);
    }
    __syncthreads();
  }
#pragma unroll
  for (int i = 0; i < 4; ++i) {
    int mi = m0 + tr * 4 + i;
    if (mi >= ne) continue;
    int row = rowlist[base + mi];
    float wl = wlist[base + mi];
#pragma unroll
    for (int j = 0; j < 4; ++j) {
      int n = n0 + tc * 4 + j;
      atomicAdd(&h2[(size_t)row * N + n], wl * (acc[i][j] + bde[n]));
    }
  }
}

// ---------------- small elementwise / router kernels ----------------
__global__ void k_mean7(const u16* __restrict__ y3, float* __restrict__ h) {
  int idx = blockIdx.x * 256 + threadIdx.x;
  if (idx >= BATCH * 1024) return;
  int b = idx >> 10, o = idx & 1023;
  const u16* p = y3 + (size_t)b * 7 * 1024 + o;
  float s = 0.f;
#pragma unroll
  for (int t = 0; t < 7; ++t) s += b2f(p[(size_t)t * 1024]);
  h[idx] = s * (1.f / 7.f);
}

__global__ void k_z(const float* __restrict__ e3, const float* __restrict__ noise,
                    float* __restrict__ z) {
  int idx = blockIdx.x * 256 + threadIdx.x;
  if (idx >= BATCH * 64) return;
  int b = idx >> 6, j = idx & 63;
  float mu = e3[(size_t)b * 128 + j];
  float lv = e3[(size_t)b * 128 + 64 + j];
  z[idx] = mu + expf(0.5f * lv) * noise[idx];
}

__global__ void k_router(const float* __restrict__ logits, int* __restrict__ tidA,
                         float* __restrict__ twA, int* __restrict__ posA,
                         int* __restrict__ counts) {
  int b = blockIdx.x * 256 + threadIdx.x;
  if (b >= BATCH) return;
  float s[16];
#pragma unroll
  for (int e = 0; e < 16; ++e)
    s[e] = 1.f / (1.f + expf(-logits[(size_t)b * 16 + e]));
  float gsc[4];
#pragma unroll
  for (int g = 0; g < 4; ++g) {
    float m1 = -1e30f; int i1 = -1;
    for (int i = 0; i < 4; ++i) { float v = s[g * 4 + i]; if (v > m1) { m1 = v; i1 = i; } }
    float m2 = -1e30f;
    for (int i = 0; i < 4; ++i) { if (i == i1) continue; float v = s[g * 4 + i]; if (v > m2) m2 = v; }
    gsc[g] = m1 + m2;
  }
  int g1 = 0; float b1 = gsc[0];
  for (int g = 1; g < 4; ++g) if (gsc[g] > b1) { b1 = gsc[g]; g1 = g; }
  int g2 = -1; float b2 = -1e30f;
  for (int g = 0; g < 4; ++g) { if (g == g1) continue; if (gsc[g] > b2) { b2 = gsc[g]; g2 = g; } }
  float ms[16]; bool used[16];
#pragma unroll
  for (int e = 0; e < 16; ++e) {
    int g = e >> 2;
    ms[e] = (g == g1 || g == g2) ? s[e] : 0.f;
    used[e] = false;
  }
  int te[4]; float tv[4]; float tsum = 0.f;
  for (int t = 0; t < 4; ++t) {
    float best = -1.f; int bi = 0;
    for (int e = 0; e < 16; ++e)
      if (!used[e] && ms[e] > best) { best = ms[e]; bi = e; }
    used[bi] = true;
    te[t] = bi;
    tv[t] = s[bi];
    tsum += s[bi];
  }
  float inv = 1.f / (tsum + 1e-20f);
  for (int t = 0; t < 4; ++t) {
    int e = te[t];
    tidA[b * 4 + t] = e;
    twA[b * 4 + t] = tv[t] * inv;  // ROUTE_SCALE = 1.0
    posA[b * 4 + t] = atomicAdd(&counts[e], 1);
  }
}

__global__ void k_offsets(const int* __restrict__ counts, int* __restrict__ offs) {
  if (threadIdx.x == 0 && blockIdx.x == 0) {
    int a = 0;
    for (int e = 0; e < 16; ++e) { offs[e] = a; a += counts[e]; }
    offs[16] = a;
  }
}

__global__ void k_build(const int* __restrict__ tidA, const float* __restrict__ twA,
                        const int* __restrict__ posA, const int* __restrict__ offs,
                        int* __restrict__ rowlist, float* __restrict__ wlist) {
  int idx = blockIdx.x * 256 + threadIdx.x;
  if (idx >= BATCH * 4) return;
  int e = tidA[idx];
  int p = offs[e] + posA[idx];
  rowlist[p] = idx >> 2;
  wlist[p] = twA[idx];
}

// ============================================================================
extern "C" void kernel_launch(void* const* d_in, const int* in_sizes, int n_in,
                              void* d_out, int out_size, void* d_ws, size_t ws_size,
                              hipStream_t stream) {
  const float* cur_obs  = (const float*)d_in[0];
  const float* hist_seq = (const float*)d_in[1];
  const float* fut_ref  = (const float*)d_in[2];
  const float* noise    = (const float*)d_in[3];
  const float* conv1_w  = (const float*)d_in[4];
  const float* conv1_b  = (const float*)d_in[5];
  const float* conv2_w  = (const float*)d_in[6];
  const float* conv2_b  = (const float*)d_in[7];
  const float* conv3_w  = (const float*)d_in[8];
  const float* conv3_b  = (const float*)d_in[9];
  const float* hlin1_w  = (const float*)d_in[10];
  const float* hlin1_b  = (const float*)d_in[11];
  const float* hlin2_w  = (const float*)d_in[12];
  const float* hlin2_b  = (const float*)d_in[13];
  const float* enc1_w   = (const float*)d_in[14];
  const float* enc1_b   = (const float*)d_in[15];
  const float* enc2_w   = (const float*)d_in[16];
  const float* enc2_b   = (const float*)d_in[17];
  const float* enc3_w   = (const float*)d_in[18];
  const float* enc3_b   = (const float*)d_in[19];
  const float* proj_w   = (const float*)d_in[20];
  const float* proj_b   = (const float*)d_in[21];
  const float* router_w = (const float*)d_in[22];
  const float* router_b = (const float*)d_in[23];
  const float* Wg       = (const float*)d_in[24];
  const float* bg       = (const float*)d_in[25];
  const float* Wu       = (const float*)d_in[26];
  const float* bu       = (const float*)d_in[27];
  const float* Wd       = (const float*)d_in[28];
  const float* bd       = (const float*)d_in[29];
  const float* shg_w    = (const float*)d_in[30];
  const float* shg_b    = (const float*)d_in[31];
  const float* shu_w    = (const float*)d_in[32];
  const float* shu_b    = (const float*)d_in[33];
  const float* shd_w    = (const float*)d_in[34];
  const float* shd_b    = (const float*)d_in[35];
  const float* out1_w   = (const float*)d_in[36];
  const float* out1_b   = (const float*)d_in[37];
  const float* out2_w   = (const float*)d_in[38];
  const float* out2_b   = (const float*)d_in[39];
  const float* head_w   = (const float*)d_in[40];
  const float* head_b   = (const float*)d_in[41];
  (void)in_sizes; (void)n_in; (void)out_size; (void)ws_size;

  float* ws    = (float*)d_ws;
  u16*   y1b   = (u16*)(ws + A_OFF);          // 4096*25*256 bf16
  u16*   y3b   = (u16*)(ws + A_OFF);          // 4096*7*1024 bf16 (y1 dead by then)
  u16*   y2b   = (u16*)(ws + B_OFF);          // 4096*13*512 bf16
  u16*   tmoeb = (u16*)(ws + A_OFF);          // 16384*1024 bf16 (y3 dead by then)
  u16*   stb   = (u16*)(ws + A_OFF + TMOE_FE);// 4096*2048 bf16
  float* h2    = ws + H2_OFF;
  float* h     = ws + H_OFF;
  float* hist1 = ws + HIST1_OFF;
  float* e1    = ws + E1_OFF;
  float* e2    = ws + E2_OFF;
  float* e3    = ws + E3_OFF;
  float* o1    = ws + O1_OFF;
  float* o2    = ws + O2_OFF;
  float* hlat  = ws + HLAT_OFF;
  float* z     = ws + Z_OFF;
  float* x     = ws + X_OFF;
  float* logitsb = ws + LOG_OFF;
  int*   tidA  = (int*)(ws + TID_OFF);
  float* twA   = ws + TW_OFF;
  int*   posA  = (int*)(ws + POS_OFF);
  int*   counts = (int*)(ws + CNT_OFF);
  int*   offs  = (int*)(ws + OFS_OFF);
  int*   rowlist = (int*)(ws + ROWL_OFF);
  float* wlist = ws + WL_OFF;
  float* wt1   = ws + WT1_OFF;
  float* wt2   = ws + WT2_OFF;
  float* wt3   = ws + WT3_OFF;

  k_zero_i<<<dim3(1), 64, 0, stream>>>(counts, 16);

  // conv weight transposes: [O][I][3] -> [k*CIN+i][O]
  k_transpose_w<<<dim3(288), 256, 0, stream>>>(conv1_w, wt1, 96, 256);
  k_transpose_w<<<dim3(1536), 256, 0, stream>>>(conv2_w, wt2, 256, 512);
  k_transpose_w<<<dim3(6144), 256, 0, stream>>>(conv3_w, wt3, 512, 1024);

  // history conv encoder (bf16 activations, fp32 math)
  k_conv_gemm<96, 25, 25, 1, float><<<dim3(1600, 4), 256, 0, stream>>>(hist_seq, wt1, conv1_b, y1b, 256);
  k_conv_gemm<256, 25, 13, 2, u16><<<dim3(832, 8), 256, 0, stream>>>(y1b, wt2, conv2_b, y2b, 512);
  k_conv_gemm<512, 13, 7, 2, u16><<<dim3(448, 16), 256, 0, stream>>>(y2b, wt3, conv3_b, y3b, 1024);
  k_mean7<<<dim3(16384), 256, 0, stream>>>(y3b, h);
  k_gemm<1, false, float><<<dim3(64, 16), 256, 0, stream>>>(h, hlin1_w, hlin1_b, hist1, 1024, 1024);
  k_gemm<0, false, float><<<dim3(64, 1), 256, 0, stream>>>(hist1, hlin2_w, hlin2_b, hlat, 64, 1024);

  // fut-ref VAE encoder + reparameterize
  k_gemm<1, false, float><<<dim3(64, 16), 256, 0, stream>>>(fut_ref, enc1_w, enc1_b, e1, 1024, 2560);
  k_gemm<1, false, float><<<dim3(64, 16), 256, 0, stream>>>(e1, enc2_w, enc2_b, e2, 1024, 1024);
  k_gemm<0, false, float><<<dim3(64, 2), 256, 0, stream>>>(e2, enc3_w, enc3_b, e3, 128, 1024);
  k_z<<<dim3(1024), 256, 0, stream>>>(e3, noise, z);

  // projection
  k_gemm_proj<<<dim3(64, 8), 256, 0, stream>>>(cur_obs, hlat, z, proj_w, proj_b, x);

  // router
  k_gemm<0, true, float><<<dim3(64, 1), 256, 0, stream>>>(x, router_w, router_b, logitsb, 16, 512);
  k_router<<<dim3(16), 256, 0, stream>>>(logitsb, tidA, twA, posA, counts);
  k_offsets<<<dim3(1), 64, 0, stream>>>(counts, offs);
  k_build<<<dim3(64), 256, 0, stream>>>(tidA, twA, posA, offs, rowlist, wlist);

  // shared experts -> h2 (MoE scatter adds on top)
  k_gemm_dual<<<dim3(64, 32), 256, 0, stream>>>(x, shg_w, shu_w, shg_b, shu_b, stb, 2048, 512);
  k_gemm<0, false, u16><<<dim3(64, 8), 256, 0, stream>>>(stb, shd_w, shd_b, h2, 512, 2048);

  // sparse MoE (top-4 of 16)
  k_moe_up<<<dim3(64, 16, 16), 256, 0, stream>>>(x, Wg, Wu, bg, bu, rowlist, counts, offs, tmoeb);
  k_moe_down<<<dim3(64, 8, 16), 256, 0, stream>>>(tmoeb, Wd, bd, rowlist, wlist, counts, offs, h2);

  // output MLP + head
  k_gemm<1, false, float><<<dim3(64, 16), 256, 0, stream>>>(h2, out1_w, out1_b, o1, 1024, 512);
  k_gemm<0, false, float><<<dim3(64, 16), 256, 0, stream>>>(o1, out2_w, out2_b, o2, 1024, 1024);
  k_gemm<0, true, float><<<dim3(64, 1), 256, 0, stream>>>(o2, head_w, head_b, (float*)d_out, 23, 1024);
}

// Round 3
// 2357.237 us; speedup vs baseline: 2.1009x; 2.1009x over previous
//
#include <hip/hip_runtime.h>
#include <hip/hip_bf16.h>

// ============================================================================
// EstVAEStudent forward, round 3: bf16 MFMA for conv path + dense GEMMs.
// fp32 kept for: proj, router, small-N tails (hlin2/enc3/head), MoE experts.
// Workspace: 134.45 MiB, regions reused across phases.
// ============================================================================

#define BATCH 4096
typedef unsigned short u16;
using bf16x8 = __attribute__((ext_vector_type(8))) __bf16;
using f32x4  = __attribute__((ext_vector_type(4))) float;

__device__ __forceinline__ float silu_f(float v) { return v / (1.f + __expf(-v)); }

__device__ __forceinline__ float b2f(u16 u) {
  union { unsigned int i; float f; } c; c.i = ((unsigned int)u) << 16; return c.f;
}
__device__ __forceinline__ u16 f2b(float f) {
  union { float f; unsigned int i; } c; c.f = f;
  unsigned int r = c.i + 0x7FFFu + ((c.i >> 16) & 1u);
  return (u16)(r >> 16);
}
__device__ __forceinline__ float4 ld4(const float* p) { return *(const float4*)p; }
__device__ __forceinline__ float4 ld4(const u16* p) {
  ushort4 v = *(const ushort4*)p;
  return make_float4(b2f(v.x), b2f(v.y), b2f(v.z), b2f(v.w));
}
// load 8 elements as a 16-byte bf16 packet
__device__ __forceinline__ uint4 load8b(const u16* p) { return *(const uint4*)p; }
__device__ __forceinline__ uint4 load8b(const float* p) {
  float4 a = *(const float4*)p, b = *(const float4*)(p + 4);
  union { u16 h[8]; uint4 u; } r;
  r.h[0] = f2b(a.x); r.h[1] = f2b(a.y); r.h[2] = f2b(a.z); r.h[3] = f2b(a.w);
  r.h[4] = f2b(b.x); r.h[5] = f2b(b.y); r.h[6] = f2b(b.z); r.h[7] = f2b(b.w);
  return r.u;
}

// ---------------- workspace layout (BYTE offsets) ----------------
static constexpr size_t WT1T_B = 0;                 // 256x288 bf16
static constexpr size_t WT2T_B = 147456;            // 512x768 bf16
static constexpr size_t WT3T_B = 933888;            // 1024x1536 bf16
static constexpr size_t HL1T_B = 4079616;           // 1024x1024 bf16
static constexpr size_t E1T_B  = 6176768;           // 1024x2560 bf16
static constexpr size_t E2T_B  = 11419648;          // 1024x1024 bf16
static constexpr size_t SHGT_B = 13516800;          // 2048x512 bf16
static constexpr size_t SHUT_B = 15613952;          // 2048x512 bf16
static constexpr size_t SHDT_B = 17711104;          // 512x2048 bf16
static constexpr size_t O1T_B  = 19808256;          // 1024x512 bf16
static constexpr size_t O2T_B  = 20856832;          // 1024x1024 bf16
static constexpr size_t RA_B   = 22953984;          // 58,720,256 B region
static constexpr size_t RB_B   = RA_B + 58720256;   // 54,525,952 B region
static constexpr size_t P_B    = RB_B + 54525952;
// inside RA (lifetimes disjoint):
static constexpr size_t Y1_B  = RA_B;               // 4096*25*256 bf16
static constexpr size_t Y3_B  = RA_B;               // 4096*7*1024 bf16 (y1 dead)
static constexpr size_t E1_B  = RA_B;               // 4096*1024 bf16 (y3 dead)
static constexpr size_t E2_B  = RA_B + 8388608;     // 4096*1024 bf16
static constexpr size_t X_B   = RA_B + 16777216;    // 4096*512 f32
static constexpr size_t H2_B  = RA_B + 29360128;    // 4096*512 f32
static constexpr size_t H2B_B = RA_B + 37748736;    // 4096*512 bf16
// inside RB:
static constexpr size_t Y2_B  = RB_B;               // 4096*13*512 bf16
static constexpr size_t HB_B  = RB_B;               // 4096*1024 bf16 (y2 dead)
static constexpr size_t HI1_B = RB_B + 8388608;     // 4096*1024 bf16
static constexpr size_t TM_B  = RB_B;               // 16384*1024 bf16 (hb dead)
static constexpr size_t STT_B = RB_B + 33554432;    // 4096*2048 bf16
static constexpr size_t O1_B  = RB_B;               // 4096*1024 bf16 (tmoe dead)
static constexpr size_t O2_B  = RB_B + 8388608;     // 4096*1024 bf16
// P smalls:
static constexpr size_t HLAT_B = P_B;               // 4096*64 f32
static constexpr size_t E3_B   = P_B + 1048576;     // 4096*128 f32
static constexpr size_t Z_B    = P_B + 3145728;     // 4096*64 f32
static constexpr size_t LOG_B  = P_B + 4194304;     // 4096*16 f32
static constexpr size_t TID_B  = P_B + 4456448;
static constexpr size_t TW_B   = P_B + 4521984;
static constexpr size_t POS_B  = P_B + 4587520;
static constexpr size_t CNT_B  = P_B + 4653056;
static constexpr size_t OFS_B  = P_B + 4653184;
static constexpr size_t ROWL_B = P_B + 4653312;
static constexpr size_t WL_B   = P_B + 4718848;     // end 140,984,576 (~134.5 MiB)

// ---------------- prep kernels ----------------
__global__ void k_zero_i(int* __restrict__ p, int n) {
  int i = blockIdx.x * 64 + threadIdx.x;
  if (i < n) p[i] = 0;
}
__global__ void k_zero_f4(float4* __restrict__ p, int n4) {
  int i = blockIdx.x * 256 + threadIdx.x;
  if (i < n4) p[i] = make_float4(0.f, 0.f, 0.f, 0.f);
}
__global__ void k_f32_to_bf4(const float* __restrict__ s, u16* __restrict__ d, int n4) {
  int i = blockIdx.x * 256 + threadIdx.x;
  if (i >= n4) return;
  float4 v = *(const float4*)(s + (size_t)i * 4);
  *(ushort4*)(d + (size_t)i * 4) = make_ushort4(f2b(v.x), f2b(v.y), f2b(v.z), f2b(v.w));
}
// conv weight: [O][I][3] fp32 -> WT[o][k*CIN+i] bf16
__global__ void k_wt_conv(const float* __restrict__ w, u16* __restrict__ wt,
                          int CIN, int COUT) {
  int idx = blockIdx.x * 256 + threadIdx.x;
  int Kc = CIN * 3;
  if (idx >= COUT * Kc) return;
  int o = idx / Kc, c = idx - o * Kc;
  int k = c / CIN, i = c - k * CIN;
  wt[idx] = f2b(w[(size_t)o * Kc + i * 3 + k]);
}
// dense weight: W[K][N] fp32 -> WT[N][K] bf16 (32x32 LDS tiles)
__global__ __launch_bounds__(256) void k_transpose_bf(const float* __restrict__ W,
                                                      u16* __restrict__ WT,
                                                      int K, int N) {
  __shared__ float t[32][33];
  int n0 = blockIdx.x * 32, k0 = blockIdx.y * 32;
  int lx = threadIdx.x & 31, ly = threadIdx.x >> 5;
#pragma unroll
  for (int r = 0; r < 32; r += 8)
    t[ly + r][lx] = W[(size_t)(k0 + ly + r) * N + n0 + lx];
  __syncthreads();
#pragma unroll
  for (int r = 0; r < 32; r += 8)
    WT[(size_t)(n0 + ly + r) * K + k0 + lx] = f2b(t[lx][ly + r]);
}

// ============================================================================
// MFMA GEMM core: C[M,N] = epi(A[M,K] @ WT[N,K]^T + bias)
// 128x128 tile, BK=32, 256 threads (4 waves, 2x2 of 64x64), 16x16x32 bf16 MFMA.
// LDS slot-XOR swizzle: chunk (row, slot) stored at slot^(row&3).
// ============================================================================
#define MFMA_PROLOG \
  __shared__ u16 Asm[128 * 32]; \
  __shared__ u16 Bsm[128 * 32]; \
  const int tid = threadIdx.x; \
  const int m0 = blockIdx.x * 128; \
  const int n0 = blockIdx.y * 128; \
  const int lane = tid & 63; \
  const int wid = tid >> 6; \
  const int wr = (wid >> 1) * 64, wc = (wid & 1) * 64; \
  const int l15 = lane & 15, lsub = lane >> 4;

template<int ACT, int OUTMODE, typename TA>  // OUTMODE: 0 f32, 1 bf16, 2 f32 +=
__global__ __launch_bounds__(256) void k_mfma_gemm(const TA* __restrict__ A,
                                                   const u16* __restrict__ WT,
                                                   const float* __restrict__ bias,
                                                   void* __restrict__ Cv,
                                                   int N, int K) {
  MFMA_PROLOG
  f32x4 acc[4][4];
  const f32x4 zf = {0.f, 0.f, 0.f, 0.f};
#pragma unroll
  for (int i = 0; i < 4; ++i)
#pragma unroll
    for (int j = 0; j < 4; ++j) acc[i][j] = zf;

  for (int k0 = 0; k0 < K; k0 += 32) {
#pragma unroll
    for (int c = 0; c < 2; ++c) {
      int idx = c * 256 + tid;
      int row = idx >> 2, slot = idx & 3;
      uint4 va = load8b(A + (size_t)(m0 + row) * K + k0 + slot * 8);
      *(uint4*)&Asm[row * 32 + (slot ^ (row & 3)) * 8] = va;
      uint4 vb = load8b(WT + (size_t)(n0 + row) * K + k0 + slot * 8);
      *(uint4*)&Bsm[row * 32 + (slot ^ (row & 3)) * 8] = vb;
    }
    __syncthreads();
    union { uint4 u; bf16x8 b; } fa[4], fb[4];
#pragma unroll
    for (int i = 0; i < 4; ++i) {
      int ra = wr + i * 16 + l15;
      fa[i].u = *(const uint4*)&Asm[ra * 32 + ((lsub ^ (ra & 3))) * 8];
      int rb = wc + i * 16 + l15;
      fb[i].u = *(const uint4*)&Bsm[rb * 32 + ((lsub ^ (rb & 3))) * 8];
    }
#pragma unroll
    for (int mi = 0; mi < 4; ++mi)
#pragma unroll
      for (int ni = 0; ni < 4; ++ni)
        acc[mi][ni] = __builtin_amdgcn_mfma_f32_16x16x32_bf16(
            fa[mi].b, fb[ni].b, acc[mi][ni], 0, 0, 0);
    __syncthreads();
  }
  const int row4 = lsub * 4;
#pragma unroll
  for (int mi = 0; mi < 4; ++mi)
#pragma unroll
    for (int ni = 0; ni < 4; ++ni) {
      int col = n0 + wc + ni * 16 + l15;
      float bv = bias[col];
#pragma unroll
      for (int j = 0; j < 4; ++j) {
        int row = m0 + wr + mi * 16 + row4 + j;
        float v = acc[mi][ni][j] + bv;
        if (ACT) v = silu_f(v);
        if (OUTMODE == 0)      ((float*)Cv)[(size_t)row * N + col] = v;
        else if (OUTMODE == 1) ((u16*)Cv)[(size_t)row * N + col] = f2b(v);
        else                   ((float*)Cv)[(size_t)row * N + col] += v;
      }
    }
}

// dual MFMA GEMM: C bf16 = silu(A@Wg^T+bg) * (A@Wu^T+bu)
template<typename TA>
__global__ __launch_bounds__(256) void k_mfma_dual(const TA* __restrict__ A,
                                                   const u16* __restrict__ WTg,
                                                   const u16* __restrict__ WTu,
                                                   const float* __restrict__ bg,
                                                   const float* __restrict__ bu,
                                                   u16* __restrict__ C,
                                                   int N, int K) {
  __shared__ u16 Asm[128 * 32];
  __shared__ u16 Gsm[128 * 32];
  __shared__ u16 Usm[128 * 32];
  const int tid = threadIdx.x;
  const int m0 = blockIdx.x * 128;
  const int n0 = blockIdx.y * 128;
  const int lane = tid & 63;
  const int wid = tid >> 6;
  const int wr = (wid >> 1) * 64, wc = (wid & 1) * 64;
  const int l15 = lane & 15, lsub = lane >> 4;
  f32x4 ag[4][4], au[4][4];
  const f32x4 zf = {0.f, 0.f, 0.f, 0.f};
#pragma unroll
  for (int i = 0; i < 4; ++i)
#pragma unroll
    for (int j = 0; j < 4; ++j) { ag[i][j] = zf; au[i][j] = zf; }

  for (int k0 = 0; k0 < K; k0 += 32) {
#pragma unroll
    for (int c = 0; c < 2; ++c) {
      int idx = c * 256 + tid;
      int row = idx >> 2, slot = idx & 3;
      int dst = row * 32 + (slot ^ (row & 3)) * 8;
      *(uint4*)&Asm[dst] = load8b(A + (size_t)(m0 + row) * K + k0 + slot * 8);
      *(uint4*)&Gsm[dst] = load8b(WTg + (size_t)(n0 + row) * K + k0 + slot * 8);
      *(uint4*)&Usm[dst] = load8b(WTu + (size_t)(n0 + row) * K + k0 + slot * 8);
    }
    __syncthreads();
    union { uint4 u; bf16x8 b; } fa[4], fg, fu;
#pragma unroll
    for (int i = 0; i < 4; ++i) {
      int ra = wr + i * 16 + l15;
      fa[i].u = *(const uint4*)&Asm[ra * 32 + ((lsub ^ (ra & 3))) * 8];
    }
#pragma unroll
    for (int ni = 0; ni < 4; ++ni) {
      int rb = wc + ni * 16 + l15;
      int off = rb * 32 + ((lsub ^ (rb & 3))) * 8;
      fg.u = *(const uint4*)&Gsm[off];
      fu.u = *(const uint4*)&Usm[off];
#pragma unroll
      for (int mi = 0; mi < 4; ++mi) {
        ag[mi][ni] = __builtin_amdgcn_mfma_f32_16x16x32_bf16(fa[mi].b, fg.b, ag[mi][ni], 0, 0, 0);
        au[mi][ni] = __builtin_amdgcn_mfma_f32_16x16x32_bf16(fa[mi].b, fu.b, au[mi][ni], 0, 0, 0);
      }
    }
    __syncthreads();
  }
  const int row4 = lsub * 4;
#pragma unroll
  for (int mi = 0; mi < 4; ++mi)
#pragma unroll
    for (int ni = 0; ni < 4; ++ni) {
      int col = n0 + wc + ni * 16 + l15;
      float bgv = bg[col], buv = bu[col];
#pragma unroll
      for (int j = 0; j < 4; ++j) {
        int row = m0 + wr + mi * 16 + row4 + j;
        float v = silu_f(ag[mi][ni][j] + bgv) * (au[mi][ni][j] + buv);
        C[(size_t)row * N + col] = f2b(v);
      }
    }
}

// conv as implicit-im2col MFMA GEMM. X:[B][TIN][CIN], WT:[COUT][3*CIN] bf16.
// Y bf16 [B*TOUT][COUT] = silu(conv+bias). kernel=3, pad=1.
template<int CIN, int TIN, int TOUT, int STRIDE, typename TX>
__global__ __launch_bounds__(256) void k_mfma_conv(const TX* __restrict__ X,
                                                   const u16* __restrict__ WT,
                                                   const float* __restrict__ bias,
                                                   u16* __restrict__ Y,
                                                   int COUT) {
  MFMA_PROLOG
  const int K = CIN * 3;
  f32x4 acc[4][4];
  const f32x4 zf = {0.f, 0.f, 0.f, 0.f};
#pragma unroll
  for (int i = 0; i < 4; ++i)
#pragma unroll
    for (int j = 0; j < 4; ++j) acc[i][j] = zf;

  for (int k0 = 0; k0 < K; k0 += 32) {
#pragma unroll
    for (int c = 0; c < 2; ++c) {
      int idx = c * 256 + tid;
      int row = idx >> 2, slot = idx & 3;
      int m = m0 + row;
      int b = m / TOUT;
      int t = m - b * TOUT;
      int kk = k0 + slot * 8;
      int ker = kk / CIN;
      int i0 = kk - ker * CIN;
      int tin = t * STRIDE - 1 + ker;
      uint4 va = make_uint4(0u, 0u, 0u, 0u);
      if (tin >= 0 && tin < TIN)
        va = load8b(X + ((size_t)b * TIN + tin) * CIN + i0);
      *(uint4*)&Asm[row * 32 + (slot ^ (row & 3)) * 8] = va;
      uint4 vb = load8b(WT + (size_t)(n0 + row) * K + k0 + slot * 8);
      *(uint4*)&Bsm[row * 32 + (slot ^ (row & 3)) * 8] = vb;
    }
    __syncthreads();
    union { uint4 u; bf16x8 b; } fa[4], fb[4];
#pragma unroll
    for (int i = 0; i < 4; ++i) {
      int ra = wr + i * 16 + l15;
      fa[i].u = *(const uint4*)&Asm[ra * 32 + ((lsub ^ (ra & 3))) * 8];
      int rb = wc + i * 16 + l15;
      fb[i].u = *(const uint4*)&Bsm[rb * 32 + ((lsub ^ (rb & 3))) * 8];
    }
#pragma unroll
    for (int mi = 0; mi < 4; ++mi)
#pragma unroll
      for (int ni = 0; ni < 4; ++ni)
        acc[mi][ni] = __builtin_amdgcn_mfma_f32_16x16x32_bf16(
            fa[mi].b, fb[ni].b, acc[mi][ni], 0, 0, 0);
    __syncthreads();
  }
  const int row4 = lsub * 4;
#pragma unroll
  for (int mi = 0; mi < 4; ++mi)
#pragma unroll
    for (int ni = 0; ni < 4; ++ni) {
      int col = n0 + wc + ni * 16 + l15;
      float bv = bias[col];
#pragma unroll
      for (int j = 0; j < 4; ++j) {
        int row = m0 + wr + mi * 16 + row4 + j;
        Y[(size_t)row * COUT + col] = f2b(silu_f(acc[mi][ni][j] + bv));
      }
    }
}

// ---------------- fp32 64x64 GEMM (small-N tails) ----------------
template<int ACT, bool NG, typename TA>
__global__ __launch_bounds__(256) void k_gemm(const TA* __restrict__ A,
                                              const float* __restrict__ W,
                                              const float* __restrict__ bias,
                                              float* __restrict__ C,
                                              int N, int K) {
  __shared__ float As[16][64];
  __shared__ float Bs[16][64];
  const int tid = threadIdx.x;
  const int m0 = blockIdx.x * 64;
  const int n0 = blockIdx.y * 64;
  const int tr = tid >> 4, tc = tid & 15;
  const int lm = tid >> 2, lk = (tid & 3) * 4;
  const int ln = tid & 63, lkb = (tid >> 6) * 4;
  float acc[4][4] = {};
  for (int k0 = 0; k0 < K; k0 += 16) {
    float4 av = ld4(A + (size_t)(m0 + lm) * K + k0 + lk);
    As[lk + 0][lm] = av.x; As[lk + 1][lm] = av.y;
    As[lk + 2][lm] = av.z; As[lk + 3][lm] = av.w;
#pragma unroll
    for (int s = 0; s < 4; ++s) {
      int kk = lkb + s;
      float v = 0.f;
      if (!NG || (n0 + ln) < N) v = W[(size_t)(k0 + kk) * N + n0 + ln];
      Bs[kk][ln] = v;
    }
    __syncthreads();
#pragma unroll
    for (int kk = 0; kk < 16; ++kk) {
      float4 a4 = *(const float4*)&As[kk][tr * 4];
      float4 b4 = *(const float4*)&Bs[kk][tc * 4];
      float a[4] = {a4.x, a4.y, a4.z, a4.w};
      float b[4] = {b4.x, b4.y, b4.z, b4.w};
#pragma unroll
      for (int i = 0; i < 4; ++i)
#pragma unroll
        for (int j = 0; j < 4; ++j) acc[i][j] = fmaf(a[i], b[j], acc[i][j]);
    }
    __syncthreads();
  }
#pragma unroll
  for (int i = 0; i < 4; ++i) {
    int m = m0 + tr * 4 + i;
#pragma unroll
    for (int j = 0; j < 4; ++j) {
      int n = n0 + tc * 4 + j;
      if (NG && n >= N) continue;
      float v = acc[i][j] + bias[n];
      if (ACT == 1) v = silu_f(v);
      C[(size_t)m * N + n] = v;
    }
  }
}

// concat projection GEMM: A = [cur_obs | hist_lat | z] -> x fp32
__global__ __launch_bounds__(256) void k_gemm_proj(const float* __restrict__ obs,
                                                   const float* __restrict__ hl,
                                                   const float* __restrict__ z,
                                                   const float* __restrict__ W,
                                                   const float* __restrict__ bias,
                                                   float* __restrict__ C) {
  const int N = 512, K = 384;
  __shared__ float As[16][64];
  __shared__ float Bs[16][64];
  const int tid = threadIdx.x;
  const int m0 = blockIdx.x * 64;
  const int n0 = blockIdx.y * 64;
  const int tr = tid >> 4, tc = tid & 15;
  const int lm = tid >> 2, lk = (tid & 3) * 4;
  const int ln = tid & 63, lkb = (tid >> 6) * 4;
  const int m = m0 + lm;
  float acc[4][4] = {};
  for (int k0 = 0; k0 < K; k0 += 16) {
#pragma unroll
    for (int j = 0; j < 4; ++j) {
      int c = k0 + lk + j;
      float v;
      if (c < 256)      v = obs[(size_t)m * 256 + c];
      else if (c < 320) v = hl[(size_t)m * 64 + (c - 256)];
      else              v = z[(size_t)m * 64 + (c - 320)];
      As[lk + j][lm] = v;
    }
#pragma unroll
    for (int s = 0; s < 4; ++s) {
      int kk = lkb + s;
      Bs[kk][ln] = W[(size_t)(k0 + kk) * N + n0 + ln];
    }
    __syncthreads();
#pragma unroll
    for (int kk = 0; kk < 16; ++kk) {
      float4 a4 = *(const float4*)&As[kk][tr * 4];
      float4 b4 = *(const float4*)&Bs[kk][tc * 4];
      float a[4] = {a4.x, a4.y, a4.z, a4.w};
      float b[4] = {b4.x, b4.y, b4.z, b4.w};
#pragma unroll
      for (int i = 0; i < 4; ++i)
#pragma unroll
        for (int j = 0; j < 4; ++j) acc[i][j] = fmaf(a[i], b[j], acc[i][j]);
    }
    __syncthreads();
  }
#pragma unroll
  for (int i = 0; i < 4; ++i) {
    int mo = m0 + tr * 4 + i;
#pragma unroll
    for (int j = 0; j < 4; ++j) {
      int n = n0 + tc * 4 + j;
      C[(size_t)mo * N + n] = acc[i][j] + bias[n];
    }
  }
}

// ---------------- MoE (fp32 experts, as round 2) ----------------
__global__ __launch_bounds__(256) void k_moe_up(const float* __restrict__ x,
                                                const float* __restrict__ Wg,
                                                const float* __restrict__ Wu,
                                                const float* __restrict__ bg,
                                                const float* __restrict__ bu,
                                                const int* __restrict__ rowlist,
                                                const int* __restrict__ counts,
                                                const int* __restrict__ offs,
                                                u16* __restrict__ t_moe) {
  const int e = blockIdx.z;
  const int ne = counts[e];
  const int m0 = blockIdx.x * 64;
  if (m0 >= ne) return;
  const int base = offs[e];
  const int N = 1024, K = 512;
  const float* Wge = Wg + (size_t)e * K * N;
  const float* Wue = Wu + (size_t)e * K * N;
  const float* bge = bg + (size_t)e * N;
  const float* bue = bu + (size_t)e * N;
  __shared__ int rs[64];
  __shared__ float As[16][64];
  __shared__ float Bg[16][64];
  __shared__ float Bu[16][64];
  const int tid = threadIdx.x;
  if (tid < 64) rs[tid] = (m0 + tid < ne) ? rowlist[base + m0 + tid] : -1;
  __syncthreads();
  const int n0 = blockIdx.y * 64;
  const int tr = tid >> 4, tc = tid & 15;
  const int lm = tid >> 2, lk = (tid & 3) * 4;
  const int ln = tid & 63, lkb = (tid >> 6) * 4;
  float ag[4][4] = {};
  float au[4][4] = {};
  for (int k0 = 0; k0 < K; k0 += 16) {
    int r = rs[lm];
    float4 av = make_float4(0.f, 0.f, 0.f, 0.f);
    if (r >= 0) av = ld4(x + (size_t)r * K + k0 + lk);
    As[lk + 0][lm] = av.x; As[lk + 1][lm] = av.y;
    As[lk + 2][lm] = av.z; As[lk + 3][lm] = av.w;
#pragma unroll
    for (int s = 0; s < 4; ++s) {
      int kk = lkb + s;
      Bg[kk][ln] = Wge[(size_t)(k0 + kk) * N + n0 + ln];
      Bu[kk][ln] = Wue[(size_t)(k0 + kk) * N + n0 + ln];
    }
    __syncthreads();
#pragma unroll
    for (int kk = 0; kk < 16; ++kk) {
      float4 a4 = *(const float4*)&As[kk][tr * 4];
      float4 g4 = *(const float4*)&Bg[kk][tc * 4];
      float4 u4 = *(const float4*)&Bu[kk][tc * 4];
      float a[4] = {a4.x, a4.y, a4.z, a4.w};
      float g[4] = {g4.x, g4.y, g4.z, g4.w};
      float u[4] = {u4.x, u4.y, u4.z, u4.w};
#pragma unroll
      for (int i = 0; i < 4; ++i)
#pragma unroll
        for (int j = 0; j < 4; ++j) {
          ag[i][j] = fmaf(a[i], g[j], ag[i][j]);
          au[i][j] = fmaf(a[i], u[j], au[i][j]);
        }
    }
    __syncthreads();
  }
#pragma unroll
  for (int i = 0; i < 4; ++i) {
    int mi = m0 + tr * 4 + i;
    if (mi >= ne) continue;
    float r[4];
#pragma unroll
    for (int j = 0; j < 4; ++j) {
      int n = n0 + tc * 4 + j;
      r[j] = silu_f(ag[i][j] + bge[n]) * (au[i][j] + bue[n]);
    }
    *(ushort4*)(t_moe + (size_t)(base + mi) * N + n0 + tc * 4) =
        make_ushort4(f2b(r[0]), f2b(r[1]), f2b(r[2]), f2b(r[3]));
  }
}

__global__ __launch_bounds__(256) void k_moe_down(const u16* __restrict__ t_moe,
                                                  const float* __restrict__ Wd,
                                                  const float* __restrict__ bd,
                                                  const int* __restrict__ rowlist,
                                                  const float* __restrict__ wlist,
                                                  const int* __restrict__ counts,
                                                  const int* __restrict__ offs,
                                                  float* __restrict__ h2) {
  const int e = blockIdx.z;
  const int ne = counts[e];
  const int m0 = blockIdx.x * 64;
  if (m0 >= ne) return;
  const int base = offs[e];
  const int N = 512, K = 1024;
  const float* Wde = Wd + (size_t)e * K * N;
  const float* bde = bd + (size_t)e * N;
  __shared__ float As[16][64];
  __shared__ float Bs[16][64];
  const int tid = threadIdx.x;
  const int n0 = blockIdx.y * 64;
  const int tr = tid >> 4, tc = tid & 15;
  const int lm = tid >> 2, lk = (tid & 3) * 4;
  const int ln = tid & 63, lkb = (tid >> 6) * 4;
  float acc[4][4] = {};
  for (int k0 = 0; k0 < K; k0 += 16) {
    float4 av = make_float4(0.f, 0.f, 0.f, 0.f);
    if (m0 + lm < ne)
      av = ld4(t_moe + (size_t)(base + m0 + lm) * K + k0 + lk);
    As[lk + 0][lm] = av.x; As[lk + 1][lm] = av.y;
    As[lk + 2][lm] = av.z; As[lk + 3][lm] = av.w;
#pragma unroll
    for (int s = 0; s < 4; ++s) {
      int kk = lkb + s;
      Bs[kk][ln] = Wde[(size_t)(k0 + kk) * N + n0 + ln];
    }
    __syncthreads();
#pragma unroll
    for (int kk = 0; kk < 16; ++kk) {
      float4 a4 = *(const float4*)&As[kk][tr * 4];
      float4 b4 = *(const float4*)&Bs[kk][tc * 4];
      float a[4] = {a4.x, a4.y, a4.z, a4.w};
      float b[4] = {b4.x, b4.y, b4.z, b4.w};
#pragma unroll
      for (int i = 0; i < 4; ++i)
#pragma unroll
        for (int j = 0; j < 4; ++j) acc[i][j] = fmaf(a[i], b[j], acc[i][j]);
    }
    __syncthreads();
  }
#pragma unroll
  for (int i = 0; i < 4; ++i) {
    int mi = m0 + tr * 4 + i;
    if (mi >= ne) continue;
    int row = rowlist[base + mi];
    float wl = wlist[base + mi];
#pragma unroll
    for (int j = 0; j < 4; ++j) {
      int n = n0 + tc * 4 + j;
      atomicAdd(&h2[(size_t)row * N + n], wl * (acc[i][j] + bde[n]));
    }
  }
}

// ---------------- small elementwise / router kernels ----------------
__global__ void k_mean7(const u16* __restrict__ y3, u16* __restrict__ hb) {
  int idx = blockIdx.x * 256 + threadIdx.x;
  if (idx >= BATCH * 1024) return;
  int b = idx >> 10, o = idx & 1023;
  const u16* p = y3 + (size_t)b * 7 * 1024 + o;
  float s = 0.f;
#pragma unroll
  for (int t = 0; t < 7; ++t) s += b2f(p[(size_t)t * 1024]);
  hb[idx] = f2b(s * (1.f / 7.f));
}

__global__ void k_z(const float* __restrict__ e3, const float* __restrict__ noise,
                    float* __restrict__ z) {
  int idx = blockIdx.x * 256 + threadIdx.x;
  if (idx >= BATCH * 64) return;
  int b = idx >> 6, j = idx & 63;
  float mu = e3[(size_t)b * 128 + j];
  float lv = e3[(size_t)b * 128 + 64 + j];
  z[idx] = mu + expf(0.5f * lv) * noise[idx];
}

__global__ void k_router(const float* __restrict__ logits, int* __restrict__ tidA,
                         float* __restrict__ twA, int* __restrict__ posA,
                         int* __restrict__ counts) {
  int b = blockIdx.x * 256 + threadIdx.x;
  if (b >= BATCH) return;
  float s[16];
#pragma unroll
  for (int e = 0; e < 16; ++e)
    s[e] = 1.f / (1.f + expf(-logits[(size_t)b * 16 + e]));
  float gsc[4];
#pragma unroll
  for (int g = 0; g < 4; ++g) {
    float m1 = -1e30f; int i1 = -1;
    for (int i = 0; i < 4; ++i) { float v = s[g * 4 + i]; if (v > m1) { m1 = v; i1 = i; } }
    float m2 = -1e30f;
    for (int i = 0; i < 4; ++i) { if (i == i1) continue; float v = s[g * 4 + i]; if (v > m2) m2 = v; }
    gsc[g] = m1 + m2;
  }
  int g1 = 0; float b1 = gsc[0];
  for (int g = 1; g < 4; ++g) if (gsc[g] > b1) { b1 = gsc[g]; g1 = g; }
  int g2 = -1; float b2 = -1e30f;
  for (int g = 0; g < 4; ++g) { if (g == g1) continue; if (gsc[g] > b2) { b2 = gsc[g]; g2 = g; } }
  float ms[16]; bool used[16];
#pragma unroll
  for (int e = 0; e < 16; ++e) {
    int g = e >> 2;
    ms[e] = (g == g1 || g == g2) ? s[e] : 0.f;
    used[e] = false;
  }
  int te[4]; float tv[4]; float tsum = 0.f;
  for (int t = 0; t < 4; ++t) {
    float best = -1.f; int bi = 0;
    for (int e = 0; e < 16; ++e)
      if (!used[e] && ms[e] > best) { best = ms[e]; bi = e; }
    used[bi] = true;
    te[t] = bi;
    tv[t] = s[bi];
    tsum += s[bi];
  }
  float inv = 1.f / (tsum + 1e-20f);
  for (int t = 0; t < 4; ++t) {
    int e = te[t];
    tidA[b * 4 + t] = e;
    twA[b * 4 + t] = tv[t] * inv;  // ROUTE_SCALE = 1.0
    posA[b * 4 + t] = atomicAdd(&counts[e], 1);
  }
}

__global__ void k_offsets(const int* __restrict__ counts, int* __restrict__ offs) {
  if (threadIdx.x == 0 && blockIdx.x == 0) {
    int a = 0;
    for (int e = 0; e < 16; ++e) { offs[e] = a; a += counts[e]; }
    offs[16] = a;
  }
}

__global__ void k_build(const int* __restrict__ tidA, const float* __restrict__ twA,
                        const int* __restrict__ posA, const int* __restrict__ offs,
                        int* __restrict__ rowlist, float* __restrict__ wlist) {
  int idx = blockIdx.x * 256 + threadIdx.x;
  if (idx >= BATCH * 4) return;
  int e = tidA[idx];
  int p = offs[e] + posA[idx];
  rowlist[p] = idx >> 2;
  wlist[p] = twA[idx];
}

// ============================================================================
extern "C" void kernel_launch(void* const* d_in, const int* in_sizes, int n_in,
                              void* d_out, int out_size, void* d_ws, size_t ws_size,
                              hipStream_t stream) {
  const float* cur_obs  = (const float*)d_in[0];
  const float* hist_seq = (const float*)d_in[1];
  const float* fut_ref  = (const float*)d_in[2];
  const float* noise    = (const float*)d_in[3];
  const float* conv1_w  = (const float*)d_in[4];
  const float* conv1_b  = (const float*)d_in[5];
  const float* conv2_w  = (const float*)d_in[6];
  const float* conv2_b  = (const float*)d_in[7];
  const float* conv3_w  = (const float*)d_in[8];
  const float* conv3_b  = (const float*)d_in[9];
  const float* hlin1_w  = (const float*)d_in[10];
  const float* hlin1_b  = (const float*)d_in[11];
  const float* hlin2_w  = (const float*)d_in[12];
  const float* hlin2_b  = (const float*)d_in[13];
  const float* enc1_w   = (const float*)d_in[14];
  const float* enc1_b   = (const float*)d_in[15];
  const float* enc2_w   = (const float*)d_in[16];
  const float* enc2_b   = (const float*)d_in[17];
  const float* enc3_w   = (const float*)d_in[18];
  const float* enc3_b   = (const float*)d_in[19];
  const float* proj_w   = (const float*)d_in[20];
  const float* proj_b   = (const float*)d_in[21];
  const float* router_w = (const float*)d_in[22];
  const float* router_b = (const float*)d_in[23];
  const float* Wg       = (const float*)d_in[24];
  const float* bg       = (const float*)d_in[25];
  const float* Wu       = (const float*)d_in[26];
  const float* bu       = (const float*)d_in[27];
  const float* Wd       = (const float*)d_in[28];
  const float* bd       = (const float*)d_in[29];
  const float* shg_w    = (const float*)d_in[30];
  const float* shg_b    = (const float*)d_in[31];
  const float* shu_w    = (const float*)d_in[32];
  const float* shu_b    = (const float*)d_in[33];
  const float* shd_w    = (const float*)d_in[34];
  const float* shd_b    = (const float*)d_in[35];
  const float* out1_w   = (const float*)d_in[36];
  const float* out1_b   = (const float*)d_in[37];
  const float* out2_w   = (const float*)d_in[38];
  const float* out2_b   = (const float*)d_in[39];
  const float* head_w   = (const float*)d_in[40];
  const float* head_b   = (const float*)d_in[41];
  (void)in_sizes; (void)n_in; (void)out_size; (void)ws_size;

  char* wsb = (char*)d_ws;
  u16* wt1T  = (u16*)(wsb + WT1T_B);
  u16* wt2T  = (u16*)(wsb + WT2T_B);
  u16* wt3T  = (u16*)(wsb + WT3T_B);
  u16* hl1T  = (u16*)(wsb + HL1T_B);
  u16* e1T   = (u16*)(wsb + E1T_B);
  u16* e2T   = (u16*)(wsb + E2T_B);
  u16* shgT  = (u16*)(wsb + SHGT_B);
  u16* shuT  = (u16*)(wsb + SHUT_B);
  u16* shdT  = (u16*)(wsb + SHDT_B);
  u16* o1T   = (u16*)(wsb + O1T_B);
  u16* o2T   = (u16*)(wsb + O2T_B);
  u16* y1b   = (u16*)(wsb + Y1_B);
  u16* y2b   = (u16*)(wsb + Y2_B);
  u16* y3b   = (u16*)(wsb + Y3_B);
  u16* e1b   = (u16*)(wsb + E1_B);
  u16* e2b   = (u16*)(wsb + E2_B);
  float* x   = (float*)(wsb + X_B);
  float* h2  = (float*)(wsb + H2_B);
  u16* h2b   = (u16*)(wsb + H2B_B);
  u16* hb    = (u16*)(wsb + HB_B);
  u16* hi1b  = (u16*)(wsb + HI1_B);
  u16* tmoeb = (u16*)(wsb + TM_B);
  u16* stb   = (u16*)(wsb + STT_B);
  u16* o1b   = (u16*)(wsb + O1_B);
  u16* o2b   = (u16*)(wsb + O2_B);
  float* hlat = (float*)(wsb + HLAT_B);
  float* e3   = (float*)(wsb + E3_B);
  float* z    = (float*)(wsb + Z_B);
  float* logitsb = (float*)(wsb + LOG_B);
  int*   tidA  = (int*)(wsb + TID_B);
  float* twA   = (float*)(wsb + TW_B);
  int*   posA  = (int*)(wsb + POS_B);
  int*   counts = (int*)(wsb + CNT_B);
  int*   offs  = (int*)(wsb + OFS_B);
  int*   rowlist = (int*)(wsb + ROWL_B);
  float* wlist = (float*)(wsb + WL_B);

  k_zero_i<<<dim3(1), 64, 0, stream>>>(counts, 16);

  // ---- weight prep: conv [O][I][3]->[O][K] bf16; dense [K][N]->[N][K] bf16 ----
  k_wt_conv<<<dim3(288), 256, 0, stream>>>(conv1_w, wt1T, 96, 256);
  k_wt_conv<<<dim3(1536), 256, 0, stream>>>(conv2_w, wt2T, 256, 512);
  k_wt_conv<<<dim3(6144), 256, 0, stream>>>(conv3_w, wt3T, 512, 1024);
  k_transpose_bf<<<dim3(32, 32), 256, 0, stream>>>(hlin1_w, hl1T, 1024, 1024);
  k_transpose_bf<<<dim3(32, 80), 256, 0, stream>>>(enc1_w, e1T, 2560, 1024);
  k_transpose_bf<<<dim3(32, 32), 256, 0, stream>>>(enc2_w, e2T, 1024, 1024);
  k_transpose_bf<<<dim3(64, 16), 256, 0, stream>>>(shg_w, shgT, 512, 2048);
  k_transpose_bf<<<dim3(64, 16), 256, 0, stream>>>(shu_w, shuT, 512, 2048);
  k_transpose_bf<<<dim3(16, 64), 256, 0, stream>>>(shd_w, shdT, 2048, 512);
  k_transpose_bf<<<dim3(32, 16), 256, 0, stream>>>(out1_w, o1T, 512, 1024);
  k_transpose_bf<<<dim3(32, 32), 256, 0, stream>>>(out2_w, o2T, 1024, 1024);

  // ---- history conv encoder (MFMA implicit-im2col) ----
  k_mfma_conv<96, 25, 25, 1, float><<<dim3(800, 2), 256, 0, stream>>>(hist_seq, wt1T, conv1_b, y1b, 256);
  k_mfma_conv<256, 25, 13, 2, u16><<<dim3(416, 4), 256, 0, stream>>>(y1b, wt2T, conv2_b, y2b, 512);
  k_mfma_conv<512, 13, 7, 2, u16><<<dim3(224, 8), 256, 0, stream>>>(y2b, wt3T, conv3_b, y3b, 1024);
  k_mean7<<<dim3(16384), 256, 0, stream>>>(y3b, hb);
  k_mfma_gemm<1, 1, u16><<<dim3(32, 8), 256, 0, stream>>>(hb, hl1T, hlin1_b, hi1b, 1024, 1024);
  k_gemm<0, false, u16><<<dim3(64, 1), 256, 0, stream>>>(hi1b, hlin2_w, hlin2_b, hlat, 64, 1024);

  // ---- fut-ref VAE encoder + reparameterize ----
  k_mfma_gemm<1, 1, float><<<dim3(32, 8), 256, 0, stream>>>(fut_ref, e1T, enc1_b, e1b, 1024, 2560);
  k_mfma_gemm<1, 1, u16><<<dim3(32, 8), 256, 0, stream>>>(e1b, e2T, enc2_b, e2b, 1024, 1024);
  k_gemm<0, false, u16><<<dim3(64, 2), 256, 0, stream>>>(e2b, enc3_w, enc3_b, e3, 128, 1024);
  k_z<<<dim3(1024), 256, 0, stream>>>(e3, noise, z);

  // ---- projection (fp32) + router ----
  k_gemm_proj<<<dim3(64, 8), 256, 0, stream>>>(cur_obs, hlat, z, proj_w, proj_b, x);
  k_gemm<0, true, float><<<dim3(64, 1), 256, 0, stream>>>(x, router_w, router_b, logitsb, 16, 512);
  k_router<<<dim3(16), 256, 0, stream>>>(logitsb, tidA, twA, posA, counts);
  k_offsets<<<dim3(1), 64, 0, stream>>>(counts, offs);
  k_build<<<dim3(64), 256, 0, stream>>>(tidA, twA, posA, offs, rowlist, wlist);

  // ---- sparse MoE (fp32) into zeroed h2 ----
  k_zero_f4<<<dim3(2048), 256, 0, stream>>>((float4*)h2, BATCH * 512 / 4);
  k_moe_up<<<dim3(64, 16, 16), 256, 0, stream>>>(x, Wg, Wu, bg, bu, rowlist, counts, offs, tmoeb);
  k_moe_down<<<dim3(64, 8, 16), 256, 0, stream>>>(tmoeb, Wd, bd, rowlist, wlist, counts, offs, h2);

  // ---- shared experts (MFMA), accumulate into h2 ----
  k_mfma_dual<float><<<dim3(32, 16), 256, 0, stream>>>(x, shgT, shuT, shg_b, shu_b, stb, 2048, 512);
  k_mfma_gemm<0, 2, u16><<<dim3(32, 4), 256, 0, stream>>>(stb, shdT, shd_b, h2, 512, 2048);

  // ---- output MLP (MFMA) + head (fp32) ----
  k_f32_to_bf4<<<dim3(2048), 256, 0, stream>>>(h2, h2b, BATCH * 512 / 4);
  k_mfma_gemm<1, 1, u16><<<dim3(32, 8), 256, 0, stream>>>(h2b, o1T, out1_b, o1b, 1024, 512);
  k_mfma_gemm<0, 1, u16><<<dim3(32, 8), 256, 0, stream>>>(o1b, o2T, out2_b, o2b, 1024, 1024);
  k_gemm<0, true, u16><<<dim3(64, 1), 256, 0, stream>>>(o2b, head_w, head_b, (float*)d_out, 23, 1024);
}

// Round 5
// 1781.867 us; speedup vs baseline: 2.7793x; 1.3229x over previous
//
#include <hip/hip_runtime.h>
#include <hip/hip_bf16.h>

// ============================================================================
// EstVAEStudent forward, round 5: precision-targeted MFMA.
//  - enc1/enc2: hi/lo 3-MFMA (~fp32); enc3/hlin2: fp32 VALU GEMM
//  - MoE up: A=x split hi/lo (2-MFMA), W bf16; down: 1-MFMA + atomic scatter
//  - shared: dual full hi/lo (3-MFMA each), down bf16-A x hi/lo-W (2-MFMA)
//  - out1/out2: hi/lo (3-MFMA); head/proj/router fp32
//  - workspace 124.2 MB
// ============================================================================

#define BATCH 4096
typedef unsigned short u16;
using bf16x8 = __attribute__((ext_vector_type(8))) __bf16;
using f32x4  = __attribute__((ext_vector_type(4))) float;

__device__ __forceinline__ float silu_f(float v) { return v / (1.f + __expf(-v)); }

__device__ __forceinline__ float b2f(u16 u) {
  union { unsigned int i; float f; } c; c.i = ((unsigned int)u) << 16; return c.f;
}
__device__ __forceinline__ u16 f2b(float f) {
  union { float f; unsigned int i; } c; c.f = f;
  unsigned int r = c.i + 0x7FFFu + ((c.i >> 16) & 1u);
  return (u16)(r >> 16);
}
__device__ __forceinline__ float4 ld4(const float* p) { return *(const float4*)p; }
__device__ __forceinline__ float4 ld4(const u16* p) {
  ushort4 v = *(const ushort4*)p;
  return make_float4(b2f(v.x), b2f(v.y), b2f(v.z), b2f(v.w));
}
__device__ __forceinline__ uint4 load8b(const u16* p) { return *(const uint4*)p; }
__device__ __forceinline__ uint4 load8b(const float* p) {
  float4 a = *(const float4*)p, b = *(const float4*)(p + 4);
  union { u16 h[8]; uint4 u; } r;
  r.h[0] = f2b(a.x); r.h[1] = f2b(a.y); r.h[2] = f2b(a.z); r.h[3] = f2b(a.w);
  r.h[4] = f2b(b.x); r.h[5] = f2b(b.y); r.h[6] = f2b(b.z); r.h[7] = f2b(b.w);
  return r.u;
}

// ---------------- workspace layout (BYTE offsets) ----------------
static constexpr size_t WT1T_B = 0;
static constexpr size_t WT2T_B = 147456;
static constexpr size_t WT3T_B = 933888;
static constexpr size_t HL1T_B = 4079616;          // ends 6,176,768
static constexpr size_t RA_B   = 6176768;          // 58,720,256 B
static constexpr size_t RB_B   = 64897024;         // 54,525,952 B
static constexpr size_t P_B    = 119422976;        // smalls
// RA phases (disjoint lifetimes):
static constexpr size_t Y1_B   = RA_B;
static constexpr size_t Y3_B   = RA_B;
static constexpr size_t E1F_B  = RA_B;                    // e1 f32 16,777,216
static constexpr size_t E2F_B  = RA_B + 16777216;         // e2 f32 16,777,216
static constexpr size_t WGT_B  = RA_B;                    // experts bf16 16,777,216
static constexpr size_t WUT_B  = RA_B + 16777216;
static constexpr size_t WDT_B  = RA_B + 33554432;         // ends +50,331,648
static constexpr size_t X_B    = RA_B + 50331648;         // x f32, ends RA end
static constexpr size_t SHGTH_B = RA_B;                   // after moe_up (wgT dead)
static constexpr size_t SHGTL_B = RA_B + 2097152;
static constexpr size_t SHUTH_B = RA_B + 4194304;
static constexpr size_t SHUTL_B = RA_B + 6291456;
static constexpr size_t SHDTH_B = RA_B + 8388608;
static constexpr size_t SHDTL_B = RA_B + 10485760;
static constexpr size_t O1TH_B  = RA_B + 12582912;
static constexpr size_t O1TL_B  = RA_B + 13631488;
static constexpr size_t O2TH_B  = RA_B + 14680064;
static constexpr size_t O2TL_B  = RA_B + 16777216;        // ends 18,874,368 (wuT dead)
static constexpr size_t H2_B    = RA_B + 25165824;        // f32, ends 33,554,432
// RB phases:
static constexpr size_t Y2_B   = RB_B;
static constexpr size_t HB_B   = RB_B;                    // bf16 8,388,608
static constexpr size_t HI1_B  = RB_B + 8388608;          // bf16 8,388,608
static constexpr size_t E1TH_B = RB_B + 16777216;         // bf16 5,242,880
static constexpr size_t E1TL_B = RB_B + 22020096;
static constexpr size_t E2TH_B = RB_B + 27262976;         // bf16 2,097,152
static constexpr size_t E2TL_B = RB_B + 29360128;         // ends 31,457,280
static constexpr size_t XH_B   = RB_B;                    // bf16 4,194,304
static constexpr size_t XL_B   = RB_B + 4194304;
static constexpr size_t TM_B   = RB_B + 8388608;          // t_moe bf16 33,554,432
static constexpr size_t STB_B  = RB_B + 8388608;          // stb bf16 16,777,216 (t_moe dead)
static constexpr size_t O1F_B  = RB_B;                    // o1 f32 16,777,216 (stb dead)
static constexpr size_t O2F_B  = RB_B + 16777216;         // o2 f32 16,777,216
// P smalls:
static constexpr size_t HLAT_B = P_B;                     // 1,048,576
static constexpr size_t E3P_B  = P_B + 1048576;           // 2,097,152
static constexpr size_t Z_B    = P_B + 3145728;           // 1,048,576
static constexpr size_t LOG_B  = P_B + 4194304;           // 262,144
static constexpr size_t TID_B  = P_B + 4456448;
static constexpr size_t TW_B   = P_B + 4521984;
static constexpr size_t POS_B  = P_B + 4587520;
static constexpr size_t CNT_B  = P_B + 4653056;
static constexpr size_t OFS_B  = P_B + 4653184;
static constexpr size_t ROWL_B = P_B + 4653312;
static constexpr size_t WL_B   = P_B + 4718848;           // end ~124.2 MB

// ---------------- prep kernels ----------------
__global__ void k_zero_i(int* __restrict__ p, int n) {
  int i = blockIdx.x * 64 + threadIdx.x;
  if (i < n) p[i] = 0;
}
__global__ void k_zero_f4(float4* __restrict__ p, int n4) {
  int i = blockIdx.x * 256 + threadIdx.x;
  if (i < n4) p[i] = make_float4(0.f, 0.f, 0.f, 0.f);
}
// x f32 -> xh, xl bf16 (hi/lo split)
__global__ void k_split_x(const float* __restrict__ s, u16* __restrict__ dh,
                          u16* __restrict__ dl, int n4) {
  int i = blockIdx.x * 256 + threadIdx.x;
  if (i >= n4) return;
  float4 v = *(const float4*)(s + (size_t)i * 4);
  float a[4] = {v.x, v.y, v.z, v.w};
  ushort4 h, l;
  u16* hp = (u16*)&h; u16* lp = (u16*)&l;
#pragma unroll
  for (int j = 0; j < 4; ++j) {
    u16 hh = f2b(a[j]);
    hp[j] = hh;
    lp[j] = f2b(a[j] - b2f(hh));
  }
  *(ushort4*)(dh + (size_t)i * 4) = h;
  *(ushort4*)(dl + (size_t)i * 4) = l;
}
// conv weight: [O][I][3] fp32 -> WT[o][k*CIN+i] bf16
__global__ void k_wt_conv(const float* __restrict__ w, u16* __restrict__ wt,
                          int CIN, int COUT) {
  int idx = blockIdx.x * 256 + threadIdx.x;
  int Kc = CIN * 3;
  if (idx >= COUT * Kc) return;
  int o = idx / Kc, c = idx - o * Kc;
  int k = c / CIN, i = c - k * CIN;
  wt[idx] = f2b(w[(size_t)o * Kc + i * 3 + k]);
}
// dense weight: W[K][N] fp32 -> WT[N][K] bf16
__global__ __launch_bounds__(256) void k_transpose_bf(const float* __restrict__ W,
                                                      u16* __restrict__ WT,
                                                      int K, int N) {
  __shared__ float t[32][33];
  int n0 = blockIdx.x * 32, k0 = blockIdx.y * 32;
  int lx = threadIdx.x & 31, ly = threadIdx.x >> 5;
#pragma unroll
  for (int r = 0; r < 32; r += 8)
    t[ly + r][lx] = W[(size_t)(k0 + ly + r) * N + n0 + lx];
  __syncthreads();
#pragma unroll
  for (int r = 0; r < 32; r += 8)
    WT[(size_t)(n0 + ly + r) * K + k0 + lx] = f2b(t[lx][ly + r]);
}
// batched (per-expert): W[E][K][N] fp32 -> WT[E][N][K] bf16
__global__ __launch_bounds__(256) void k_transpose_bf_b(const float* __restrict__ W,
                                                        u16* __restrict__ WT,
                                                        int K, int N) {
  const size_t eo = (size_t)blockIdx.z * K * N;
  __shared__ float t[32][33];
  int n0 = blockIdx.x * 32, k0 = blockIdx.y * 32;
  int lx = threadIdx.x & 31, ly = threadIdx.x >> 5;
#pragma unroll
  for (int r = 0; r < 32; r += 8)
    t[ly + r][lx] = W[eo + (size_t)(k0 + ly + r) * N + n0 + lx];
  __syncthreads();
#pragma unroll
  for (int r = 0; r < 32; r += 8)
    WT[eo + (size_t)(n0 + ly + r) * K + k0 + lx] = f2b(t[lx][ly + r]);
}
// hi/lo split transpose: W[K][N] fp32 -> WTh/WTl[N][K] bf16
__global__ __launch_bounds__(256) void k_transpose_hilo(const float* __restrict__ W,
                                                        u16* __restrict__ WTh,
                                                        u16* __restrict__ WTl,
                                                        int K, int N) {
  __shared__ float t[32][33];
  int n0 = blockIdx.x * 32, k0 = blockIdx.y * 32;
  int lx = threadIdx.x & 31, ly = threadIdx.x >> 5;
#pragma unroll
  for (int r = 0; r < 32; r += 8)
    t[ly + r][lx] = W[(size_t)(k0 + ly + r) * N + n0 + lx];
  __syncthreads();
#pragma unroll
  for (int r = 0; r < 32; r += 8) {
    float f = t[lx][ly + r];
    u16 h = f2b(f);
    size_t o = (size_t)(n0 + ly + r) * K + k0 + lx;
    WTh[o] = h;
    WTl[o] = f2b(f - b2f(h));
  }
}

// ============================================================================
// MFMA cores: 128x128 tile, BK=32, 256 thr (4 waves 2x2), 16x16x32 bf16.
// LDS slot-XOR swizzle: chunk (row, slot) at slot^(row&3).
// ============================================================================
#define MFMA_PROLOG \
  const int tid = threadIdx.x; \
  const int m0 = blockIdx.x * 128; \
  const int n0 = blockIdx.y * 128; \
  const int lane = tid & 63; \
  const int wid = tid >> 6; \
  const int wr = (wid >> 1) * 64, wc = (wid & 1) * 64; \
  const int l15 = lane & 15, lsub = lane >> 4;

// plain bf16 GEMM. OUTMODE: 0 f32, 1 bf16, 2 f32 +=
template<int ACT, int OUTMODE, typename TA, bool NG>
__global__ __launch_bounds__(256) void k_mfma_gemm(const TA* __restrict__ A,
                                                   const u16* __restrict__ WT,
                                                   const float* __restrict__ bias,
                                                   void* __restrict__ Cv,
                                                   int N, int K, int ldw) {
  __shared__ u16 Asm[128 * 32];
  __shared__ u16 Bsm[128 * 32];
  MFMA_PROLOG
  f32x4 acc[4][4];
  const f32x4 zf = {0.f, 0.f, 0.f, 0.f};
#pragma unroll
  for (int i = 0; i < 4; ++i)
#pragma unroll
    for (int j = 0; j < 4; ++j) acc[i][j] = zf;

  for (int k0 = 0; k0 < K; k0 += 32) {
#pragma unroll
    for (int c = 0; c < 2; ++c) {
      int idx = c * 256 + tid;
      int row = idx >> 2, slot = idx & 3;
      int dst = row * 32 + (slot ^ (row & 3)) * 8;
      *(uint4*)&Asm[dst] = load8b(A + (size_t)(m0 + row) * K + k0 + slot * 8);
      uint4 vb = make_uint4(0u, 0u, 0u, 0u);
      if (!NG || (n0 + row) < N)
        vb = load8b(WT + (size_t)(n0 + row) * ldw + k0 + slot * 8);
      *(uint4*)&Bsm[dst] = vb;
    }
    __syncthreads();
    union { uint4 u; bf16x8 b; } fa[4], fb[4];
#pragma unroll
    for (int i = 0; i < 4; ++i) {
      int ra = wr + i * 16 + l15;
      fa[i].u = *(const uint4*)&Asm[ra * 32 + ((lsub ^ (ra & 3))) * 8];
      int rb = wc + i * 16 + l15;
      fb[i].u = *(const uint4*)&Bsm[rb * 32 + ((lsub ^ (rb & 3))) * 8];
    }
#pragma unroll
    for (int mi = 0; mi < 4; ++mi)
#pragma unroll
      for (int ni = 0; ni < 4; ++ni)
        acc[mi][ni] = __builtin_amdgcn_mfma_f32_16x16x32_bf16(
            fa[mi].b, fb[ni].b, acc[mi][ni], 0, 0, 0);
    __syncthreads();
  }
  const int row4 = lsub * 4;
#pragma unroll
  for (int mi = 0; mi < 4; ++mi)
#pragma unroll
    for (int ni = 0; ni < 4; ++ni) {
      int col = n0 + wc + ni * 16 + l15;
      if (NG && col >= N) continue;
      float bv = bias[col];
#pragma unroll
      for (int j = 0; j < 4; ++j) {
        int row = m0 + wr + mi * 16 + row4 + j;
        float v = acc[mi][ni][j] + bv;
        if (ACT) v = silu_f(v);
        if (OUTMODE == 0)      ((float*)Cv)[(size_t)row * N + col] = v;
        else if (OUTMODE == 1) ((u16*)Cv)[(size_t)row * N + col] = f2b(v);
        else                   ((float*)Cv)[(size_t)row * N + col] += v;
      }
    }
}

// hi/lo GEMM (~fp32): A f32 split in-kernel, W pre-split, 3 MFMA, C f32.
template<int ACT>
__global__ __launch_bounds__(256) void k_mfma_gemm_hl(const float* __restrict__ A,
                                                      const u16* __restrict__ WTh,
                                                      const u16* __restrict__ WTl,
                                                      const float* __restrict__ bias,
                                                      float* __restrict__ C,
                                                      int N, int K) {
  __shared__ u16 Ah[128 * 32];
  __shared__ u16 Al[128 * 32];
  __shared__ u16 Bh[128 * 32];
  __shared__ u16 Bl[128 * 32];
  MFMA_PROLOG
  f32x4 acc[4][4];
  const f32x4 zf = {0.f, 0.f, 0.f, 0.f};
#pragma unroll
  for (int i = 0; i < 4; ++i)
#pragma unroll
    for (int j = 0; j < 4; ++j) acc[i][j] = zf;

  for (int k0 = 0; k0 < K; k0 += 32) {
#pragma unroll
    for (int c = 0; c < 2; ++c) {
      int idx = c * 256 + tid;
      int row = idx >> 2, slot = idx & 3;
      int dst = row * 32 + (slot ^ (row & 3)) * 8;
      const float* ap = A + (size_t)(m0 + row) * K + k0 + slot * 8;
      float4 a0 = *(const float4*)ap, a1 = *(const float4*)(ap + 4);
      float av[8] = {a0.x, a0.y, a0.z, a0.w, a1.x, a1.y, a1.z, a1.w};
      union { u16 h[8]; uint4 u; } uh, ul;
#pragma unroll
      for (int p = 0; p < 8; ++p) {
        u16 hh = f2b(av[p]);
        uh.h[p] = hh;
        ul.h[p] = f2b(av[p] - b2f(hh));
      }
      *(uint4*)&Ah[dst] = uh.u;
      *(uint4*)&Al[dst] = ul.u;
      size_t bo = (size_t)(n0 + row) * K + k0 + slot * 8;
      *(uint4*)&Bh[dst] = *(const uint4*)(WTh + bo);
      *(uint4*)&Bl[dst] = *(const uint4*)(WTl + bo);
    }
    __syncthreads();
    union { uint4 u; bf16x8 b; } fah[4], fal[4], fbh, fbl;
#pragma unroll
    for (int i = 0; i < 4; ++i) {
      int ra = wr + i * 16 + l15;
      int off = ra * 32 + ((lsub ^ (ra & 3))) * 8;
      fah[i].u = *(const uint4*)&Ah[off];
      fal[i].u = *(const uint4*)&Al[off];
    }
#pragma unroll
    for (int ni = 0; ni < 4; ++ni) {
      int rb = wc + ni * 16 + l15;
      int off = rb * 32 + ((lsub ^ (rb & 3))) * 8;
      fbh.u = *(const uint4*)&Bh[off];
      fbl.u = *(const uint4*)&Bl[off];
#pragma unroll
      for (int mi = 0; mi < 4; ++mi) {
        acc[mi][ni] = __builtin_amdgcn_mfma_f32_16x16x32_bf16(fah[mi].b, fbh.b, acc[mi][ni], 0, 0, 0);
        acc[mi][ni] = __builtin_amdgcn_mfma_f32_16x16x32_bf16(fah[mi].b, fbl.b, acc[mi][ni], 0, 0, 0);
        acc[mi][ni] = __builtin_amdgcn_mfma_f32_16x16x32_bf16(fal[mi].b, fbh.b, acc[mi][ni], 0, 0, 0);
      }
    }
    __syncthreads();
  }
  const int row4 = lsub * 4;
#pragma unroll
  for (int mi = 0; mi < 4; ++mi)
#pragma unroll
    for (int ni = 0; ni < 4; ++ni) {
      int col = n0 + wc + ni * 16 + l15;
      float bv = bias[col];
#pragma unroll
      for (int j = 0; j < 4; ++j) {
        int row = m0 + wr + mi * 16 + row4 + j;
        float v = acc[mi][ni][j] + bv;
        if (ACT) v = silu_f(v);
        C[(size_t)row * N + col] = v;
      }
    }
}

// A bf16 (exact) x W hi/lo (2 MFMA), f32 += epilogue (shared-expert down)
__global__ __launch_bounds__(256) void k_mfma_gemm_bhl(const u16* __restrict__ A,
                                                       const u16* __restrict__ WTh,
                                                       const u16* __restrict__ WTl,
                                                       const float* __restrict__ bias,
                                                       float* __restrict__ C,
                                                       int N, int K, int ldw) {
  __shared__ u16 Asm[128 * 32];
  __shared__ u16 Bh[128 * 32];
  __shared__ u16 Bl[128 * 32];
  MFMA_PROLOG
  f32x4 acc[4][4];
  const f32x4 zf = {0.f, 0.f, 0.f, 0.f};
#pragma unroll
  for (int i = 0; i < 4; ++i)
#pragma unroll
    for (int j = 0; j < 4; ++j) acc[i][j] = zf;

  for (int k0 = 0; k0 < K; k0 += 32) {
#pragma unroll
    for (int c = 0; c < 2; ++c) {
      int idx = c * 256 + tid;
      int row = idx >> 2, slot = idx & 3;
      int dst = row * 32 + (slot ^ (row & 3)) * 8;
      *(uint4*)&Asm[dst] = *(const uint4*)(A + (size_t)(m0 + row) * K + k0 + slot * 8);
      size_t bo = (size_t)(n0 + row) * ldw + k0 + slot * 8;
      *(uint4*)&Bh[dst] = *(const uint4*)(WTh + bo);
      *(uint4*)&Bl[dst] = *(const uint4*)(WTl + bo);
    }
    __syncthreads();
    union { uint4 u; bf16x8 b; } fa[4], fbh, fbl;
#pragma unroll
    for (int i = 0; i < 4; ++i) {
      int ra = wr + i * 16 + l15;
      fa[i].u = *(const uint4*)&Asm[ra * 32 + ((lsub ^ (ra & 3))) * 8];
    }
#pragma unroll
    for (int ni = 0; ni < 4; ++ni) {
      int rb = wc + ni * 16 + l15;
      int off = rb * 32 + ((lsub ^ (rb & 3))) * 8;
      fbh.u = *(const uint4*)&Bh[off];
      fbl.u = *(const uint4*)&Bl[off];
#pragma unroll
      for (int mi = 0; mi < 4; ++mi) {
        acc[mi][ni] = __builtin_amdgcn_mfma_f32_16x16x32_bf16(fa[mi].b, fbh.b, acc[mi][ni], 0, 0, 0);
        acc[mi][ni] = __builtin_amdgcn_mfma_f32_16x16x32_bf16(fa[mi].b, fbl.b, acc[mi][ni], 0, 0, 0);
      }
    }
    __syncthreads();
  }
  const int row4 = lsub * 4;
#pragma unroll
  for (int mi = 0; mi < 4; ++mi)
#pragma unroll
    for (int ni = 0; ni < 4; ++ni) {
      int col = n0 + wc + ni * 16 + l15;
      float bv = bias[col];
#pragma unroll
      for (int j = 0; j < 4; ++j) {
        int row = m0 + wr + mi * 16 + row4 + j;
        C[(size_t)row * N + col] += acc[mi][ni][j] + bv;
      }
    }
}

// shared-expert dual, full hi/lo: C bf16 = silu(A@Wg+bg)*(A@Wu+bu), A f32 split
__global__ __launch_bounds__(256) void k_mfma_dual_hl(const float* __restrict__ A,
                                                      const u16* __restrict__ WgTh,
                                                      const u16* __restrict__ WgTl,
                                                      const u16* __restrict__ WuTh,
                                                      const u16* __restrict__ WuTl,
                                                      const float* __restrict__ bg,
                                                      const float* __restrict__ bu,
                                                      u16* __restrict__ C,
                                                      int N, int K) {
  __shared__ u16 Ah[128 * 32];
  __shared__ u16 Al[128 * 32];
  __shared__ u16 Gh[128 * 32];
  __shared__ u16 Gl[128 * 32];
  __shared__ u16 Uh[128 * 32];
  __shared__ u16 Ul[128 * 32];
  MFMA_PROLOG
  f32x4 ag[4][4], au[4][4];
  const f32x4 zf = {0.f, 0.f, 0.f, 0.f};
#pragma unroll
  for (int i = 0; i < 4; ++i)
#pragma unroll
    for (int j = 0; j < 4; ++j) { ag[i][j] = zf; au[i][j] = zf; }

  for (int k0 = 0; k0 < K; k0 += 32) {
#pragma unroll
    for (int c = 0; c < 2; ++c) {
      int idx = c * 256 + tid;
      int row = idx >> 2, slot = idx & 3;
      int dst = row * 32 + (slot ^ (row & 3)) * 8;
      const float* ap = A + (size_t)(m0 + row) * K + k0 + slot * 8;
      float4 a0 = *(const float4*)ap, a1 = *(const float4*)(ap + 4);
      float av[8] = {a0.x, a0.y, a0.z, a0.w, a1.x, a1.y, a1.z, a1.w};
      union { u16 h[8]; uint4 u; } uh, ul;
#pragma unroll
      for (int p = 0; p < 8; ++p) {
        u16 hh = f2b(av[p]);
        uh.h[p] = hh;
        ul.h[p] = f2b(av[p] - b2f(hh));
      }
      *(uint4*)&Ah[dst] = uh.u;
      *(uint4*)&Al[dst] = ul.u;
      size_t bo = (size_t)(n0 + row) * K + k0 + slot * 8;
      *(uint4*)&Gh[dst] = *(const uint4*)(WgTh + bo);
      *(uint4*)&Gl[dst] = *(const uint4*)(WgTl + bo);
      *(uint4*)&Uh[dst] = *(const uint4*)(WuTh + bo);
      *(uint4*)&Ul[dst] = *(const uint4*)(WuTl + bo);
    }
    __syncthreads();
    union { uint4 u; bf16x8 b; } fah[4], fal[4], fbh, fbl;
#pragma unroll
    for (int i = 0; i < 4; ++i) {
      int ra = wr + i * 16 + l15;
      int off = ra * 32 + ((lsub ^ (ra & 3))) * 8;
      fah[i].u = *(const uint4*)&Ah[off];
      fal[i].u = *(const uint4*)&Al[off];
    }
#pragma unroll
    for (int ni = 0; ni < 4; ++ni) {
      int rb = wc + ni * 16 + l15;
      int off = rb * 32 + ((lsub ^ (rb & 3))) * 8;
      fbh.u = *(const uint4*)&Gh[off];
      fbl.u = *(const uint4*)&Gl[off];
#pragma unroll
      for (int mi = 0; mi < 4; ++mi) {
        ag[mi][ni] = __builtin_amdgcn_mfma_f32_16x16x32_bf16(fah[mi].b, fbh.b, ag[mi][ni], 0, 0, 0);
        ag[mi][ni] = __builtin_amdgcn_mfma_f32_16x16x32_bf16(fah[mi].b, fbl.b, ag[mi][ni], 0, 0, 0);
        ag[mi][ni] = __builtin_amdgcn_mfma_f32_16x16x32_bf16(fal[mi].b, fbh.b, ag[mi][ni], 0, 0, 0);
      }
      fbh.u = *(const uint4*)&Uh[off];
      fbl.u = *(const uint4*)&Ul[off];
#pragma unroll
      for (int mi = 0; mi < 4; ++mi) {
        au[mi][ni] = __builtin_amdgcn_mfma_f32_16x16x32_bf16(fah[mi].b, fbh.b, au[mi][ni], 0, 0, 0);
        au[mi][ni] = __builtin_amdgcn_mfma_f32_16x16x32_bf16(fah[mi].b, fbl.b, au[mi][ni], 0, 0, 0);
        au[mi][ni] = __builtin_amdgcn_mfma_f32_16x16x32_bf16(fal[mi].b, fbh.b, au[mi][ni], 0, 0, 0);
      }
    }
    __syncthreads();
  }
  const int row4 = lsub * 4;
#pragma unroll
  for (int mi = 0; mi < 4; ++mi)
#pragma unroll
    for (int ni = 0; ni < 4; ++ni) {
      int col = n0 + wc + ni * 16 + l15;
      float bgv = bg[col], buv = bu[col];
#pragma unroll
      for (int j = 0; j < 4; ++j) {
        int row = m0 + wr + mi * 16 + row4 + j;
        float v = silu_f(ag[mi][ni][j] + bgv) * (au[mi][ni][j] + buv);
        C[(size_t)row * N + col] = f2b(v);
      }
    }
}

// MoE up: gathered A hi/lo (xh/xl) x bf16 W (2-MFMA per operand)
__global__ __launch_bounds__(256) void k_moe_up2(const u16* __restrict__ xh,
                                                 const u16* __restrict__ xl,
                                                 const u16* __restrict__ WgT,
                                                 const u16* __restrict__ WuT,
                                                 const float* __restrict__ bg,
                                                 const float* __restrict__ bu,
                                                 const int* __restrict__ rowlist,
                                                 const int* __restrict__ counts,
                                                 const int* __restrict__ offs,
                                                 u16* __restrict__ t_moe) {
  const int e = blockIdx.z;
  const int ne = counts[e];
  const int N = 1024, K = 512;
  __shared__ int rs[128];
  __shared__ u16 Ah[128 * 32];
  __shared__ u16 Al[128 * 32];
  __shared__ u16 Gs[128 * 32];
  __shared__ u16 Us[128 * 32];
  MFMA_PROLOG
  if (m0 >= ne) return;
  const int base = offs[e];
  const u16* Wge = WgT + (size_t)e * N * K;
  const u16* Wue = WuT + (size_t)e * N * K;
  const float* bge = bg + (size_t)e * N;
  const float* bue = bu + (size_t)e * N;
  if (tid < 128) rs[tid] = (m0 + tid < ne) ? rowlist[base + m0 + tid] : -1;
  __syncthreads();
  f32x4 ag[4][4], au[4][4];
  const f32x4 zf = {0.f, 0.f, 0.f, 0.f};
#pragma unroll
  for (int i = 0; i < 4; ++i)
#pragma unroll
    for (int j = 0; j < 4; ++j) { ag[i][j] = zf; au[i][j] = zf; }

  for (int k0 = 0; k0 < K; k0 += 32) {
#pragma unroll
    for (int c = 0; c < 2; ++c) {
      int idx = c * 256 + tid;
      int row = idx >> 2, slot = idx & 3;
      int dst = row * 32 + (slot ^ (row & 3)) * 8;
      int r = rs[row];
      uint4 vh = make_uint4(0u, 0u, 0u, 0u), vl = vh;
      if (r >= 0) {
        vh = *(const uint4*)(xh + (size_t)r * K + k0 + slot * 8);
        vl = *(const uint4*)(xl + (size_t)r * K + k0 + slot * 8);
      }
      *(uint4*)&Ah[dst] = vh;
      *(uint4*)&Al[dst] = vl;
      *(uint4*)&Gs[dst] = *(const uint4*)(Wge + (size_t)(n0 + row) * K + k0 + slot * 8);
      *(uint4*)&Us[dst] = *(const uint4*)(Wue + (size_t)(n0 + row) * K + k0 + slot * 8);
    }
    __syncthreads();
    union { uint4 u; bf16x8 b; } fah[4], fal[4], fg, fu;
#pragma unroll
    for (int i = 0; i < 4; ++i) {
      int ra = wr + i * 16 + l15;
      int off = ra * 32 + ((lsub ^ (ra & 3))) * 8;
      fah[i].u = *(const uint4*)&Ah[off];
      fal[i].u = *(const uint4*)&Al[off];
    }
#pragma unroll
    for (int ni = 0; ni < 4; ++ni) {
      int rb = wc + ni * 16 + l15;
      int off = rb * 32 + ((lsub ^ (rb & 3))) * 8;
      fg.u = *(const uint4*)&Gs[off];
      fu.u = *(const uint4*)&Us[off];
#pragma unroll
      for (int mi = 0; mi < 4; ++mi) {
        ag[mi][ni] = __builtin_amdgcn_mfma_f32_16x16x32_bf16(fah[mi].b, fg.b, ag[mi][ni], 0, 0, 0);
        ag[mi][ni] = __builtin_amdgcn_mfma_f32_16x16x32_bf16(fal[mi].b, fg.b, ag[mi][ni], 0, 0, 0);
        au[mi][ni] = __builtin_amdgcn_mfma_f32_16x16x32_bf16(fah[mi].b, fu.b, au[mi][ni], 0, 0, 0);
        au[mi][ni] = __builtin_amdgcn_mfma_f32_16x16x32_bf16(fal[mi].b, fu.b, au[mi][ni], 0, 0, 0);
      }
    }
    __syncthreads();
  }
  const int row4 = lsub * 4;
#pragma unroll
  for (int mi = 0; mi < 4; ++mi)
#pragma unroll
    for (int ni = 0; ni < 4; ++ni) {
      int col = n0 + wc + ni * 16 + l15;
      float bgv = bge[col], buv = bue[col];
#pragma unroll
      for (int j = 0; j < 4; ++j) {
        int row = m0 + wr + mi * 16 + row4 + j;
        if (row >= ne) continue;
        float v = silu_f(ag[mi][ni][j] + bgv) * (au[mi][ni][j] + buv);
        t_moe[(size_t)(base + row) * N + col] = f2b(v);
      }
    }
}

// MoE down: t_moe bf16 @ WdT_e -> weighted atomic scatter into h2 f32
__global__ __launch_bounds__(256) void k_moe_down_mfma(const u16* __restrict__ t_moe,
                                                       const u16* __restrict__ WdT,
                                                       const float* __restrict__ bd,
                                                       const int* __restrict__ rowlist,
                                                       const float* __restrict__ wlist,
                                                       const int* __restrict__ counts,
                                                       const int* __restrict__ offs,
                                                       float* __restrict__ h2) {
  const int e = blockIdx.z;
  const int ne = counts[e];
  const int N = 512, K = 1024;
  __shared__ u16 Asm[128 * 32];
  __shared__ u16 Bsm[128 * 32];
  MFMA_PROLOG
  if (m0 >= ne) return;
  const int base = offs[e];
  const u16* Wde = WdT + (size_t)e * N * K;
  const float* bde = bd + (size_t)e * N;
  f32x4 acc[4][4];
  const f32x4 zf = {0.f, 0.f, 0.f, 0.f};
#pragma unroll
  for (int i = 0; i < 4; ++i)
#pragma unroll
    for (int j = 0; j < 4; ++j) acc[i][j] = zf;

  for (int k0 = 0; k0 < K; k0 += 32) {
#pragma unroll
    for (int c = 0; c < 2; ++c) {
      int idx = c * 256 + tid;
      int row = idx >> 2, slot = idx & 3;
      int dst = row * 32 + (slot ^ (row & 3)) * 8;
      uint4 va = make_uint4(0u, 0u, 0u, 0u);
      if (m0 + row < ne)
        va = *(const uint4*)(t_moe + (size_t)(base + m0 + row) * K + k0 + slot * 8);
      *(uint4*)&Asm[dst] = va;
      *(uint4*)&Bsm[dst] = *(const uint4*)(Wde + (size_t)(n0 + row) * K + k0 + slot * 8);
    }
    __syncthreads();
    union { uint4 u; bf16x8 b; } fa[4], fb[4];
#pragma unroll
    for (int i = 0; i < 4; ++i) {
      int ra = wr + i * 16 + l15;
      fa[i].u = *(const uint4*)&Asm[ra * 32 + ((lsub ^ (ra & 3))) * 8];
      int rb = wc + i * 16 + l15;
      fb[i].u = *(const uint4*)&Bsm[rb * 32 + ((lsub ^ (rb & 3))) * 8];
    }
#pragma unroll
    for (int mi = 0; mi < 4; ++mi)
#pragma unroll
      for (int ni = 0; ni < 4; ++ni)
        acc[mi][ni] = __builtin_amdgcn_mfma_f32_16x16x32_bf16(
            fa[mi].b, fb[ni].b, acc[mi][ni], 0, 0, 0);
    __syncthreads();
  }
  const int row4 = lsub * 4;
#pragma unroll
  for (int mi = 0; mi < 4; ++mi)
#pragma unroll
    for (int j = 0; j < 4; ++j) {
      int row = m0 + wr + mi * 16 + row4 + j;
      if (row >= ne) continue;
      int r = rowlist[base + row];
      float wl = wlist[base + row];
#pragma unroll
      for (int ni = 0; ni < 4; ++ni) {
        int col = n0 + wc + ni * 16 + l15;
        atomicAdd(&h2[(size_t)r * 512 + col], wl * (acc[mi][ni][j] + bde[col]));
      }
    }
}

// conv as implicit-im2col MFMA GEMM
template<int CIN, int TIN, int TOUT, int STRIDE, typename TX>
__global__ __launch_bounds__(256) void k_mfma_conv(const TX* __restrict__ X,
                                                   const u16* __restrict__ WT,
                                                   const float* __restrict__ bias,
                                                   u16* __restrict__ Y,
                                                   int COUT) {
  __shared__ u16 Asm[128 * 32];
  __shared__ u16 Bsm[128 * 32];
  MFMA_PROLOG
  const int K = CIN * 3;
  f32x4 acc[4][4];
  const f32x4 zf = {0.f, 0.f, 0.f, 0.f};
#pragma unroll
  for (int i = 0; i < 4; ++i)
#pragma unroll
    for (int j = 0; j < 4; ++j) acc[i][j] = zf;

  for (int k0 = 0; k0 < K; k0 += 32) {
#pragma unroll
    for (int c = 0; c < 2; ++c) {
      int idx = c * 256 + tid;
      int row = idx >> 2, slot = idx & 3;
      int m = m0 + row;
      int b = m / TOUT;
      int t = m - b * TOUT;
      int kk = k0 + slot * 8;
      int ker = kk / CIN;
      int i0 = kk - ker * CIN;
      int tin = t * STRIDE - 1 + ker;
      uint4 va = make_uint4(0u, 0u, 0u, 0u);
      if (tin >= 0 && tin < TIN)
        va = load8b(X + ((size_t)b * TIN + tin) * CIN + i0);
      *(uint4*)&Asm[row * 32 + (slot ^ (row & 3)) * 8] = va;
      *(uint4*)&Bsm[row * 32 + (slot ^ (row & 3)) * 8] =
          load8b(WT + (size_t)(n0 + row) * K + k0 + slot * 8);
    }
    __syncthreads();
    union { uint4 u; bf16x8 b; } fa[4], fb[4];
#pragma unroll
    for (int i = 0; i < 4; ++i) {
      int ra = wr + i * 16 + l15;
      fa[i].u = *(const uint4*)&Asm[ra * 32 + ((lsub ^ (ra & 3))) * 8];
      int rb = wc + i * 16 + l15;
      fb[i].u = *(const uint4*)&Bsm[rb * 32 + ((lsub ^ (rb & 3))) * 8];
    }
#pragma unroll
    for (int mi = 0; mi < 4; ++mi)
#pragma unroll
      for (int ni = 0; ni < 4; ++ni)
        acc[mi][ni] = __builtin_amdgcn_mfma_f32_16x16x32_bf16(
            fa[mi].b, fb[ni].b, acc[mi][ni], 0, 0, 0);
    __syncthreads();
  }
  const int row4 = lsub * 4;
#pragma unroll
  for (int mi = 0; mi < 4; ++mi)
#pragma unroll
    for (int ni = 0; ni < 4; ++ni) {
      int col = n0 + wc + ni * 16 + l15;
      float bv = bias[col];
#pragma unroll
      for (int j = 0; j < 4; ++j) {
        int row = m0 + wr + mi * 16 + row4 + j;
        Y[(size_t)row * COUT + col] = f2b(silu_f(acc[mi][ni][j] + bv));
      }
    }
}

// ---------------- fp32 64x64 GEMM (hlin2 / enc3 / router / head) ----------------
template<int ACT, bool NG, typename TA>
__global__ __launch_bounds__(256) void k_gemm(const TA* __restrict__ A,
                                              const float* __restrict__ W,
                                              const float* __restrict__ bias,
                                              float* __restrict__ C,
                                              int N, int K) {
  __shared__ float As[16][64];
  __shared__ float Bs[16][64];
  const int tid = threadIdx.x;
  const int m0 = blockIdx.x * 64;
  const int n0 = blockIdx.y * 64;
  const int tr = tid >> 4, tc = tid & 15;
  const int lm = tid >> 2, lk = (tid & 3) * 4;
  const int ln = tid & 63, lkb = (tid >> 6) * 4;
  float acc[4][4] = {};
  for (int k0 = 0; k0 < K; k0 += 16) {
    float4 av = ld4(A + (size_t)(m0 + lm) * K + k0 + lk);
    As[lk + 0][lm] = av.x; As[lk + 1][lm] = av.y;
    As[lk + 2][lm] = av.z; As[lk + 3][lm] = av.w;
#pragma unroll
    for (int s = 0; s < 4; ++s) {
      int kk = lkb + s;
      float v = 0.f;
      if (!NG || (n0 + ln) < N) v = W[(size_t)(k0 + kk) * N + n0 + ln];
      Bs[kk][ln] = v;
    }
    __syncthreads();
#pragma unroll
    for (int kk = 0; kk < 16; ++kk) {
      float4 a4 = *(const float4*)&As[kk][tr * 4];
      float4 b4 = *(const float4*)&Bs[kk][tc * 4];
      float a[4] = {a4.x, a4.y, a4.z, a4.w};
      float b[4] = {b4.x, b4.y, b4.z, b4.w};
#pragma unroll
      for (int i = 0; i < 4; ++i)
#pragma unroll
        for (int j = 0; j < 4; ++j) acc[i][j] = fmaf(a[i], b[j], acc[i][j]);
    }
    __syncthreads();
  }
#pragma unroll
  for (int i = 0; i < 4; ++i) {
    int m = m0 + tr * 4 + i;
#pragma unroll
    for (int j = 0; j < 4; ++j) {
      int n = n0 + tc * 4 + j;
      if (NG && n >= N) continue;
      float v = acc[i][j] + bias[n];
      if (ACT == 1) v = silu_f(v);
      C[(size_t)m * N + n] = v;
    }
  }
}

// concat projection GEMM (fp32, routing-safe)
__global__ __launch_bounds__(256) void k_gemm_proj(const float* __restrict__ obs,
                                                   const float* __restrict__ hl,
                                                   const float* __restrict__ z,
                                                   const float* __restrict__ W,
                                                   const float* __restrict__ bias,
                                                   float* __restrict__ C) {
  const int N = 512, K = 384;
  __shared__ float As[16][64];
  __shared__ float Bs[16][64];
  const int tid = threadIdx.x;
  const int m0 = blockIdx.x * 64;
  const int n0 = blockIdx.y * 64;
  const int tr = tid >> 4, tc = tid & 15;
  const int lm = tid >> 2, lk = (tid & 3) * 4;
  const int ln = tid & 63, lkb = (tid >> 6) * 4;
  const int m = m0 + lm;
  float acc[4][4] = {};
  for (int k0 = 0; k0 < K; k0 += 16) {
#pragma unroll
    for (int j = 0; j < 4; ++j) {
      int c = k0 + lk + j;
      float v;
      if (c < 256)      v = obs[(size_t)m * 256 + c];
      else if (c < 320) v = hl[(size_t)m * 64 + (c - 256)];
      else              v = z[(size_t)m * 64 + (c - 320)];
      As[lk + j][lm] = v;
    }
#pragma unroll
    for (int s = 0; s < 4; ++s) {
      int kk = lkb + s;
      Bs[kk][ln] = W[(size_t)(k0 + kk) * N + n0 + ln];
    }
    __syncthreads();
#pragma unroll
    for (int kk = 0; kk < 16; ++kk) {
      float4 a4 = *(const float4*)&As[kk][tr * 4];
      float4 b4 = *(const float4*)&Bs[kk][tc * 4];
      float a[4] = {a4.x, a4.y, a4.z, a4.w};
      float b[4] = {b4.x, b4.y, b4.z, b4.w};
#pragma unroll
      for (int i = 0; i < 4; ++i)
#pragma unroll
        for (int j = 0; j < 4; ++j) acc[i][j] = fmaf(a[i], b[j], acc[i][j]);
    }
    __syncthreads();
  }
#pragma unroll
  for (int i = 0; i < 4; ++i) {
    int mo = m0 + tr * 4 + i;
#pragma unroll
    for (int j = 0; j < 4; ++j) {
      int n = n0 + tc * 4 + j;
      C[(size_t)mo * N + n] = acc[i][j] + bias[n];
    }
  }
}

// ---------------- small elementwise / router kernels ----------------
__global__ void k_mean7(const u16* __restrict__ y3, u16* __restrict__ hb) {
  int idx = blockIdx.x * 256 + threadIdx.x;
  if (idx >= BATCH * 1024) return;
  int b = idx >> 10, o = idx & 1023;
  const u16* p = y3 + (size_t)b * 7 * 1024 + o;
  float s = 0.f;
#pragma unroll
  for (int t = 0; t < 7; ++t) s += b2f(p[(size_t)t * 1024]);
  hb[idx] = f2b(s * (1.f / 7.f));
}

__global__ void k_z(const float* __restrict__ e3, const float* __restrict__ noise,
                    float* __restrict__ z) {
  int idx = blockIdx.x * 256 + threadIdx.x;
  if (idx >= BATCH * 64) return;
  int b = idx >> 6, j = idx & 63;
  float mu = e3[(size_t)b * 128 + j];
  float lv = e3[(size_t)b * 128 + 64 + j];
  z[idx] = mu + expf(0.5f * lv) * noise[idx];
}

__global__ void k_router(const float* __restrict__ logits, int* __restrict__ tidA,
                         float* __restrict__ twA, int* __restrict__ posA,
                         int* __restrict__ counts) {
  int b = blockIdx.x * 256 + threadIdx.x;
  if (b >= BATCH) return;
  float s[16];
#pragma unroll
  for (int e = 0; e < 16; ++e)
    s[e] = 1.f / (1.f + expf(-logits[(size_t)b * 16 + e]));
  float gsc[4];
#pragma unroll
  for (int g = 0; g < 4; ++g) {
    float m1 = -1e30f; int i1 = -1;
    for (int i = 0; i < 4; ++i) { float v = s[g * 4 + i]; if (v > m1) { m1 = v; i1 = i; } }
    float m2 = -1e30f;
    for (int i = 0; i < 4; ++i) { if (i == i1) continue; float v = s[g * 4 + i]; if (v > m2) m2 = v; }
    gsc[g] = m1 + m2;
  }
  int g1 = 0; float b1 = gsc[0];
  for (int g = 1; g < 4; ++g) if (gsc[g] > b1) { b1 = gsc[g]; g1 = g; }
  int g2 = -1; float b2 = -1e30f;
  for (int g = 0; g < 4; ++g) { if (g == g1) continue; if (gsc[g] > b2) { b2 = gsc[g]; g2 = g; } }
  float ms[16]; bool used[16];
#pragma unroll
  for (int e = 0; e < 16; ++e) {
    int g = e >> 2;
    ms[e] = (g == g1 || g == g2) ? s[e] : 0.f;
    used[e] = false;
  }
  int te[4]; float tv[4]; float tsum = 0.f;
  for (int t = 0; t < 4; ++t) {
    float best = -1.f; int bi = 0;
    for (int e = 0; e < 16; ++e)
      if (!used[e] && ms[e] > best) { best = ms[e]; bi = e; }
    used[bi] = true;
    te[t] = bi;
    tv[t] = s[bi];
    tsum += s[bi];
  }
  float inv = 1.f / (tsum + 1e-20f);
  for (int t = 0; t < 4; ++t) {
    int e = te[t];
    tidA[b * 4 + t] = e;
    twA[b * 4 + t] = tv[t] * inv;  // ROUTE_SCALE = 1.0
    posA[b * 4 + t] = atomicAdd(&counts[e], 1);
  }
}

__global__ void k_offsets(const int* __restrict__ counts, int* __restrict__ offs) {
  if (threadIdx.x == 0 && blockIdx.x == 0) {
    int a = 0;
    for (int e = 0; e < 16; ++e) { offs[e] = a; a += counts[e]; }
    offs[16] = a;
  }
}

__global__ void k_build(const int* __restrict__ tidA, const float* __restrict__ twA,
                        const int* __restrict__ posA, const int* __restrict__ offs,
                        int* __restrict__ rowlist, float* __restrict__ wlist) {
  int idx = blockIdx.x * 256 + threadIdx.x;
  if (idx >= BATCH * 4) return;
  int e = tidA[idx];
  int p = offs[e] + posA[idx];
  rowlist[p] = idx >> 2;
  wlist[p] = twA[idx];
}

// ============================================================================
extern "C" void kernel_launch(void* const* d_in, const int* in_sizes, int n_in,
                              void* d_out, int out_size, void* d_ws, size_t ws_size,
                              hipStream_t stream) {
  const float* cur_obs  = (const float*)d_in[0];
  const float* hist_seq = (const float*)d_in[1];
  const float* fut_ref  = (const float*)d_in[2];
  const float* noise    = (const float*)d_in[3];
  const float* conv1_w  = (const float*)d_in[4];
  const float* conv1_b  = (const float*)d_in[5];
  const float* conv2_w  = (const float*)d_in[6];
  const float* conv2_b  = (const float*)d_in[7];
  const float* conv3_w  = (const float*)d_in[8];
  const float* conv3_b  = (const float*)d_in[9];
  const float* hlin1_w  = (const float*)d_in[10];
  const float* hlin1_b  = (const float*)d_in[11];
  const float* hlin2_w  = (const float*)d_in[12];
  const float* hlin2_b  = (const float*)d_in[13];
  const float* enc1_w   = (const float*)d_in[14];
  const float* enc1_b   = (const float*)d_in[15];
  const float* enc2_w   = (const float*)d_in[16];
  const float* enc2_b   = (const float*)d_in[17];
  const float* enc3_w   = (const float*)d_in[18];
  const float* enc3_b   = (const float*)d_in[19];
  const float* proj_w   = (const float*)d_in[20];
  const float* proj_b   = (const float*)d_in[21];
  const float* router_w = (const float*)d_in[22];
  const float* router_b = (const float*)d_in[23];
  const float* Wg       = (const float*)d_in[24];
  const float* bg       = (const float*)d_in[25];
  const float* Wu       = (const float*)d_in[26];
  const float* bu       = (const float*)d_in[27];
  const float* Wd       = (const float*)d_in[28];
  const float* bd       = (const float*)d_in[29];
  const float* shg_w    = (const float*)d_in[30];
  const float* shg_b    = (const float*)d_in[31];
  const float* shu_w    = (const float*)d_in[32];
  const float* shu_b    = (const float*)d_in[33];
  const float* shd_w    = (const float*)d_in[34];
  const float* shd_b    = (const float*)d_in[35];
  const float* out1_w   = (const float*)d_in[36];
  const float* out1_b   = (const float*)d_in[37];
  const float* out2_w   = (const float*)d_in[38];
  const float* out2_b   = (const float*)d_in[39];
  const float* head_w   = (const float*)d_in[40];
  const float* head_b   = (const float*)d_in[41];
  (void)in_sizes; (void)n_in; (void)out_size; (void)ws_size;

  char* wsb = (char*)d_ws;
  u16* wt1T  = (u16*)(wsb + WT1T_B);
  u16* wt2T  = (u16*)(wsb + WT2T_B);
  u16* wt3T  = (u16*)(wsb + WT3T_B);
  u16* hl1T  = (u16*)(wsb + HL1T_B);
  u16* y1b   = (u16*)(wsb + Y1_B);
  u16* y2b   = (u16*)(wsb + Y2_B);
  u16* y3b   = (u16*)(wsb + Y3_B);
  float* e1f = (float*)(wsb + E1F_B);
  float* e2f = (float*)(wsb + E2F_B);
  u16* wgT   = (u16*)(wsb + WGT_B);
  u16* wuT   = (u16*)(wsb + WUT_B);
  u16* wdT   = (u16*)(wsb + WDT_B);
  float* x   = (float*)(wsb + X_B);
  u16* shgTh = (u16*)(wsb + SHGTH_B);
  u16* shgTl = (u16*)(wsb + SHGTL_B);
  u16* shuTh = (u16*)(wsb + SHUTH_B);
  u16* shuTl = (u16*)(wsb + SHUTL_B);
  u16* shdTh = (u16*)(wsb + SHDTH_B);
  u16* shdTl = (u16*)(wsb + SHDTL_B);
  u16* o1Th  = (u16*)(wsb + O1TH_B);
  u16* o1Tl  = (u16*)(wsb + O1TL_B);
  u16* o2Th  = (u16*)(wsb + O2TH_B);
  u16* o2Tl  = (u16*)(wsb + O2TL_B);
  float* h2  = (float*)(wsb + H2_B);
  u16* hb    = (u16*)(wsb + HB_B);
  u16* hi1b  = (u16*)(wsb + HI1_B);
  u16* e1Th  = (u16*)(wsb + E1TH_B);
  u16* e1Tl  = (u16*)(wsb + E1TL_B);
  u16* e2Th  = (u16*)(wsb + E2TH_B);
  u16* e2Tl  = (u16*)(wsb + E2TL_B);
  u16* xh    = (u16*)(wsb + XH_B);
  u16* xl    = (u16*)(wsb + XL_B);
  u16* tmoeb = (u16*)(wsb + TM_B);
  u16* stb   = (u16*)(wsb + STB_B);
  float* o1  = (float*)(wsb + O1F_B);
  float* o2  = (float*)(wsb + O2F_B);
  float* hlat = (float*)(wsb + HLAT_B);
  float* e3   = (float*)(wsb + E3P_B);
  float* z    = (float*)(wsb + Z_B);
  float* logitsb = (float*)(wsb + LOG_B);
  int*   tidA  = (int*)(wsb + TID_B);
  float* twA   = (float*)(wsb + TW_B);
  int*   posA  = (int*)(wsb + POS_B);
  int*   counts = (int*)(wsb + CNT_B);
  int*   offs  = (int*)(wsb + OFS_B);
  int*   rowlist = (int*)(wsb + ROWL_B);
  float* wlist = (float*)(wsb + WL_B);

  k_zero_i<<<dim3(1), 64, 0, stream>>>(counts, 16);

  // ---- weight prep (prefix) ----
  k_wt_conv<<<dim3(288), 256, 0, stream>>>(conv1_w, wt1T, 96, 256);
  k_wt_conv<<<dim3(1536), 256, 0, stream>>>(conv2_w, wt2T, 256, 512);
  k_wt_conv<<<dim3(6144), 256, 0, stream>>>(conv3_w, wt3T, 512, 1024);
  k_transpose_bf<<<dim3(32, 32), 256, 0, stream>>>(hlin1_w, hl1T, 1024, 1024);

  // ---- history conv encoder ----
  k_mfma_conv<96, 25, 25, 1, float><<<dim3(800, 2), 256, 0, stream>>>(hist_seq, wt1T, conv1_b, y1b, 256);
  k_mfma_conv<256, 25, 13, 2, u16><<<dim3(416, 4), 256, 0, stream>>>(y1b, wt2T, conv2_b, y2b, 512);
  k_mfma_conv<512, 13, 7, 2, u16><<<dim3(224, 8), 256, 0, stream>>>(y2b, wt3T, conv3_b, y3b, 1024);
  k_mean7<<<dim3(16384), 256, 0, stream>>>(y3b, hb);
  k_mfma_gemm<1, 1, u16, false><<<dim3(32, 8), 256, 0, stream>>>(hb, hl1T, hlin1_b, hi1b, 1024, 1024, 1024);
  k_gemm<0, false, u16><<<dim3(64, 1), 256, 0, stream>>>(hi1b, hlin2_w, hlin2_b, hlat, 64, 1024);

  // ---- VAE encoder hi/lo weights (RB, y2 dead) ----
  k_transpose_hilo<<<dim3(32, 80), 256, 0, stream>>>(enc1_w, e1Th, e1Tl, 2560, 1024);
  k_transpose_hilo<<<dim3(32, 32), 256, 0, stream>>>(enc2_w, e2Th, e2Tl, 1024, 1024);

  // ---- fut-ref VAE encoder (hi/lo ~fp32) + reparameterize ----
  k_mfma_gemm_hl<1><<<dim3(32, 8), 256, 0, stream>>>(fut_ref, e1Th, e1Tl, enc1_b, e1f, 1024, 2560);
  k_mfma_gemm_hl<1><<<dim3(32, 8), 256, 0, stream>>>(e1f, e2Th, e2Tl, enc2_b, e2f, 1024, 1024);
  k_gemm<0, false, float><<<dim3(64, 2), 256, 0, stream>>>(e2f, enc3_w, enc3_b, e3, 128, 1024);
  k_z<<<dim3(1024), 256, 0, stream>>>(e3, noise, z);

  // ---- expert weight transposes (RA, e1f/e2f dead) ----
  k_transpose_bf_b<<<dim3(32, 16, 16), 256, 0, stream>>>(Wg, wgT, 512, 1024);
  k_transpose_bf_b<<<dim3(32, 16, 16), 256, 0, stream>>>(Wu, wuT, 512, 1024);
  k_transpose_bf_b<<<dim3(16, 32, 16), 256, 0, stream>>>(Wd, wdT, 1024, 512);

  // ---- projection (fp32) + router ----
  k_gemm_proj<<<dim3(64, 8), 256, 0, stream>>>(cur_obs, hlat, z, proj_w, proj_b, x);
  k_gemm<0, true, float><<<dim3(64, 1), 256, 0, stream>>>(x, router_w, router_b, logitsb, 16, 512);
  k_router<<<dim3(16), 256, 0, stream>>>(logitsb, tidA, twA, posA, counts);
  k_offsets<<<dim3(1), 64, 0, stream>>>(counts, offs);
  k_build<<<dim3(64), 256, 0, stream>>>(tidA, twA, posA, offs, rowlist, wlist);
  k_split_x<<<dim3(2048), 256, 0, stream>>>(x, xh, xl, BATCH * 512 / 4);

  // ---- MoE up (A hi/lo x bf16 W) ----
  k_moe_up2<<<dim3(32, 8, 16), 256, 0, stream>>>(xh, xl, wgT, wuT, bg, bu, rowlist, counts, offs, tmoeb);

  // ---- sh/out hi/lo weights into dead wgT/wuT region; zero h2 ----
  k_transpose_hilo<<<dim3(64, 16), 256, 0, stream>>>(shg_w, shgTh, shgTl, 512, 2048);
  k_transpose_hilo<<<dim3(64, 16), 256, 0, stream>>>(shu_w, shuTh, shuTl, 512, 2048);
  k_transpose_hilo<<<dim3(16, 64), 256, 0, stream>>>(shd_w, shdTh, shdTl, 2048, 512);
  k_transpose_hilo<<<dim3(32, 16), 256, 0, stream>>>(out1_w, o1Th, o1Tl, 512, 1024);
  k_transpose_hilo<<<dim3(32, 32), 256, 0, stream>>>(out2_w, o2Th, o2Tl, 1024, 1024);
  k_zero_f4<<<dim3(2048), 256, 0, stream>>>((float4*)h2, BATCH * 512 / 4);

  // ---- MoE down (atomic scatter into h2; wdT still alive) ----
  k_moe_down_mfma<<<dim3(32, 4, 16), 256, 0, stream>>>(tmoeb, wdT, bd, rowlist, wlist, counts, offs, h2);

  // ---- shared experts (full hi/lo dual; stb in dead t_moe region) ----
  k_mfma_dual_hl<<<dim3(32, 16), 256, 0, stream>>>(x, shgTh, shgTl, shuTh, shuTl, shg_b, shu_b, stb, 2048, 512);
  k_mfma_gemm_bhl<<<dim3(32, 4), 256, 0, stream>>>(stb, shdTh, shdTl, shd_b, h2, 512, 2048, 2048);

  // ---- output MLP (hi/lo, ~fp32) + head (fp32) ----
  k_mfma_gemm_hl<1><<<dim3(32, 8), 256, 0, stream>>>(h2, o1Th, o1Tl, out1_b, o1, 1024, 512);
  k_mfma_gemm_hl<0><<<dim3(32, 8), 256, 0, stream>>>(o1, o2Th, o2Tl, out2_b, o2, 1024, 1024);
  k_gemm<0, true, float><<<dim3(64, 1), 256, 0, stream>>>(o2, head_w, head_b, (float*)d_out, 23, 1024);
}

// Round 7
// 1372.485 us; speedup vs baseline: 3.6083x; 1.2983x over previous
//
#include <hip/hip_runtime.h>
#include <hip/hip_bf16.h>

// ============================================================================
// EstVAEStudent forward, round 7: round 6 (gll staging + XCD swizzle) with the
// LDS DMA addressing fixed: each global_load_lds call covers 512 u16 (1024 B);
// wave region per tensor tile = wid*1024 u16, call i at +i*512.
// ============================================================================

#define BATCH 4096
typedef unsigned short u16;
typedef unsigned int u32;
using bf16x8 = __attribute__((ext_vector_type(8))) __bf16;
using f32x4  = __attribute__((ext_vector_type(4))) float;

__device__ __forceinline__ float silu_f(float v) { return v / (1.f + __expf(-v)); }

__device__ __forceinline__ float b2f(u16 u) {
  union { u32 i; float f; } c; c.i = ((u32)u) << 16; return c.f;
}
__device__ __forceinline__ u16 f2b(float f) {
  union { float f; u32 i; } c; c.f = f;
  u32 r = c.i + 0x7FFFu + ((c.i >> 16) & 1u);
  return (u16)(r >> 16);
}
__device__ __forceinline__ float4 ld4(const float* p) { return *(const float4*)p; }
__device__ __forceinline__ float4 ld4(const u16* p) {
  ushort4 v = *(const ushort4*)p;
  return make_float4(b2f(v.x), b2f(v.y), b2f(v.z), b2f(v.w));
}

// global_load_lds, 16B per lane, wave-uniform LDS base (lane l -> base+l*16B).
__device__ __forceinline__ void gll16(const u16* g, u16* l) {
  __attribute__((address_space(3))) u32* lp =
      reinterpret_cast<__attribute__((address_space(3))) u32*>(
          reinterpret_cast<uintptr_t>(l));
  __builtin_amdgcn_global_load_lds(reinterpret_cast<const u32*>(g), lp, 16, 0, 0);
}

union U8 { uint4 u; bf16x8 b; };

// ---------------- workspace layout (BYTE offsets) ----------------
static constexpr size_t WT1T_B = 0;               // 256x288 bf16
static constexpr size_t WT2T_B = 147456;          // 512x768
static constexpr size_t WT3T_B = 933888;          // 1024x1536
static constexpr size_t HL1T_B = 4079616;         // 1024x1024 -> ends 6176768
static constexpr size_t RA_B   = 6176768;         // 58,720,256 B
static constexpr size_t RB_B   = 64897024;        // 54,525,952 B
static constexpr size_t P_B    = 119422976;
// RA phases:
static constexpr size_t FRH_B  = RA_B;                    // fut_ref hi bf16 20,971,520
static constexpr size_t FRL_B  = RA_B + 20971520;
static constexpr size_t E1H_B  = RA_B + 41943040;         // e1 pair bf16 8,388,608 ea
static constexpr size_t E1L_B  = RA_B + 50331648;
static constexpr size_t Y1_B   = RA_B;                    // conv1 out (52,428,800)
static constexpr size_t Y3_B   = RA_B;                    // conv3 out (58,720,256)
static constexpr size_t WGT_B  = RA_B;                    // experts bf16
static constexpr size_t WUT_B  = RA_B + 16777216;
static constexpr size_t WDT_B  = RA_B + 33554432;
static constexpr size_t X_B    = RA_B + 50331648;         // x f32 8,388,608
static constexpr size_t SHGTH_B = RA_B;                   // after moe_up (wg/wu dead)
static constexpr size_t SHGTL_B = RA_B + 2097152;
static constexpr size_t SHUTH_B = RA_B + 4194304;
static constexpr size_t SHUTL_B = RA_B + 6291456;
static constexpr size_t SHDTH_B = RA_B + 8388608;
static constexpr size_t SHDTL_B = RA_B + 10485760;
static constexpr size_t O1TH_B  = RA_B + 12582912;
static constexpr size_t O1TL_B  = RA_B + 13631488;
static constexpr size_t O2TH_B  = RA_B + 14680064;
static constexpr size_t O2TL_B  = RA_B + 16777216;        // ends RA+18,874,368
static constexpr size_t H2_B    = RA_B + 25165824;        // f32 8,388,608
static constexpr size_t H2H_B   = RA_B + 33554432;        // pair bf16 (wdT dead)
static constexpr size_t H2L_B   = RA_B + 37748736;
// RB phases:
static constexpr size_t E1TH_B = RB_B;                    // enc1 WT pair 5,242,880 ea
static constexpr size_t E1TL_B = RB_B + 5242880;
static constexpr size_t E2TH_B = RB_B + 10485760;         // enc2 WT pair 2,097,152 ea
static constexpr size_t E2TL_B = RB_B + 12582912;
static constexpr size_t E2F_B  = RB_B + 14680064;         // e2 f32 16,777,216
static constexpr size_t HSB_B  = RB_B;                    // hist_seq bf16 19,660,800
static constexpr size_t Y2_B   = RB_B;                    // conv2 out 54,525,952
static constexpr size_t HB_B   = RB_B;                    // hb bf16 8,388,608
static constexpr size_t HI1_B  = RB_B + 8388608;          // hi1b bf16 8,388,608
static constexpr size_t XH_B   = RB_B;                    // x pair bf16 4,194,304 ea
static constexpr size_t XL_B   = RB_B + 4194304;
static constexpr size_t TM_B   = RB_B + 8388608;          // t_moe bf16 33,554,432
static constexpr size_t STB_B  = RB_B + 8388608;          // stb bf16 16,777,216 (tm dead)
static constexpr size_t O1H_B  = RB_B;                    // o1 pair (xh/xl dead)
static constexpr size_t O1L_B  = RB_B + 8388608;
static constexpr size_t O2F_B  = RB_B + 16777216;         // o2 f32 16,777,216
// P smalls:
static constexpr size_t HLAT_B = P_B;
static constexpr size_t E3P_B  = P_B + 1048576;
static constexpr size_t Z_B    = P_B + 3145728;
static constexpr size_t LOG_B  = P_B + 4194304;
static constexpr size_t TID_B  = P_B + 4456448;
static constexpr size_t TW_B   = P_B + 4521984;
static constexpr size_t POS_B  = P_B + 4587520;
static constexpr size_t CNT_B  = P_B + 4653056;
static constexpr size_t OFS_B  = P_B + 4653184;
static constexpr size_t ROWL_B = P_B + 4653312;
static constexpr size_t WL_B   = P_B + 4718848;
static constexpr size_t ZP_B   = P_B + 4784384;           // 4096 B zero page

// ---------------- prep kernels ----------------
__global__ void k_zero_i(int* __restrict__ p, int n) {
  int i = blockIdx.x * 64 + threadIdx.x;
  if (i < n) p[i] = 0;
}
__global__ void k_zero_f4(float4* __restrict__ p, int n4) {
  int i = blockIdx.x * 256 + threadIdx.x;
  if (i < n4) p[i] = make_float4(0.f, 0.f, 0.f, 0.f);
}
__global__ void k_f32_to_bf4(const float* __restrict__ s, u16* __restrict__ d, int n4) {
  int i = blockIdx.x * 256 + threadIdx.x;
  if (i >= n4) return;
  float4 v = *(const float4*)(s + (size_t)i * 4);
  *(ushort4*)(d + (size_t)i * 4) = make_ushort4(f2b(v.x), f2b(v.y), f2b(v.z), f2b(v.w));
}
// f32 -> (hi, lo) bf16 pair
__global__ void k_split_x(const float* __restrict__ s, u16* __restrict__ dh,
                          u16* __restrict__ dl, int n4) {
  int i = blockIdx.x * 256 + threadIdx.x;
  if (i >= n4) return;
  float4 v = *(const float4*)(s + (size_t)i * 4);
  float a[4] = {v.x, v.y, v.z, v.w};
  ushort4 h, l;
  u16* hp = (u16*)&h; u16* lp = (u16*)&l;
#pragma unroll
  for (int j = 0; j < 4; ++j) {
    u16 hh = f2b(a[j]);
    hp[j] = hh;
    lp[j] = f2b(a[j] - b2f(hh));
  }
  *(ushort4*)(dh + (size_t)i * 4) = h;
  *(ushort4*)(dl + (size_t)i * 4) = l;
}
// conv weight: [O][I][3] fp32 -> WT[o][k*CIN+i] bf16
__global__ void k_wt_conv(const float* __restrict__ w, u16* __restrict__ wt,
                          int CIN, int COUT) {
  int idx = blockIdx.x * 256 + threadIdx.x;
  int Kc = CIN * 3;
  if (idx >= COUT * Kc) return;
  int o = idx / Kc, c = idx - o * Kc;
  int k = c / CIN, i = c - k * CIN;
  wt[idx] = f2b(w[(size_t)o * Kc + i * 3 + k]);
}
// dense weight: W[K][N] fp32 -> WT[N][K] bf16
__global__ __launch_bounds__(256) void k_transpose_bf(const float* __restrict__ W,
                                                      u16* __restrict__ WT,
                                                      int K, int N) {
  __shared__ float t[32][33];
  int n0 = blockIdx.x * 32, k0 = blockIdx.y * 32;
  int lx = threadIdx.x & 31, ly = threadIdx.x >> 5;
#pragma unroll
  for (int r = 0; r < 32; r += 8)
    t[ly + r][lx] = W[(size_t)(k0 + ly + r) * N + n0 + lx];
  __syncthreads();
#pragma unroll
  for (int r = 0; r < 32; r += 8)
    WT[(size_t)(n0 + ly + r) * K + k0 + lx] = f2b(t[lx][ly + r]);
}
// batched per-expert transpose
__global__ __launch_bounds__(256) void k_transpose_bf_b(const float* __restrict__ W,
                                                        u16* __restrict__ WT,
                                                        int K, int N) {
  const size_t eo = (size_t)blockIdx.z * K * N;
  __shared__ float t[32][33];
  int n0 = blockIdx.x * 32, k0 = blockIdx.y * 32;
  int lx = threadIdx.x & 31, ly = threadIdx.x >> 5;
#pragma unroll
  for (int r = 0; r < 32; r += 8)
    t[ly + r][lx] = W[eo + (size_t)(k0 + ly + r) * N + n0 + lx];
  __syncthreads();
#pragma unroll
  for (int r = 0; r < 32; r += 8)
    WT[eo + (size_t)(n0 + ly + r) * K + k0 + lx] = f2b(t[lx][ly + r]);
}
// hi/lo split transpose
__global__ __launch_bounds__(256) void k_transpose_hilo(const float* __restrict__ W,
                                                        u16* __restrict__ WTh,
                                                        u16* __restrict__ WTl,
                                                        int K, int N) {
  __shared__ float t[32][33];
  int n0 = blockIdx.x * 32, k0 = blockIdx.y * 32;
  int lx = threadIdx.x & 31, ly = threadIdx.x >> 5;
#pragma unroll
  for (int r = 0; r < 32; r += 8)
    t[ly + r][lx] = W[(size_t)(k0 + ly + r) * N + n0 + lx];
  __syncthreads();
#pragma unroll
  for (int r = 0; r < 32; r += 8) {
    float f = t[lx][ly + r];
    u16 h = f2b(f);
    size_t o = (size_t)(n0 + ly + r) * K + k0 + lx;
    WTh[o] = h;
    WTl[o] = f2b(f - b2f(h));
  }
}

// ============================================================================
// gll GEMM cores: 128x128 tile, BK=32, 4 waves (2x2 of 64x64), 16x16x32 bf16.
// LDS layout per tensor tile: 4096 u16; wave wid covers rows [wid*32, wid*32+32)
// at u16 offset wid*1024; call i (16 rows) at +i*512. Source pre-swizzled
// slot^(row&3); reader applies the same XOR.
// ============================================================================
#define PRO128 \
  const int tid = threadIdx.x; \
  const int lane = tid & 63; \
  const int wid = tid >> 6; \
  const int wr = (wid >> 1) * 64, wc = (wid & 1) * 64; \
  const int l15 = lane & 15, lsub = lane >> 4;

#define MFMA_BF16(a, b, c) __builtin_amdgcn_mfma_f32_16x16x32_bf16(a, b, c, 0, 0, 0)

// generic GEMM: AP/BP = number of hi/lo parts of A/B (1 or 2); 3-term when 2x2.
// EPI: 0 f32 store, 1 bf16 store, 2 f32 +=, 3 bf16 pair store.
template<int ACT, int EPI, int AP, int BP>
__global__ __launch_bounds__(256) void k_gg(
    const u16* __restrict__ A0, const u16* __restrict__ A1,
    const u16* __restrict__ B0, const u16* __restrict__ B1,
    const float* __restrict__ bias,
    float* __restrict__ Cf, u16* __restrict__ Ch, u16* __restrict__ Cl,
    int N, int K, int lda, int ldb) {
  constexpr int NT = AP + BP;
  __shared__ u16 lds[NT * 4096];
  PRO128
  const int m0 = blockIdx.x * 128, n0 = blockIdx.y * 128;
  // per-lane staging sources (call 1 = call 0 + 16 rows; row&3 unchanged)
  const int r0 = wid * 32 + (lane >> 2);
  const int sl = ((lane & 3) ^ (r0 & 3)) * 8;
  const u16* sA0 = A0 + (size_t)(m0 + r0) * lda + sl;
  const u16* sA1 = (AP == 2) ? A1 + (size_t)(m0 + r0) * lda + sl : nullptr;
  const u16* sB0 = B0 + (size_t)(n0 + r0) * ldb + sl;
  const u16* sB1 = (BP == 2) ? B1 + (size_t)(n0 + r0) * ldb + sl : nullptr;
  const size_t stepA = (size_t)16 * lda, stepB = (size_t)16 * ldb;
  const int wb = wid * 1024;

  f32x4 acc[4][4];
  const f32x4 zf = {0.f, 0.f, 0.f, 0.f};
#pragma unroll
  for (int i = 0; i < 4; ++i)
#pragma unroll
    for (int j = 0; j < 4; ++j) acc[i][j] = zf;

  for (int k0 = 0; k0 < K; k0 += 32) {
    {
      int t = 0;
      gll16(sA0 + k0, &lds[t * 4096 + wb]);
      gll16(sA0 + stepA + k0, &lds[t * 4096 + wb + 512]);
      ++t;
      if (AP == 2) {
        gll16(sA1 + k0, &lds[t * 4096 + wb]);
        gll16(sA1 + stepA + k0, &lds[t * 4096 + wb + 512]);
        ++t;
      }
      gll16(sB0 + k0, &lds[t * 4096 + wb]);
      gll16(sB0 + stepB + k0, &lds[t * 4096 + wb + 512]);
      ++t;
      if (BP == 2) {
        gll16(sB1 + k0, &lds[t * 4096 + wb]);
        gll16(sB1 + stepB + k0, &lds[t * 4096 + wb + 512]);
      }
    }
    __syncthreads();
    U8 fah[4], fal[4];
#pragma unroll
    for (int i = 0; i < 4; ++i) {
      int ra = wr + i * 16 + l15;
      int ao = ra * 32 + ((lsub ^ (ra & 3))) * 8;
      fah[i].u = *(const uint4*)&lds[ao];
      if (AP == 2) fal[i].u = *(const uint4*)&lds[4096 + ao];
    }
#pragma unroll
    for (int ni = 0; ni < 4; ++ni) {
      int rb = wc + ni * 16 + l15;
      int bo = AP * 4096 + rb * 32 + ((lsub ^ (rb & 3))) * 8;
      U8 fbh, fbl;
      fbh.u = *(const uint4*)&lds[bo];
      if (BP == 2) fbl.u = *(const uint4*)&lds[4096 + bo];
#pragma unroll
      for (int mi = 0; mi < 4; ++mi) {
        acc[mi][ni] = MFMA_BF16(fah[mi].b, fbh.b, acc[mi][ni]);
        if (BP == 2) acc[mi][ni] = MFMA_BF16(fah[mi].b, fbl.b, acc[mi][ni]);
        if (AP == 2) acc[mi][ni] = MFMA_BF16(fal[mi].b, fbh.b, acc[mi][ni]);
      }
    }
    __syncthreads();
  }
  const int row4 = lsub * 4;
#pragma unroll
  for (int mi = 0; mi < 4; ++mi)
#pragma unroll
    for (int ni = 0; ni < 4; ++ni) {
      int col = n0 + wc + ni * 16 + l15;
      float bv = bias[col];
#pragma unroll
      for (int j = 0; j < 4; ++j) {
        int row = m0 + wr + mi * 16 + row4 + j;
        float v = acc[mi][ni][j] + bv;
        if (ACT) v = silu_f(v);
        if (EPI == 0) Cf[(size_t)row * N + col] = v;
        else if (EPI == 1) Ch[(size_t)row * N + col] = f2b(v);
        else if (EPI == 2) Cf[(size_t)row * N + col] += v;
        else {
          u16 vh = f2b(v);
          Ch[(size_t)row * N + col] = vh;
          Cl[(size_t)row * N + col] = f2b(v - b2f(vh));
        }
      }
    }
}

// dual hi/lo GEMM: C bf16 = silu(Apair@Gpair + bg) * (Apair@Upair + bu)
__global__ __launch_bounds__(256) void k_gdual(
    const u16* __restrict__ A0, const u16* __restrict__ A1,
    const u16* __restrict__ G0, const u16* __restrict__ G1,
    const u16* __restrict__ U0, const u16* __restrict__ U1,
    const float* __restrict__ bg, const float* __restrict__ bu,
    u16* __restrict__ C, int N, int K, int lda, int ldb) {
  __shared__ u16 lds[6 * 4096];
  PRO128
  const int m0 = blockIdx.x * 128, n0 = blockIdx.y * 128;
  const int r0 = wid * 32 + (lane >> 2);
  const int sl = ((lane & 3) ^ (r0 & 3)) * 8;
  const u16* s[6];
  s[0] = A0 + (size_t)(m0 + r0) * lda + sl;
  s[1] = A1 + (size_t)(m0 + r0) * lda + sl;
  s[2] = G0 + (size_t)(n0 + r0) * ldb + sl;
  s[3] = G1 + (size_t)(n0 + r0) * ldb + sl;
  s[4] = U0 + (size_t)(n0 + r0) * ldb + sl;
  s[5] = U1 + (size_t)(n0 + r0) * ldb + sl;
  const size_t stp[6] = {(size_t)16*lda, (size_t)16*lda, (size_t)16*ldb,
                         (size_t)16*ldb, (size_t)16*ldb, (size_t)16*ldb};
  const int wb = wid * 1024;
  f32x4 ag[4][4], au[4][4];
  const f32x4 zf = {0.f, 0.f, 0.f, 0.f};
#pragma unroll
  for (int i = 0; i < 4; ++i)
#pragma unroll
    for (int j = 0; j < 4; ++j) { ag[i][j] = zf; au[i][j] = zf; }

  for (int k0 = 0; k0 < K; k0 += 32) {
#pragma unroll
    for (int t = 0; t < 6; ++t) {
      gll16(s[t] + k0, &lds[t * 4096 + wb]);
      gll16(s[t] + stp[t] + k0, &lds[t * 4096 + wb + 512]);
    }
    __syncthreads();
    U8 fah[4], fal[4];
#pragma unroll
    for (int i = 0; i < 4; ++i) {
      int ra = wr + i * 16 + l15;
      int ao = ra * 32 + ((lsub ^ (ra & 3))) * 8;
      fah[i].u = *(const uint4*)&lds[ao];
      fal[i].u = *(const uint4*)&lds[4096 + ao];
    }
#pragma unroll
    for (int ni = 0; ni < 4; ++ni) {
      int rb = wc + ni * 16 + l15;
      int bo = rb * 32 + ((lsub ^ (rb & 3))) * 8;
      U8 gh, gl, uh, ul;
      gh.u = *(const uint4*)&lds[2 * 4096 + bo];
      gl.u = *(const uint4*)&lds[3 * 4096 + bo];
      uh.u = *(const uint4*)&lds[4 * 4096 + bo];
      ul.u = *(const uint4*)&lds[5 * 4096 + bo];
#pragma unroll
      for (int mi = 0; mi < 4; ++mi) {
        ag[mi][ni] = MFMA_BF16(fah[mi].b, gh.b, ag[mi][ni]);
        ag[mi][ni] = MFMA_BF16(fah[mi].b, gl.b, ag[mi][ni]);
        ag[mi][ni] = MFMA_BF16(fal[mi].b, gh.b, ag[mi][ni]);
        au[mi][ni] = MFMA_BF16(fah[mi].b, uh.b, au[mi][ni]);
        au[mi][ni] = MFMA_BF16(fah[mi].b, ul.b, au[mi][ni]);
        au[mi][ni] = MFMA_BF16(fal[mi].b, uh.b, au[mi][ni]);
      }
    }
    __syncthreads();
  }
  const int row4 = lsub * 4;
#pragma unroll
  for (int mi = 0; mi < 4; ++mi)
#pragma unroll
    for (int ni = 0; ni < 4; ++ni) {
      int col = n0 + wc + ni * 16 + l15;
      float bgv = bg[col], buv = bu[col];
#pragma unroll
      for (int j = 0; j < 4; ++j) {
        int row = m0 + wr + mi * 16 + row4 + j;
        float v = silu_f(ag[mi][ni][j] + bgv) * (au[mi][ni][j] + buv);
        C[(size_t)row * N + col] = f2b(v);
      }
    }
}

// conv as implicit-im2col gll GEMM; zero-page for pad/OOB.
template<int CIN, int TIN, int TOUT, int STRIDE>
__global__ __launch_bounds__(256) void k_gconv(
    const u16* __restrict__ X, const u16* __restrict__ WT,
    const float* __restrict__ bias, u16* __restrict__ Y,
    const u16* __restrict__ zp, int COUT) {
  constexpr int K = CIN * 3;
  __shared__ u16 lds[2 * 4096];
  PRO128
  const int m0 = blockIdx.x * 128, n0 = blockIdx.y * 128;
  int bA_[2], tb_[2], sl_[2];
  const u16* sB[2];
#pragma unroll
  for (int i = 0; i < 2; ++i) {
    int r = wid * 32 + i * 16 + (lane >> 2);
    int sl = ((lane & 3) ^ (r & 3)) * 8;
    sl_[i] = sl;
    int m = m0 + r;
    int bb = m / TOUT;
    int tt = m - bb * TOUT;
    bA_[i] = bb;
    tb_[i] = tt * STRIDE - 1;
    sB[i] = WT + (size_t)(n0 + r) * K + sl;
  }
  const int wb = wid * 1024;
  f32x4 acc[4][4];
  const f32x4 zf = {0.f, 0.f, 0.f, 0.f};
#pragma unroll
  for (int i = 0; i < 4; ++i)
#pragma unroll
    for (int j = 0; j < 4; ++j) acc[i][j] = zf;

  for (int k0 = 0; k0 < K; k0 += 32) {
#pragma unroll
    for (int i = 0; i < 2; ++i) {
      int kk = k0 + sl_[i];
      int ker = kk / CIN;
      int i0 = kk - ker * CIN;
      int tin = tb_[i] + ker;
      const u16* sa = (tin >= 0 && tin < TIN)
          ? X + ((size_t)bA_[i] * TIN + tin) * CIN + i0 : zp;
      gll16(sa, &lds[wb + i * 512]);
      gll16(sB[i] + k0, &lds[4096 + wb + i * 512]);
    }
    __syncthreads();
    U8 fa[4], fb[4];
#pragma unroll
    for (int i = 0; i < 4; ++i) {
      int ra = wr + i * 16 + l15;
      fa[i].u = *(const uint4*)&lds[ra * 32 + ((lsub ^ (ra & 3))) * 8];
      int rb = wc + i * 16 + l15;
      fb[i].u = *(const uint4*)&lds[4096 + rb * 32 + ((lsub ^ (rb & 3))) * 8];
    }
#pragma unroll
    for (int mi = 0; mi < 4; ++mi)
#pragma unroll
      for (int ni = 0; ni < 4; ++ni)
        acc[mi][ni] = MFMA_BF16(fa[mi].b, fb[ni].b, acc[mi][ni]);
    __syncthreads();
  }
  const int row4 = lsub * 4;
#pragma unroll
  for (int mi = 0; mi < 4; ++mi)
#pragma unroll
    for (int ni = 0; ni < 4; ++ni) {
      int col = n0 + wc + ni * 16 + l15;
      float bv = bias[col];
#pragma unroll
      for (int j = 0; j < 4; ++j) {
        int row = m0 + wr + mi * 16 + row4 + j;
        Y[(size_t)row * COUT + col] = f2b(silu_f(acc[mi][ni][j] + bv));
      }
    }
}

// MoE up: expert->XCD swizzled 1D grid; gathered A pair x bf16 W (dual).
__global__ __launch_bounds__(256) void k_gmoeup(
    const u16* __restrict__ xh, const u16* __restrict__ xl,
    const u16* __restrict__ WgT, const u16* __restrict__ WuT,
    const float* __restrict__ bg, const float* __restrict__ bu,
    const int* __restrict__ rowlist, const int* __restrict__ counts,
    const int* __restrict__ offs, const u16* __restrict__ zp,
    u16* __restrict__ t_moe) {
  const int bid = blockIdx.x;
  const int xcd = bid & 7, sidx = bid >> 3;
  const int eo = sidx >> 8, r2 = sidx & 255;
  const int mt = r2 >> 3, nt = r2 & 7;
  const int e = xcd + 8 * eo;
  const int ne = counts[e];
  const int m0 = mt * 128;
  if (m0 >= ne) return;
  const int n0 = nt * 128;
  const int base = offs[e];
  constexpr int K = 512, N = 1024;
  const u16* Wge = WgT + (size_t)e * N * K;
  const u16* Wue = WuT + (size_t)e * N * K;
  const float* bge = bg + (size_t)e * N;
  const float* bue = bu + (size_t)e * N;
  __shared__ u16 lds[4 * 4096];
  PRO128
  const u16* sAh[2]; const u16* sAl[2]; const u16* sG[2]; const u16* sU[2];
#pragma unroll
  for (int i = 0; i < 2; ++i) {
    int r = wid * 32 + i * 16 + (lane >> 2);
    int sl = ((lane & 3) ^ (r & 3)) * 8;
    int grow = m0 + r;
    int xr = (grow < ne) ? rowlist[base + grow] : -1;
    sAh[i] = (xr >= 0) ? xh + (size_t)xr * K + sl : zp;
    sAl[i] = (xr >= 0) ? xl + (size_t)xr * K + sl : zp;
    sG[i] = Wge + (size_t)(n0 + r) * K + sl;
    sU[i] = Wue + (size_t)(n0 + r) * K + sl;
  }
  const int wb = wid * 1024;
  f32x4 ag[4][4], au[4][4];
  const f32x4 zf = {0.f, 0.f, 0.f, 0.f};
#pragma unroll
  for (int i = 0; i < 4; ++i)
#pragma unroll
    for (int j = 0; j < 4; ++j) { ag[i][j] = zf; au[i][j] = zf; }

  for (int k0 = 0; k0 < K; k0 += 32) {
#pragma unroll
    for (int i = 0; i < 2; ++i) {
      gll16(sAh[i] + k0, &lds[0 * 4096 + wb + i * 512]);
      gll16(sAl[i] + k0, &lds[1 * 4096 + wb + i * 512]);
      gll16(sG[i] + k0, &lds[2 * 4096 + wb + i * 512]);
      gll16(sU[i] + k0, &lds[3 * 4096 + wb + i * 512]);
    }
    __syncthreads();
    U8 fah[4], fal[4];
#pragma unroll
    for (int i = 0; i < 4; ++i) {
      int ra = wr + i * 16 + l15;
      int ao = ra * 32 + ((lsub ^ (ra & 3))) * 8;
      fah[i].u = *(const uint4*)&lds[ao];
      fal[i].u = *(const uint4*)&lds[4096 + ao];
    }
#pragma unroll
    for (int ni = 0; ni < 4; ++ni) {
      int rb = wc + ni * 16 + l15;
      int bo = rb * 32 + ((lsub ^ (rb & 3))) * 8;
      U8 fg, fu;
      fg.u = *(const uint4*)&lds[2 * 4096 + bo];
      fu.u = *(const uint4*)&lds[3 * 4096 + bo];
#pragma unroll
      for (int mi = 0; mi < 4; ++mi) {
        ag[mi][ni] = MFMA_BF16(fah[mi].b, fg.b, ag[mi][ni]);
        ag[mi][ni] = MFMA_BF16(fal[mi].b, fg.b, ag[mi][ni]);
        au[mi][ni] = MFMA_BF16(fah[mi].b, fu.b, au[mi][ni]);
        au[mi][ni] = MFMA_BF16(fal[mi].b, fu.b, au[mi][ni]);
      }
    }
    __syncthreads();
  }
  const int row4 = lsub * 4;
#pragma unroll
  for (int mi = 0; mi < 4; ++mi)
#pragma unroll
    for (int ni = 0; ni < 4; ++ni) {
      int col = n0 + wc + ni * 16 + l15;
      float bgv = bge[col], buv = bue[col];
#pragma unroll
      for (int j = 0; j < 4; ++j) {
        int row = m0 + wr + mi * 16 + row4 + j;
        if (row >= ne) continue;
        float v = silu_f(ag[mi][ni][j] + bgv) * (au[mi][ni][j] + buv);
        t_moe[(size_t)(base + row) * N + col] = f2b(v);
      }
    }
}

// MoE down: expert->XCD swizzled; t_moe x WdT -> weighted atomic scatter.
__global__ __launch_bounds__(256) void k_gmoedown(
    const u16* __restrict__ t_moe, const u16* __restrict__ WdT,
    const float* __restrict__ bd, const int* __restrict__ rowlist,
    const float* __restrict__ wlist, const int* __restrict__ counts,
    const int* __restrict__ offs, const u16* __restrict__ zp,
    float* __restrict__ h2) {
  const int bid = blockIdx.x;
  const int xcd = bid & 7, sidx = bid >> 3;
  const int eo = sidx >> 7, r2 = sidx & 127;
  const int mt = r2 >> 2, nt = r2 & 3;
  const int e = xcd + 8 * eo;
  const int ne = counts[e];
  const int m0 = mt * 128;
  if (m0 >= ne) return;
  const int n0 = nt * 128;
  const int base = offs[e];
  constexpr int K = 1024, N = 512;
  const u16* Wde = WdT + (size_t)e * N * K;
  const float* bde = bd + (size_t)e * N;
  __shared__ u16 lds[2 * 4096];
  PRO128
  const u16* sA[2]; const u16* sB[2];
#pragma unroll
  for (int i = 0; i < 2; ++i) {
    int r = wid * 32 + i * 16 + (lane >> 2);
    int sl = ((lane & 3) ^ (r & 3)) * 8;
    sA[i] = (m0 + r < ne) ? t_moe + (size_t)(base + m0 + r) * K + sl : zp;
    sB[i] = Wde + (size_t)(n0 + r) * K + sl;
  }
  const int wb = wid * 1024;
  f32x4 acc[4][4];
  const f32x4 zf = {0.f, 0.f, 0.f, 0.f};
#pragma unroll
  for (int i = 0; i < 4; ++i)
#pragma unroll
    for (int j = 0; j < 4; ++j) acc[i][j] = zf;

  for (int k0 = 0; k0 < K; k0 += 32) {
#pragma unroll
    for (int i = 0; i < 2; ++i) {
      gll16(sA[i] + k0, &lds[wb + i * 512]);
      gll16(sB[i] + k0, &lds[4096 + wb + i * 512]);
    }
    __syncthreads();
    U8 fa[4], fb[4];
#pragma unroll
    for (int i = 0; i < 4; ++i) {
      int ra = wr + i * 16 + l15;
      fa[i].u = *(const uint4*)&lds[ra * 32 + ((lsub ^ (ra & 3))) * 8];
      int rb = wc + i * 16 + l15;
      fb[i].u = *(const uint4*)&lds[4096 + rb * 32 + ((lsub ^ (rb & 3))) * 8];
    }
#pragma unroll
    for (int mi = 0; mi < 4; ++mi)
#pragma unroll
      for (int ni = 0; ni < 4; ++ni)
        acc[mi][ni] = MFMA_BF16(fa[mi].b, fb[ni].b, acc[mi][ni]);
    __syncthreads();
  }
  const int row4 = lsub * 4;
#pragma unroll
  for (int mi = 0; mi < 4; ++mi)
#pragma unroll
    for (int j = 0; j < 4; ++j) {
      int row = m0 + wr + mi * 16 + row4 + j;
      if (row >= ne) continue;
      int r = rowlist[base + row];
      float wl = wlist[base + row];
#pragma unroll
      for (int ni = 0; ni < 4; ++ni) {
        int col = n0 + wc + ni * 16 + l15;
        atomicAdd(&h2[(size_t)r * 512 + col], wl * (acc[mi][ni][j] + bde[col]));
      }
    }
}

// ---------------- fp32 64x64 GEMM (hlin2 / enc3 / router / head) ----------------
template<int ACT, bool NG, typename TA>
__global__ __launch_bounds__(256) void k_gemm(const TA* __restrict__ A,
                                              const float* __restrict__ W,
                                              const float* __restrict__ bias,
                                              float* __restrict__ C,
                                              int N, int K) {
  __shared__ float As[16][64];
  __shared__ float Bs[16][64];
  const int tid = threadIdx.x;
  const int m0 = blockIdx.x * 64;
  const int n0 = blockIdx.y * 64;
  const int tr = tid >> 4, tc = tid & 15;
  const int lm = tid >> 2, lk = (tid & 3) * 4;
  const int ln = tid & 63, lkb = (tid >> 6) * 4;
  float acc[4][4] = {};
  for (int k0 = 0; k0 < K; k0 += 16) {
    float4 av = ld4(A + (size_t)(m0 + lm) * K + k0 + lk);
    As[lk + 0][lm] = av.x; As[lk + 1][lm] = av.y;
    As[lk + 2][lm] = av.z; As[lk + 3][lm] = av.w;
#pragma unroll
    for (int s = 0; s < 4; ++s) {
      int kk = lkb + s;
      float v = 0.f;
      if (!NG || (n0 + ln) < N) v = W[(size_t)(k0 + kk) * N + n0 + ln];
      Bs[kk][ln] = v;
    }
    __syncthreads();
#pragma unroll
    for (int kk = 0; kk < 16; ++kk) {
      float4 a4 = *(const float4*)&As[kk][tr * 4];
      float4 b4 = *(const float4*)&Bs[kk][tc * 4];
      float a[4] = {a4.x, a4.y, a4.z, a4.w};
      float b[4] = {b4.x, b4.y, b4.z, b4.w};
#pragma unroll
      for (int i = 0; i < 4; ++i)
#pragma unroll
        for (int j = 0; j < 4; ++j) acc[i][j] = fmaf(a[i], b[j], acc[i][j]);
    }
    __syncthreads();
  }
#pragma unroll
  for (int i = 0; i < 4; ++i) {
    int m = m0 + tr * 4 + i;
#pragma unroll
    for (int j = 0; j < 4; ++j) {
      int n = n0 + tc * 4 + j;
      if (NG && n >= N) continue;
      float v = acc[i][j] + bias[n];
      if (ACT == 1) v = silu_f(v);
      C[(size_t)m * N + n] = v;
    }
  }
}

// concat projection GEMM (fp32, routing-safe)
__global__ __launch_bounds__(256) void k_gemm_proj(const float* __restrict__ obs,
                                                   const float* __restrict__ hl,
                                                   const float* __restrict__ z,
                                                   const float* __restrict__ W,
                                                   const float* __restrict__ bias,
                                                   float* __restrict__ C) {
  const int N = 512, K = 384;
  __shared__ float As[16][64];
  __shared__ float Bs[16][64];
  const int tid = threadIdx.x;
  const int m0 = blockIdx.x * 64;
  const int n0 = blockIdx.y * 64;
  const int tr = tid >> 4, tc = tid & 15;
  const int lm = tid >> 2, lk = (tid & 3) * 4;
  const int ln = tid & 63, lkb = (tid >> 6) * 4;
  const int m = m0 + lm;
  float acc[4][4] = {};
  for (int k0 = 0; k0 < K; k0 += 16) {
#pragma unroll
    for (int j = 0; j < 4; ++j) {
      int c = k0 + lk + j;
      float v;
      if (c < 256)      v = obs[(size_t)m * 256 + c];
      else if (c < 320) v = hl[(size_t)m * 64 + (c - 256)];
      else              v = z[(size_t)m * 64 + (c - 320)];
      As[lk + j][lm] = v;
    }
#pragma unroll
    for (int s = 0; s < 4; ++s) {
      int kk = lkb + s;
      Bs[kk][ln] = W[(size_t)(k0 + kk) * N + n0 + ln];
    }
    __syncthreads();
#pragma unroll
    for (int kk = 0; kk < 16; ++kk) {
      float4 a4 = *(const float4*)&As[kk][tr * 4];
      float4 b4 = *(const float4*)&Bs[kk][tc * 4];
      float a[4] = {a4.x, a4.y, a4.z, a4.w};
      float b[4] = {b4.x, b4.y, b4.z, b4.w};
#pragma unroll
      for (int i = 0; i < 4; ++i)
#pragma unroll
        for (int j = 0; j < 4; ++j) acc[i][j] = fmaf(a[i], b[j], acc[i][j]);
    }
    __syncthreads();
  }
#pragma unroll
  for (int i = 0; i < 4; ++i) {
    int mo = m0 + tr * 4 + i;
#pragma unroll
    for (int j = 0; j < 4; ++j) {
      int n = n0 + tc * 4 + j;
      C[(size_t)mo * N + n] = acc[i][j] + bias[n];
    }
  }
}

// ---------------- small elementwise / router kernels ----------------
__global__ void k_mean7(const u16* __restrict__ y3, u16* __restrict__ hb) {
  int idx = blockIdx.x * 256 + threadIdx.x;
  if (idx >= BATCH * 1024) return;
  int b = idx >> 10, o = idx & 1023;
  const u16* p = y3 + (size_t)b * 7 * 1024 + o;
  float s = 0.f;
#pragma unroll
  for (int t = 0; t < 7; ++t) s += b2f(p[(size_t)t * 1024]);
  hb[idx] = f2b(s * (1.f / 7.f));
}

__global__ void k_z(const float* __restrict__ e3, const float* __restrict__ noise,
                    float* __restrict__ z) {
  int idx = blockIdx.x * 256 + threadIdx.x;
  if (idx >= BATCH * 64) return;
  int b = idx >> 6, j = idx & 63;
  float mu = e3[(size_t)b * 128 + j];
  float lv = e3[(size_t)b * 128 + 64 + j];
  z[idx] = mu + expf(0.5f * lv) * noise[idx];
}

__global__ void k_router(const float* __restrict__ logits, int* __restrict__ tidA,
                         float* __restrict__ twA, int* __restrict__ posA,
                         int* __restrict__ counts) {
  int b = blockIdx.x * 256 + threadIdx.x;
  if (b >= BATCH) return;
  float s[16];
#pragma unroll
  for (int e = 0; e < 16; ++e)
    s[e] = 1.f / (1.f + expf(-logits[(size_t)b * 16 + e]));
  float gsc[4];
#pragma unroll
  for (int g = 0; g < 4; ++g) {
    float m1 = -1e30f; int i1 = -1;
    for (int i = 0; i < 4; ++i) { float v = s[g * 4 + i]; if (v > m1) { m1 = v; i1 = i; } }
    float m2 = -1e30f;
    for (int i = 0; i < 4; ++i) { if (i == i1) continue; float v = s[g * 4 + i]; if (v > m2) m2 = v; }
    gsc[g] = m1 + m2;
  }
  int g1 = 0; float b1 = gsc[0];
  for (int g = 1; g < 4; ++g) if (gsc[g] > b1) { b1 = gsc[g]; g1 = g; }
  int g2 = -1; float b2 = -1e30f;
  for (int g = 0; g < 4; ++g) { if (g == g1) continue; if (gsc[g] > b2) { b2 = gsc[g]; g2 = g; } }
  float ms[16]; bool used[16];
#pragma unroll
  for (int e = 0; e < 16; ++e) {
    int g = e >> 2;
    ms[e] = (g == g1 || g == g2) ? s[e] : 0.f;
    used[e] = false;
  }
  int te[4]; float tv[4]; float tsum = 0.f;
  for (int t = 0; t < 4; ++t) {
    float best = -1.f; int bi = 0;
    for (int e = 0; e < 16; ++e)
      if (!used[e] && ms[e] > best) { best = ms[e]; bi = e; }
    used[bi] = true;
    te[t] = bi;
    tv[t] = s[bi];
    tsum += s[bi];
  }
  float inv = 1.f / (tsum + 1e-20f);
  for (int t = 0; t < 4; ++t) {
    int e = te[t];
    tidA[b * 4 + t] = e;
    twA[b * 4 + t] = tv[t] * inv;  // ROUTE_SCALE = 1.0
    posA[b * 4 + t] = atomicAdd(&counts[e], 1);
  }
}

__global__ void k_offsets(const int* __restrict__ counts, int* __restrict__ offs) {
  if (threadIdx.x == 0 && blockIdx.x == 0) {
    int a = 0;
    for (int e = 0; e < 16; ++e) { offs[e] = a; a += counts[e]; }
    offs[16] = a;
  }
}

__global__ void k_build(const int* __restrict__ tidA, const float* __restrict__ twA,
                        const int* __restrict__ posA, const int* __restrict__ offs,
                        int* __restrict__ rowlist, float* __restrict__ wlist) {
  int idx = blockIdx.x * 256 + threadIdx.x;
  if (idx >= BATCH * 4) return;
  int e = tidA[idx];
  int p = offs[e] + posA[idx];
  rowlist[p] = idx >> 2;
  wlist[p] = twA[idx];
}

// ============================================================================
extern "C" void kernel_launch(void* const* d_in, const int* in_sizes, int n_in,
                              void* d_out, int out_size, void* d_ws, size_t ws_size,
                              hipStream_t stream) {
  const float* cur_obs  = (const float*)d_in[0];
  const float* hist_seq = (const float*)d_in[1];
  const float* fut_ref  = (const float*)d_in[2];
  const float* noise    = (const float*)d_in[3];
  const float* conv1_w  = (const float*)d_in[4];
  const float* conv1_b  = (const float*)d_in[5];
  const float* conv2_w  = (const float*)d_in[6];
  const float* conv2_b  = (const float*)d_in[7];
  const float* conv3_w  = (const float*)d_in[8];
  const float* conv3_b  = (const float*)d_in[9];
  const float* hlin1_w  = (const float*)d_in[10];
  const float* hlin1_b  = (const float*)d_in[11];
  const float* hlin2_w  = (const float*)d_in[12];
  const float* hlin2_b  = (const float*)d_in[13];
  const float* enc1_w   = (const float*)d_in[14];
  const float* enc1_b   = (const float*)d_in[15];
  const float* enc2_w   = (const float*)d_in[16];
  const float* enc2_b   = (const float*)d_in[17];
  const float* enc3_w   = (const float*)d_in[18];
  const float* enc3_b   = (const float*)d_in[19];
  const float* proj_w   = (const float*)d_in[20];
  const float* proj_b   = (const float*)d_in[21];
  const float* router_w = (const float*)d_in[22];
  const float* router_b = (const float*)d_in[23];
  const float* Wg       = (const float*)d_in[24];
  const float* bg       = (const float*)d_in[25];
  const float* Wu       = (const float*)d_in[26];
  const float* bu       = (const float*)d_in[27];
  const float* Wd       = (const float*)d_in[28];
  const float* bd       = (const float*)d_in[29];
  const float* shg_w    = (const float*)d_in[30];
  const float* shg_b    = (const float*)d_in[31];
  const float* shu_w    = (const float*)d_in[32];
  const float* shu_b    = (const float*)d_in[33];
  const float* shd_w    = (const float*)d_in[34];
  const float* shd_b    = (const float*)d_in[35];
  const float* out1_w   = (const float*)d_in[36];
  const float* out1_b   = (const float*)d_in[37];
  const float* out2_w   = (const float*)d_in[38];
  const float* out2_b   = (const float*)d_in[39];
  const float* head_w   = (const float*)d_in[40];
  const float* head_b   = (const float*)d_in[41];
  (void)in_sizes; (void)n_in; (void)out_size; (void)ws_size;

  char* wsb = (char*)d_ws;
  u16* wt1T  = (u16*)(wsb + WT1T_B);
  u16* wt2T  = (u16*)(wsb + WT2T_B);
  u16* wt3T  = (u16*)(wsb + WT3T_B);
  u16* hl1T  = (u16*)(wsb + HL1T_B);
  u16* frh   = (u16*)(wsb + FRH_B);
  u16* frl   = (u16*)(wsb + FRL_B);
  u16* e1h   = (u16*)(wsb + E1H_B);
  u16* e1l   = (u16*)(wsb + E1L_B);
  u16* y1b   = (u16*)(wsb + Y1_B);
  u16* y2b   = (u16*)(wsb + Y2_B);
  u16* y3b   = (u16*)(wsb + Y3_B);
  u16* wgT   = (u16*)(wsb + WGT_B);
  u16* wuT   = (u16*)(wsb + WUT_B);
  u16* wdT   = (u16*)(wsb + WDT_B);
  float* x   = (float*)(wsb + X_B);
  u16* shgTh = (u16*)(wsb + SHGTH_B);
  u16* shgTl = (u16*)(wsb + SHGTL_B);
  u16* shuTh = (u16*)(wsb + SHUTH_B);
  u16* shuTl = (u16*)(wsb + SHUTL_B);
  u16* shdTh = (u16*)(wsb + SHDTH_B);
  u16* shdTl = (u16*)(wsb + SHDTL_B);
  u16* o1Th  = (u16*)(wsb + O1TH_B);
  u16* o1Tl  = (u16*)(wsb + O1TL_B);
  u16* o2Th  = (u16*)(wsb + O2TH_B);
  u16* o2Tl  = (u16*)(wsb + O2TL_B);
  float* h2  = (float*)(wsb + H2_B);
  u16* h2h   = (u16*)(wsb + H2H_B);
  u16* h2l   = (u16*)(wsb + H2L_B);
  u16* e1Th  = (u16*)(wsb + E1TH_B);
  u16* e1Tl  = (u16*)(wsb + E1TL_B);
  u16* e2Th  = (u16*)(wsb + E2TH_B);
  u16* e2Tl  = (u16*)(wsb + E2TL_B);
  float* e2f = (float*)(wsb + E2F_B);
  u16* hsb   = (u16*)(wsb + HSB_B);
  u16* hb    = (u16*)(wsb + HB_B);
  u16* hi1b  = (u16*)(wsb + HI1_B);
  u16* xh    = (u16*)(wsb + XH_B);
  u16* xl    = (u16*)(wsb + XL_B);
  u16* tmoeb = (u16*)(wsb + TM_B);
  u16* stb   = (u16*)(wsb + STB_B);
  u16* o1h   = (u16*)(wsb + O1H_B);
  u16* o1l   = (u16*)(wsb + O1L_B);
  float* o2f = (float*)(wsb + O2F_B);
  float* hlat = (float*)(wsb + HLAT_B);
  float* e3   = (float*)(wsb + E3P_B);
  float* z    = (float*)(wsb + Z_B);
  float* logitsb = (float*)(wsb + LOG_B);
  int*   tidA  = (int*)(wsb + TID_B);
  float* twA   = (float*)(wsb + TW_B);
  int*   posA  = (int*)(wsb + POS_B);
  int*   counts = (int*)(wsb + CNT_B);
  int*   offs  = (int*)(wsb + OFS_B);
  int*   rowlist = (int*)(wsb + ROWL_B);
  float* wlist = (float*)(wsb + WL_B);
  u16*   zp    = (u16*)(wsb + ZP_B);

  k_zero_i<<<dim3(1), 64, 0, stream>>>(counts, 16);
  k_zero_i<<<dim3(16), 64, 0, stream>>>((int*)zp, 1024);

  // ---- weight prep (prefix + enc pairs) ----
  k_wt_conv<<<dim3(288), 256, 0, stream>>>(conv1_w, wt1T, 96, 256);
  k_wt_conv<<<dim3(1536), 256, 0, stream>>>(conv2_w, wt2T, 256, 512);
  k_wt_conv<<<dim3(6144), 256, 0, stream>>>(conv3_w, wt3T, 512, 1024);
  k_transpose_bf<<<dim3(32, 32), 256, 0, stream>>>(hlin1_w, hl1T, 1024, 1024);
  k_transpose_hilo<<<dim3(32, 80), 256, 0, stream>>>(enc1_w, e1Th, e1Tl, 2560, 1024);
  k_transpose_hilo<<<dim3(32, 32), 256, 0, stream>>>(enc2_w, e2Th, e2Tl, 1024, 1024);

  // ---- VAE encoder (hi/lo pairs) + reparameterize ----
  k_split_x<<<dim3(10240), 256, 0, stream>>>(fut_ref, frh, frl, BATCH * 2560 / 4);
  k_gg<1, 3, 2, 2><<<dim3(32, 8), 256, 0, stream>>>(frh, frl, e1Th, e1Tl, enc1_b,
      nullptr, e1h, e1l, 1024, 2560, 2560, 2560);
  k_gg<1, 0, 2, 2><<<dim3(32, 8), 256, 0, stream>>>(e1h, e1l, e2Th, e2Tl, enc2_b,
      e2f, nullptr, nullptr, 1024, 1024, 1024, 1024);
  k_gemm<0, false, float><<<dim3(64, 2), 256, 0, stream>>>(e2f, enc3_w, enc3_b, e3, 128, 1024);
  k_z<<<dim3(1024), 256, 0, stream>>>(e3, noise, z);

  // ---- history conv encoder (gll im2col) ----
  k_f32_to_bf4<<<dim3(9600), 256, 0, stream>>>(hist_seq, hsb, BATCH * 25 * 96 / 4);
  k_gconv<96, 25, 25, 1><<<dim3(800, 2), 256, 0, stream>>>(hsb, wt1T, conv1_b, y1b, zp, 256);
  k_gconv<256, 25, 13, 2><<<dim3(416, 4), 256, 0, stream>>>(y1b, wt2T, conv2_b, y2b, zp, 512);
  k_gconv<512, 13, 7, 2><<<dim3(224, 8), 256, 0, stream>>>(y2b, wt3T, conv3_b, y3b, zp, 1024);
  k_mean7<<<dim3(16384), 256, 0, stream>>>(y3b, hb);
  k_gg<1, 1, 1, 1><<<dim3(32, 8), 256, 0, stream>>>(hb, nullptr, hl1T, nullptr, hlin1_b,
      nullptr, hi1b, nullptr, 1024, 1024, 1024, 1024);
  k_gemm<0, false, u16><<<dim3(64, 1), 256, 0, stream>>>(hi1b, hlin2_w, hlin2_b, hlat, 64, 1024);

  // ---- expert weight transposes (y3 dead) ----
  k_transpose_bf_b<<<dim3(32, 16, 16), 256, 0, stream>>>(Wg, wgT, 512, 1024);
  k_transpose_bf_b<<<dim3(32, 16, 16), 256, 0, stream>>>(Wu, wuT, 512, 1024);
  k_transpose_bf_b<<<dim3(16, 32, 16), 256, 0, stream>>>(Wd, wdT, 1024, 512);

  // ---- projection (fp32) + router ----
  k_gemm_proj<<<dim3(64, 8), 256, 0, stream>>>(cur_obs, hlat, z, proj_w, proj_b, x);
  k_gemm<0, true, float><<<dim3(64, 1), 256, 0, stream>>>(x, router_w, router_b, logitsb, 16, 512);
  k_router<<<dim3(16), 256, 0, stream>>>(logitsb, tidA, twA, posA, counts);
  k_offsets<<<dim3(1), 64, 0, stream>>>(counts, offs);
  k_build<<<dim3(64), 256, 0, stream>>>(tidA, twA, posA, offs, rowlist, wlist);
  k_split_x<<<dim3(2048), 256, 0, stream>>>(x, xh, xl, BATCH * 512 / 4);

  // ---- MoE up (expert->XCD swizzled) ----
  k_gmoeup<<<dim3(4096), 256, 0, stream>>>(xh, xl, wgT, wuT, bg, bu,
                                           rowlist, counts, offs, zp, tmoeb);

  // ---- sh/out hi/lo weights into dead wg/wu region; zero h2 ----
  k_transpose_hilo<<<dim3(64, 16), 256, 0, stream>>>(shg_w, shgTh, shgTl, 512, 2048);
  k_transpose_hilo<<<dim3(64, 16), 256, 0, stream>>>(shu_w, shuTh, shuTl, 512, 2048);
  k_transpose_hilo<<<dim3(16, 64), 256, 0, stream>>>(shd_w, shdTh, shdTl, 2048, 512);
  k_transpose_hilo<<<dim3(32, 16), 256, 0, stream>>>(out1_w, o1Th, o1Tl, 512, 1024);
  k_transpose_hilo<<<dim3(32, 32), 256, 0, stream>>>(out2_w, o2Th, o2Tl, 1024, 1024);
  k_zero_f4<<<dim3(2048), 256, 0, stream>>>((float4*)h2, BATCH * 512 / 4);

  // ---- MoE down (atomic scatter into h2) ----
  k_gmoedown<<<dim3(2048), 256, 0, stream>>>(tmoeb, wdT, bd, rowlist, wlist,
                                             counts, offs, zp, h2);

  // ---- shared experts (full hi/lo dual), += into h2 ----
  k_gdual<<<dim3(32, 16), 256, 0, stream>>>(xh, xl, shgTh, shgTl, shuTh, shuTl,
                                            shg_b, shu_b, stb, 2048, 512, 512, 512);
  k_gg<0, 2, 1, 2><<<dim3(32, 4), 256, 0, stream>>>(stb, nullptr, shdTh, shdTl, shd_b,
      h2, nullptr, nullptr, 512, 2048, 2048, 2048);

  // ---- output MLP (hi/lo) + head (fp32) ----
  k_split_x<<<dim3(2048), 256, 0, stream>>>(h2, h2h, h2l, BATCH * 512 / 4);
  k_gg<1, 3, 2, 2><<<dim3(32, 8), 256, 0, stream>>>(h2h, h2l, o1Th, o1Tl, out1_b,
      nullptr, o1h, o1l, 1024, 512, 512, 512);
  k_gg<0, 0, 2, 2><<<dim3(32, 8), 256, 0, stream>>>(o1h, o1l, o2Th, o2Tl, out2_b,
      o2f, nullptr, nullptr, 1024, 1024, 1024, 1024);
  k_gemm<0, true, float><<<dim3(64, 1), 256, 0, stream>>>(o2f, head_w, head_b, (float*)d_out, 23, 1024);
}

// Round 8
// 1324.647 us; speedup vs baseline: 3.7386x; 1.0361x over previous
//
#include <hip/hip_runtime.h>
#include <hip/hip_bf16.h>

// ============================================================================
// EstVAEStudent forward, round 8: round 7 +
//  (a) XCD-coherent 1D grid for all MFMA GEMMs: same m-panel's n-tiles land on
//      one XCD (bid%8) -> A-panel L2 reuse, FETCH drop.
//  (b) LDS slot-XOR f(row) = (row>>1)&3 (banks wrap every 2 rows of 64B) ->
//      4-way bank conflict becomes free 2-way. Bit-identical numerics.
// ============================================================================

#define BATCH 4096
typedef unsigned short u16;
typedef unsigned int u32;
using bf16x8 = __attribute__((ext_vector_type(8))) __bf16;
using f32x4  = __attribute__((ext_vector_type(4))) float;

__device__ __forceinline__ float silu_f(float v) { return v / (1.f + __expf(-v)); }

__device__ __forceinline__ float b2f(u16 u) {
  union { u32 i; float f; } c; c.i = ((u32)u) << 16; return c.f;
}
__device__ __forceinline__ u16 f2b(float f) {
  union { float f; u32 i; } c; c.f = f;
  u32 r = c.i + 0x7FFFu + ((c.i >> 16) & 1u);
  return (u16)(r >> 16);
}
__device__ __forceinline__ float4 ld4(const float* p) { return *(const float4*)p; }
__device__ __forceinline__ float4 ld4(const u16* p) {
  ushort4 v = *(const ushort4*)p;
  return make_float4(b2f(v.x), b2f(v.y), b2f(v.z), b2f(v.w));
}

// global_load_lds, 16B per lane, wave-uniform LDS base (lane l -> base+l*16B).
__device__ __forceinline__ void gll16(const u16* g, u16* l) {
  __attribute__((address_space(3))) u32* lp =
      reinterpret_cast<__attribute__((address_space(3))) u32*>(
          reinterpret_cast<uintptr_t>(l));
  __builtin_amdgcn_global_load_lds(reinterpret_cast<const u32*>(g), lp, 16, 0, 0);
}

union U8 { uint4 u; bf16x8 b; };

// ---------------- workspace layout (BYTE offsets) ----------------
static constexpr size_t WT1T_B = 0;               // 256x288 bf16
static constexpr size_t WT2T_B = 147456;          // 512x768
static constexpr size_t WT3T_B = 933888;          // 1024x1536
static constexpr size_t HL1T_B = 4079616;         // 1024x1024 -> ends 6176768
static constexpr size_t RA_B   = 6176768;         // 58,720,256 B
static constexpr size_t RB_B   = 64897024;        // 54,525,952 B
static constexpr size_t P_B    = 119422976;
// RA phases:
static constexpr size_t FRH_B  = RA_B;                    // fut_ref hi bf16 20,971,520
static constexpr size_t FRL_B  = RA_B + 20971520;
static constexpr size_t E1H_B  = RA_B + 41943040;         // e1 pair bf16 8,388,608 ea
static constexpr size_t E1L_B  = RA_B + 50331648;
static constexpr size_t Y1_B   = RA_B;                    // conv1 out (52,428,800)
static constexpr size_t Y3_B   = RA_B;                    // conv3 out (58,720,256)
static constexpr size_t WGT_B  = RA_B;                    // experts bf16
static constexpr size_t WUT_B  = RA_B + 16777216;
static constexpr size_t WDT_B  = RA_B + 33554432;
static constexpr size_t X_B    = RA_B + 50331648;         // x f32 8,388,608
static constexpr size_t SHGTH_B = RA_B;                   // after moe_up (wg/wu dead)
static constexpr size_t SHGTL_B = RA_B + 2097152;
static constexpr size_t SHUTH_B = RA_B + 4194304;
static constexpr size_t SHUTL_B = RA_B + 6291456;
static constexpr size_t SHDTH_B = RA_B + 8388608;
static constexpr size_t SHDTL_B = RA_B + 10485760;
static constexpr size_t O1TH_B  = RA_B + 12582912;
static constexpr size_t O1TL_B  = RA_B + 13631488;
static constexpr size_t O2TH_B  = RA_B + 14680064;
static constexpr size_t O2TL_B  = RA_B + 16777216;        // ends RA+18,874,368
static constexpr size_t H2_B    = RA_B + 25165824;        // f32 8,388,608
static constexpr size_t H2H_B   = RA_B + 33554432;        // pair bf16 (wdT dead)
static constexpr size_t H2L_B   = RA_B + 37748736;
// RB phases:
static constexpr size_t E1TH_B = RB_B;                    // enc1 WT pair 5,242,880 ea
static constexpr size_t E1TL_B = RB_B + 5242880;
static constexpr size_t E2TH_B = RB_B + 10485760;         // enc2 WT pair 2,097,152 ea
static constexpr size_t E2TL_B = RB_B + 12582912;
static constexpr size_t E2F_B  = RB_B + 14680064;         // e2 f32 16,777,216
static constexpr size_t HSB_B  = RB_B;                    // hist_seq bf16 19,660,800
static constexpr size_t Y2_B   = RB_B;                    // conv2 out 54,525,952
static constexpr size_t HB_B   = RB_B;                    // hb bf16 8,388,608
static constexpr size_t HI1_B  = RB_B + 8388608;          // hi1b bf16 8,388,608
static constexpr size_t XH_B   = RB_B;                    // x pair bf16 4,194,304 ea
static constexpr size_t XL_B   = RB_B + 4194304;
static constexpr size_t TM_B   = RB_B + 8388608;          // t_moe bf16 33,554,432
static constexpr size_t STB_B  = RB_B + 8388608;          // stb bf16 16,777,216 (tm dead)
static constexpr size_t O1H_B  = RB_B;                    // o1 pair (xh/xl dead)
static constexpr size_t O1L_B  = RB_B + 8388608;
static constexpr size_t O2F_B  = RB_B + 16777216;         // o2 f32 16,777,216
// P smalls:
static constexpr size_t HLAT_B = P_B;
static constexpr size_t E3P_B  = P_B + 1048576;
static constexpr size_t Z_B    = P_B + 3145728;
static constexpr size_t LOG_B  = P_B + 4194304;
static constexpr size_t TID_B  = P_B + 4456448;
static constexpr size_t TW_B   = P_B + 4521984;
static constexpr size_t POS_B  = P_B + 4587520;
static constexpr size_t CNT_B  = P_B + 4653056;
static constexpr size_t OFS_B  = P_B + 4653184;
static constexpr size_t ROWL_B = P_B + 4653312;
static constexpr size_t WL_B   = P_B + 4718848;
static constexpr size_t ZP_B   = P_B + 4784384;           // 4096 B zero page

// XCD-coherent tile decode: nm % 8 == 0 required. Same m-panel's n-tiles all
// map to XCD = bid%8 (default round-robin assignment), so the A panel stays
// in one L2 while its n-tiles stream B.
#define TILE_DECODE(nn_)                         \
  const int bid = blockIdx.x;                    \
  const int xcd = bid & 7;                       \
  const int tt_ = bid >> 3;                      \
  const int n0 = (tt_ % (nn_)) * 128;            \
  const int m0 = ((tt_ / (nn_)) * 8 + xcd) * 128;

// ---------------- prep kernels ----------------
__global__ void k_zero_i(int* __restrict__ p, int n) {
  int i = blockIdx.x * 64 + threadIdx.x;
  if (i < n) p[i] = 0;
}
__global__ void k_zero_f4(float4* __restrict__ p, int n4) {
  int i = blockIdx.x * 256 + threadIdx.x;
  if (i < n4) p[i] = make_float4(0.f, 0.f, 0.f, 0.f);
}
__global__ void k_f32_to_bf4(const float* __restrict__ s, u16* __restrict__ d, int n4) {
  int i = blockIdx.x * 256 + threadIdx.x;
  if (i >= n4) return;
  float4 v = *(const float4*)(s + (size_t)i * 4);
  *(ushort4*)(d + (size_t)i * 4) = make_ushort4(f2b(v.x), f2b(v.y), f2b(v.z), f2b(v.w));
}
// f32 -> (hi, lo) bf16 pair
__global__ void k_split_x(const float* __restrict__ s, u16* __restrict__ dh,
                          u16* __restrict__ dl, int n4) {
  int i = blockIdx.x * 256 + threadIdx.x;
  if (i >= n4) return;
  float4 v = *(const float4*)(s + (size_t)i * 4);
  float a[4] = {v.x, v.y, v.z, v.w};
  ushort4 h, l;
  u16* hp = (u16*)&h; u16* lp = (u16*)&l;
#pragma unroll
  for (int j = 0; j < 4; ++j) {
    u16 hh = f2b(a[j]);
    hp[j] = hh;
    lp[j] = f2b(a[j] - b2f(hh));
  }
  *(ushort4*)(dh + (size_t)i * 4) = h;
  *(ushort4*)(dl + (size_t)i * 4) = l;
}
// conv weight: [O][I][3] fp32 -> WT[o][k*CIN+i] bf16
__global__ void k_wt_conv(const float* __restrict__ w, u16* __restrict__ wt,
                          int CIN, int COUT) {
  int idx = blockIdx.x * 256 + threadIdx.x;
  int Kc = CIN * 3;
  if (idx >= COUT * Kc) return;
  int o = idx / Kc, c = idx - o * Kc;
  int k = c / CIN, i = c - k * CIN;
  wt[idx] = f2b(w[(size_t)o * Kc + i * 3 + k]);
}
// dense weight: W[K][N] fp32 -> WT[N][K] bf16
__global__ __launch_bounds__(256) void k_transpose_bf(const float* __restrict__ W,
                                                      u16* __restrict__ WT,
                                                      int K, int N) {
  __shared__ float t[32][33];
  int n0 = blockIdx.x * 32, k0 = blockIdx.y * 32;
  int lx = threadIdx.x & 31, ly = threadIdx.x >> 5;
#pragma unroll
  for (int r = 0; r < 32; r += 8)
    t[ly + r][lx] = W[(size_t)(k0 + ly + r) * N + n0 + lx];
  __syncthreads();
#pragma unroll
  for (int r = 0; r < 32; r += 8)
    WT[(size_t)(n0 + ly + r) * K + k0 + lx] = f2b(t[lx][ly + r]);
}
// batched per-expert transpose
__global__ __launch_bounds__(256) void k_transpose_bf_b(const float* __restrict__ W,
                                                        u16* __restrict__ WT,
                                                        int K, int N) {
  const size_t eo = (size_t)blockIdx.z * K * N;
  __shared__ float t[32][33];
  int n0 = blockIdx.x * 32, k0 = blockIdx.y * 32;
  int lx = threadIdx.x & 31, ly = threadIdx.x >> 5;
#pragma unroll
  for (int r = 0; r < 32; r += 8)
    t[ly + r][lx] = W[eo + (size_t)(k0 + ly + r) * N + n0 + lx];
  __syncthreads();
#pragma unroll
  for (int r = 0; r < 32; r += 8)
    WT[eo + (size_t)(n0 + ly + r) * K + k0 + lx] = f2b(t[lx][ly + r]);
}
// hi/lo split transpose
__global__ __launch_bounds__(256) void k_transpose_hilo(const float* __restrict__ W,
                                                        u16* __restrict__ WTh,
                                                        u16* __restrict__ WTl,
                                                        int K, int N) {
  __shared__ float t[32][33];
  int n0 = blockIdx.x * 32, k0 = blockIdx.y * 32;
  int lx = threadIdx.x & 31, ly = threadIdx.x >> 5;
#pragma unroll
  for (int r = 0; r < 32; r += 8)
    t[ly + r][lx] = W[(size_t)(k0 + ly + r) * N + n0 + lx];
  __syncthreads();
#pragma unroll
  for (int r = 0; r < 32; r += 8) {
    float f = t[lx][ly + r];
    u16 h = f2b(f);
    size_t o = (size_t)(n0 + ly + r) * K + k0 + lx;
    WTh[o] = h;
    WTl[o] = f2b(f - b2f(h));
  }
}

// ============================================================================
// gll GEMM cores: 128x128 tile, BK=32, 4 waves (2x2 of 64x64), 16x16x32 bf16.
// LDS per tensor tile: 4096 u16; wave wid rows [wid*32,+32) at u16 wid*1024,
// call i at +i*512. Slot swizzle f(r) = (r>>1)&3 (2-way bank = free); source
// pre-swizzled with the same f; f(r+16) = f(r) so both calls share sl.
// ============================================================================
#define PRO128 \
  const int tid = threadIdx.x; \
  const int lane = tid & 63; \
  const int wid = tid >> 6; \
  const int wr = (wid >> 1) * 64, wc = (wid & 1) * 64; \
  const int l15 = lane & 15, lsub = lane >> 4;

#define MFMA_BF16(a, b, c) __builtin_amdgcn_mfma_f32_16x16x32_bf16(a, b, c, 0, 0, 0)

// generic GEMM: AP/BP = number of hi/lo parts of A/B (1 or 2); 3-term when 2x2.
// EPI: 0 f32 store, 1 bf16 store, 2 f32 +=, 3 bf16 pair store.
template<int ACT, int EPI, int AP, int BP>
__global__ __launch_bounds__(256) void k_gg(
    const u16* __restrict__ A0, const u16* __restrict__ A1,
    const u16* __restrict__ B0, const u16* __restrict__ B1,
    const float* __restrict__ bias,
    float* __restrict__ Cf, u16* __restrict__ Ch, u16* __restrict__ Cl,
    int N, int K, int lda, int ldb, int nn) {
  constexpr int NT = AP + BP;
  __shared__ u16 lds[NT * 4096];
  PRO128
  TILE_DECODE(nn)
  // per-lane staging sources (call 1 = call 0 + 16 rows; f(r0+16)=f(r0))
  const int r0 = wid * 32 + (lane >> 2);
  const int sl = ((lane & 3) ^ ((r0 >> 1) & 3)) * 8;
  const u16* sA0 = A0 + (size_t)(m0 + r0) * lda + sl;
  const u16* sA1 = (AP == 2) ? A1 + (size_t)(m0 + r0) * lda + sl : nullptr;
  const u16* sB0 = B0 + (size_t)(n0 + r0) * ldb + sl;
  const u16* sB1 = (BP == 2) ? B1 + (size_t)(n0 + r0) * ldb + sl : nullptr;
  const size_t stepA = (size_t)16 * lda, stepB = (size_t)16 * ldb;
  const int wb = wid * 1024;

  f32x4 acc[4][4];
  const f32x4 zf = {0.f, 0.f, 0.f, 0.f};
#pragma unroll
  for (int i = 0; i < 4; ++i)
#pragma unroll
    for (int j = 0; j < 4; ++j) acc[i][j] = zf;

  for (int k0 = 0; k0 < K; k0 += 32) {
    {
      int t = 0;
      gll16(sA0 + k0, &lds[t * 4096 + wb]);
      gll16(sA0 + stepA + k0, &lds[t * 4096 + wb + 512]);
      ++t;
      if (AP == 2) {
        gll16(sA1 + k0, &lds[t * 4096 + wb]);
        gll16(sA1 + stepA + k0, &lds[t * 4096 + wb + 512]);
        ++t;
      }
      gll16(sB0 + k0, &lds[t * 4096 + wb]);
      gll16(sB0 + stepB + k0, &lds[t * 4096 + wb + 512]);
      ++t;
      if (BP == 2) {
        gll16(sB1 + k0, &lds[t * 4096 + wb]);
        gll16(sB1 + stepB + k0, &lds[t * 4096 + wb + 512]);
      }
    }
    __syncthreads();
    U8 fah[4], fal[4];
#pragma unroll
    for (int i = 0; i < 4; ++i) {
      int ra = wr + i * 16 + l15;
      int ao = ra * 32 + ((lsub ^ ((ra >> 1) & 3))) * 8;
      fah[i].u = *(const uint4*)&lds[ao];
      if (AP == 2) fal[i].u = *(const uint4*)&lds[4096 + ao];
    }
#pragma unroll
    for (int ni = 0; ni < 4; ++ni) {
      int rb = wc + ni * 16 + l15;
      int bo = AP * 4096 + rb * 32 + ((lsub ^ ((rb >> 1) & 3))) * 8;
      U8 fbh, fbl;
      fbh.u = *(const uint4*)&lds[bo];
      if (BP == 2) fbl.u = *(const uint4*)&lds[4096 + bo];
#pragma unroll
      for (int mi = 0; mi < 4; ++mi) {
        acc[mi][ni] = MFMA_BF16(fah[mi].b, fbh.b, acc[mi][ni]);
        if (BP == 2) acc[mi][ni] = MFMA_BF16(fah[mi].b, fbl.b, acc[mi][ni]);
        if (AP == 2) acc[mi][ni] = MFMA_BF16(fal[mi].b, fbh.b, acc[mi][ni]);
      }
    }
    __syncthreads();
  }
  const int row4 = lsub * 4;
#pragma unroll
  for (int mi = 0; mi < 4; ++mi)
#pragma unroll
    for (int ni = 0; ni < 4; ++ni) {
      int col = n0 + wc + ni * 16 + l15;
      float bv = bias[col];
#pragma unroll
      for (int j = 0; j < 4; ++j) {
        int row = m0 + wr + mi * 16 + row4 + j;
        float v = acc[mi][ni][j] + bv;
        if (ACT) v = silu_f(v);
        if (EPI == 0) Cf[(size_t)row * N + col] = v;
        else if (EPI == 1) Ch[(size_t)row * N + col] = f2b(v);
        else if (EPI == 2) Cf[(size_t)row * N + col] += v;
        else {
          u16 vh = f2b(v);
          Ch[(size_t)row * N + col] = vh;
          Cl[(size_t)row * N + col] = f2b(v - b2f(vh));
        }
      }
    }
}

// dual hi/lo GEMM: C bf16 = silu(Apair@Gpair + bg) * (Apair@Upair + bu)
__global__ __launch_bounds__(256) void k_gdual(
    const u16* __restrict__ A0, const u16* __restrict__ A1,
    const u16* __restrict__ G0, const u16* __restrict__ G1,
    const u16* __restrict__ U0, const u16* __restrict__ U1,
    const float* __restrict__ bg, const float* __restrict__ bu,
    u16* __restrict__ C, int N, int K, int lda, int ldb, int nn) {
  __shared__ u16 lds[6 * 4096];
  PRO128
  TILE_DECODE(nn)
  const int r0 = wid * 32 + (lane >> 2);
  const int sl = ((lane & 3) ^ ((r0 >> 1) & 3)) * 8;
  const u16* s[6];
  s[0] = A0 + (size_t)(m0 + r0) * lda + sl;
  s[1] = A1 + (size_t)(m0 + r0) * lda + sl;
  s[2] = G0 + (size_t)(n0 + r0) * ldb + sl;
  s[3] = G1 + (size_t)(n0 + r0) * ldb + sl;
  s[4] = U0 + (size_t)(n0 + r0) * ldb + sl;
  s[5] = U1 + (size_t)(n0 + r0) * ldb + sl;
  const size_t stp[6] = {(size_t)16*lda, (size_t)16*lda, (size_t)16*ldb,
                         (size_t)16*ldb, (size_t)16*ldb, (size_t)16*ldb};
  const int wb = wid * 1024;
  f32x4 ag[4][4], au[4][4];
  const f32x4 zf = {0.f, 0.f, 0.f, 0.f};
#pragma unroll
  for (int i = 0; i < 4; ++i)
#pragma unroll
    for (int j = 0; j < 4; ++j) { ag[i][j] = zf; au[i][j] = zf; }

  for (int k0 = 0; k0 < K; k0 += 32) {
#pragma unroll
    for (int t = 0; t < 6; ++t) {
      gll16(s[t] + k0, &lds[t * 4096 + wb]);
      gll16(s[t] + stp[t] + k0, &lds[t * 4096 + wb + 512]);
    }
    __syncthreads();
    U8 fah[4], fal[4];
#pragma unroll
    for (int i = 0; i < 4; ++i) {
      int ra = wr + i * 16 + l15;
      int ao = ra * 32 + ((lsub ^ ((ra >> 1) & 3))) * 8;
      fah[i].u = *(const uint4*)&lds[ao];
      fal[i].u = *(const uint4*)&lds[4096 + ao];
    }
#pragma unroll
    for (int ni = 0; ni < 4; ++ni) {
      int rb = wc + ni * 16 + l15;
      int bo = rb * 32 + ((lsub ^ ((rb >> 1) & 3))) * 8;
      U8 gh, gl, uh, ul;
      gh.u = *(const uint4*)&lds[2 * 4096 + bo];
      gl.u = *(const uint4*)&lds[3 * 4096 + bo];
      uh.u = *(const uint4*)&lds[4 * 4096 + bo];
      ul.u = *(const uint4*)&lds[5 * 4096 + bo];
#pragma unroll
      for (int mi = 0; mi < 4; ++mi) {
        ag[mi][ni] = MFMA_BF16(fah[mi].b, gh.b, ag[mi][ni]);
        ag[mi][ni] = MFMA_BF16(fah[mi].b, gl.b, ag[mi][ni]);
        ag[mi][ni] = MFMA_BF16(fal[mi].b, gh.b, ag[mi][ni]);
        au[mi][ni] = MFMA_BF16(fah[mi].b, uh.b, au[mi][ni]);
        au[mi][ni] = MFMA_BF16(fah[mi].b, ul.b, au[mi][ni]);
        au[mi][ni] = MFMA_BF16(fal[mi].b, uh.b, au[mi][ni]);
      }
    }
    __syncthreads();
  }
  const int row4 = lsub * 4;
#pragma unroll
  for (int mi = 0; mi < 4; ++mi)
#pragma unroll
    for (int ni = 0; ni < 4; ++ni) {
      int col = n0 + wc + ni * 16 + l15;
      float bgv = bg[col], buv = bu[col];
#pragma unroll
      for (int j = 0; j < 4; ++j) {
        int row = m0 + wr + mi * 16 + row4 + j;
        float v = silu_f(ag[mi][ni][j] + bgv) * (au[mi][ni][j] + buv);
        C[(size_t)row * N + col] = f2b(v);
      }
    }
}

// conv as implicit-im2col gll GEMM; zero-page for pad/OOB.
template<int CIN, int TIN, int TOUT, int STRIDE>
__global__ __launch_bounds__(256) void k_gconv(
    const u16* __restrict__ X, const u16* __restrict__ WT,
    const float* __restrict__ bias, u16* __restrict__ Y,
    const u16* __restrict__ zp, int COUT, int nn) {
  constexpr int K = CIN * 3;
  __shared__ u16 lds[2 * 4096];
  PRO128
  TILE_DECODE(nn)
  int bA_[2], tb_[2], sl_[2];
  const u16* sB[2];
#pragma unroll
  for (int i = 0; i < 2; ++i) {
    int r = wid * 32 + i * 16 + (lane >> 2);
    int sl = ((lane & 3) ^ ((r >> 1) & 3)) * 8;
    sl_[i] = sl;
    int m = m0 + r;
    int bb = m / TOUT;
    int tt = m - bb * TOUT;
    bA_[i] = bb;
    tb_[i] = tt * STRIDE - 1;
    sB[i] = WT + (size_t)(n0 + r) * K + sl;
  }
  const int wb = wid * 1024;
  f32x4 acc[4][4];
  const f32x4 zf = {0.f, 0.f, 0.f, 0.f};
#pragma unroll
  for (int i = 0; i < 4; ++i)
#pragma unroll
    for (int j = 0; j < 4; ++j) acc[i][j] = zf;

  for (int k0 = 0; k0 < K; k0 += 32) {
#pragma unroll
    for (int i = 0; i < 2; ++i) {
      int kk = k0 + sl_[i];
      int ker = kk / CIN;
      int i0 = kk - ker * CIN;
      int tin = tb_[i] + ker;
      const u16* sa = (tin >= 0 && tin < TIN)
          ? X + ((size_t)bA_[i] * TIN + tin) * CIN + i0 : zp;
      gll16(sa, &lds[wb + i * 512]);
      gll16(sB[i] + k0, &lds[4096 + wb + i * 512]);
    }
    __syncthreads();
    U8 fa[4], fb[4];
#pragma unroll
    for (int i = 0; i < 4; ++i) {
      int ra = wr + i * 16 + l15;
      fa[i].u = *(const uint4*)&lds[ra * 32 + ((lsub ^ ((ra >> 1) & 3))) * 8];
      int rb = wc + i * 16 + l15;
      fb[i].u = *(const uint4*)&lds[4096 + rb * 32 + ((lsub ^ ((rb >> 1) & 3))) * 8];
    }
#pragma unroll
    for (int mi = 0; mi < 4; ++mi)
#pragma unroll
      for (int ni = 0; ni < 4; ++ni)
        acc[mi][ni] = MFMA_BF16(fa[mi].b, fb[ni].b, acc[mi][ni]);
    __syncthreads();
  }
  const int row4 = lsub * 4;
#pragma unroll
  for (int mi = 0; mi < 4; ++mi)
#pragma unroll
    for (int ni = 0; ni < 4; ++ni) {
      int col = n0 + wc + ni * 16 + l15;
      float bv = bias[col];
#pragma unroll
      for (int j = 0; j < 4; ++j) {
        int row = m0 + wr + mi * 16 + row4 + j;
        Y[(size_t)row * COUT + col] = f2b(silu_f(acc[mi][ni][j] + bv));
      }
    }
}

// MoE up: expert->XCD swizzled 1D grid; gathered A pair x bf16 W (dual).
__global__ __launch_bounds__(256) void k_gmoeup(
    const u16* __restrict__ xh, const u16* __restrict__ xl,
    const u16* __restrict__ WgT, const u16* __restrict__ WuT,
    const float* __restrict__ bg, const float* __restrict__ bu,
    const int* __restrict__ rowlist, const int* __restrict__ counts,
    const int* __restrict__ offs, const u16* __restrict__ zp,
    u16* __restrict__ t_moe) {
  const int bid = blockIdx.x;
  const int xcd = bid & 7, sidx = bid >> 3;
  const int eo = sidx >> 8, r2 = sidx & 255;
  const int mt = r2 >> 3, nt = r2 & 7;
  const int e = xcd + 8 * eo;
  const int ne = counts[e];
  const int m0 = mt * 128;
  if (m0 >= ne) return;
  const int n0 = nt * 128;
  const int base = offs[e];
  constexpr int K = 512, N = 1024;
  const u16* Wge = WgT + (size_t)e * N * K;
  const u16* Wue = WuT + (size_t)e * N * K;
  const float* bge = bg + (size_t)e * N;
  const float* bue = bu + (size_t)e * N;
  __shared__ u16 lds[4 * 4096];
  PRO128
  const u16* sAh[2]; const u16* sAl[2]; const u16* sG[2]; const u16* sU[2];
#pragma unroll
  for (int i = 0; i < 2; ++i) {
    int r = wid * 32 + i * 16 + (lane >> 2);
    int sl = ((lane & 3) ^ ((r >> 1) & 3)) * 8;
    int grow = m0 + r;
    int xr = (grow < ne) ? rowlist[base + grow] : -1;
    sAh[i] = (xr >= 0) ? xh + (size_t)xr * K + sl : zp;
    sAl[i] = (xr >= 0) ? xl + (size_t)xr * K + sl : zp;
    sG[i] = Wge + (size_t)(n0 + r) * K + sl;
    sU[i] = Wue + (size_t)(n0 + r) * K + sl;
  }
  const int wb = wid * 1024;
  f32x4 ag[4][4], au[4][4];
  const f32x4 zf = {0.f, 0.f, 0.f, 0.f};
#pragma unroll
  for (int i = 0; i < 4; ++i)
#pragma unroll
    for (int j = 0; j < 4; ++j) { ag[i][j] = zf; au[i][j] = zf; }

  for (int k0 = 0; k0 < K; k0 += 32) {
#pragma unroll
    for (int i = 0; i < 2; ++i) {
      gll16(sAh[i] + k0, &lds[0 * 4096 + wb + i * 512]);
      gll16(sAl[i] + k0, &lds[1 * 4096 + wb + i * 512]);
      gll16(sG[i] + k0, &lds[2 * 4096 + wb + i * 512]);
      gll16(sU[i] + k0, &lds[3 * 4096 + wb + i * 512]);
    }
    __syncthreads();
    U8 fah[4], fal[4];
#pragma unroll
    for (int i = 0; i < 4; ++i) {
      int ra = wr + i * 16 + l15;
      int ao = ra * 32 + ((lsub ^ ((ra >> 1) & 3))) * 8;
      fah[i].u = *(const uint4*)&lds[ao];
      fal[i].u = *(const uint4*)&lds[4096 + ao];
    }
#pragma unroll
    for (int ni = 0; ni < 4; ++ni) {
      int rb = wc + ni * 16 + l15;
      int bo = rb * 32 + ((lsub ^ ((rb >> 1) & 3))) * 8;
      U8 fg, fu;
      fg.u = *(const uint4*)&lds[2 * 4096 + bo];
      fu.u = *(const uint4*)&lds[3 * 4096 + bo];
#pragma unroll
      for (int mi = 0; mi < 4; ++mi) {
        ag[mi][ni] = MFMA_BF16(fah[mi].b, fg.b, ag[mi][ni]);
        ag[mi][ni] = MFMA_BF16(fal[mi].b, fg.b, ag[mi][ni]);
        au[mi][ni] = MFMA_BF16(fah[mi].b, fu.b, au[mi][ni]);
        au[mi][ni] = MFMA_BF16(fal[mi].b, fu.b, au[mi][ni]);
      }
    }
    __syncthreads();
  }
  const int row4 = lsub * 4;
#pragma unroll
  for (int mi = 0; mi < 4; ++mi)
#pragma unroll
    for (int ni = 0; ni < 4; ++ni) {
      int col = n0 + wc + ni * 16 + l15;
      float bgv = bge[col], buv = bue[col];
#pragma unroll
      for (int j = 0; j < 4; ++j) {
        int row = m0 + wr + mi * 16 + row4 + j;
        if (row >= ne) continue;
        float v = silu_f(ag[mi][ni][j] + bgv) * (au[mi][ni][j] + buv);
        t_moe[(size_t)(base + row) * N + col] = f2b(v);
      }
    }
}

// MoE down: expert->XCD swizzled; t_moe x WdT -> weighted atomic scatter.
__global__ __launch_bounds__(256) void k_gmoedown(
    const u16* __restrict__ t_moe, const u16* __restrict__ WdT,
    const float* __restrict__ bd, const int* __restrict__ rowlist,
    const float* __restrict__ wlist, const int* __restrict__ counts,
    const int* __restrict__ offs, const u16* __restrict__ zp,
    float* __restrict__ h2) {
  const int bid = blockIdx.x;
  const int xcd = bid & 7, sidx = bid >> 3;
  const int eo = sidx >> 7, r2 = sidx & 127;
  const int mt = r2 >> 2, nt = r2 & 3;
  const int e = xcd + 8 * eo;
  const int ne = counts[e];
  const int m0 = mt * 128;
  if (m0 >= ne) return;
  const int n0 = nt * 128;
  const int base = offs[e];
  constexpr int K = 1024, N = 512;
  const u16* Wde = WdT + (size_t)e * N * K;
  const float* bde = bd + (size_t)e * N;
  __shared__ u16 lds[2 * 4096];
  PRO128
  const u16* sA[2]; const u16* sB[2];
#pragma unroll
  for (int i = 0; i < 2; ++i) {
    int r = wid * 32 + i * 16 + (lane >> 2);
    int sl = ((lane & 3) ^ ((r >> 1) & 3)) * 8;
    sA[i] = (m0 + r < ne) ? t_moe + (size_t)(base + m0 + r) * K + sl : zp;
    sB[i] = Wde + (size_t)(n0 + r) * K + sl;
  }
  const int wb = wid * 1024;
  f32x4 acc[4][4];
  const f32x4 zf = {0.f, 0.f, 0.f, 0.f};
#pragma unroll
  for (int i = 0; i < 4; ++i)
#pragma unroll
    for (int j = 0; j < 4; ++j) acc[i][j] = zf;

  for (int k0 = 0; k0 < K; k0 += 32) {
#pragma unroll
    for (int i = 0; i < 2; ++i) {
      gll16(sA[i] + k0, &lds[wb + i * 512]);
      gll16(sB[i] + k0, &lds[4096 + wb + i * 512]);
    }
    __syncthreads();
    U8 fa[4], fb[4];
#pragma unroll
    for (int i = 0; i < 4; ++i) {
      int ra = wr + i * 16 + l15;
      fa[i].u = *(const uint4*)&lds[ra * 32 + ((lsub ^ ((ra >> 1) & 3))) * 8];
      int rb = wc + i * 16 + l15;
      fb[i].u = *(const uint4*)&lds[4096 + rb * 32 + ((lsub ^ ((rb >> 1) & 3))) * 8];
    }
#pragma unroll
    for (int mi = 0; mi < 4; ++mi)
#pragma unroll
      for (int ni = 0; ni < 4; ++ni)
        acc[mi][ni] = MFMA_BF16(fa[mi].b, fb[ni].b, acc[mi][ni]);
    __syncthreads();
  }
  const int row4 = lsub * 4;
#pragma unroll
  for (int mi = 0; mi < 4; ++mi)
#pragma unroll
    for (int j = 0; j < 4; ++j) {
      int row = m0 + wr + mi * 16 + row4 + j;
      if (row >= ne) continue;
      int r = rowlist[base + row];
      float wl = wlist[base + row];
#pragma unroll
      for (int ni = 0; ni < 4; ++ni) {
        int col = n0 + wc + ni * 16 + l15;
        atomicAdd(&h2[(size_t)r * 512 + col], wl * (acc[mi][ni][j] + bde[col]));
      }
    }
}

// ---------------- fp32 64x64 GEMM (hlin2 / enc3 / router / head) ----------------
template<int ACT, bool NG, typename TA>
__global__ __launch_bounds__(256) void k_gemm(const TA* __restrict__ A,
                                              const float* __restrict__ W,
                                              const float* __restrict__ bias,
                                              float* __restrict__ C,
                                              int N, int K) {
  __shared__ float As[16][64];
  __shared__ float Bs[16][64];
  const int tid = threadIdx.x;
  const int m0 = blockIdx.x * 64;
  const int n0 = blockIdx.y * 64;
  const int tr = tid >> 4, tc = tid & 15;
  const int lm = tid >> 2, lk = (tid & 3) * 4;
  const int ln = tid & 63, lkb = (tid >> 6) * 4;
  float acc[4][4] = {};
  for (int k0 = 0; k0 < K; k0 += 16) {
    float4 av = ld4(A + (size_t)(m0 + lm) * K + k0 + lk);
    As[lk + 0][lm] = av.x; As[lk + 1][lm] = av.y;
    As[lk + 2][lm] = av.z; As[lk + 3][lm] = av.w;
#pragma unroll
    for (int s = 0; s < 4; ++s) {
      int kk = lkb + s;
      float v = 0.f;
      if (!NG || (n0 + ln) < N) v = W[(size_t)(k0 + kk) * N + n0 + ln];
      Bs[kk][ln] = v;
    }
    __syncthreads();
#pragma unroll
    for (int kk = 0; kk < 16; ++kk) {
      float4 a4 = *(const float4*)&As[kk][tr * 4];
      float4 b4 = *(const float4*)&Bs[kk][tc * 4];
      float a[4] = {a4.x, a4.y, a4.z, a4.w};
      float b[4] = {b4.x, b4.y, b4.z, b4.w};
#pragma unroll
      for (int i = 0; i < 4; ++i)
#pragma unroll
        for (int j = 0; j < 4; ++j) acc[i][j] = fmaf(a[i], b[j], acc[i][j]);
    }
    __syncthreads();
  }
#pragma unroll
  for (int i = 0; i < 4; ++i) {
    int m = m0 + tr * 4 + i;
#pragma unroll
    for (int j = 0; j < 4; ++j) {
      int n = n0 + tc * 4 + j;
      if (NG && n >= N) continue;
      float v = acc[i][j] + bias[n];
      if (ACT == 1) v = silu_f(v);
      C[(size_t)m * N + n] = v;
    }
  }
}

// concat projection GEMM (fp32, routing-safe)
__global__ __launch_bounds__(256) void k_gemm_proj(const float* __restrict__ obs,
                                                   const float* __restrict__ hl,
                                                   const float* __restrict__ z,
                                                   const float* __restrict__ W,
                                                   const float* __restrict__ bias,
                                                   float* __restrict__ C) {
  const int N = 512, K = 384;
  __shared__ float As[16][64];
  __shared__ float Bs[16][64];
  const int tid = threadIdx.x;
  const int m0 = blockIdx.x * 64;
  const int n0 = blockIdx.y * 64;
  const int tr = tid >> 4, tc = tid & 15;
  const int lm = tid >> 2, lk = (tid & 3) * 4;
  const int ln = tid & 63, lkb = (tid >> 6) * 4;
  const int m = m0 + lm;
  float acc[4][4] = {};
  for (int k0 = 0; k0 < K; k0 += 16) {
#pragma unroll
    for (int j = 0; j < 4; ++j) {
      int c = k0 + lk + j;
      float v;
      if (c < 256)      v = obs[(size_t)m * 256 + c];
      else if (c < 320) v = hl[(size_t)m * 64 + (c - 256)];
      else              v = z[(size_t)m * 64 + (c - 320)];
      As[lk + j][lm] = v;
    }
#pragma unroll
    for (int s = 0; s < 4; ++s) {
      int kk = lkb + s;
      Bs[kk][ln] = W[(size_t)(k0 + kk) * N + n0 + ln];
    }
    __syncthreads();
#pragma unroll
    for (int kk = 0; kk < 16; ++kk) {
      float4 a4 = *(const float4*)&As[kk][tr * 4];
      float4 b4 = *(const float4*)&Bs[kk][tc * 4];
      float a[4] = {a4.x, a4.y, a4.z, a4.w};
      float b[4] = {b4.x, b4.y, b4.z, b4.w};
#pragma unroll
      for (int i = 0; i < 4; ++i)
#pragma unroll
        for (int j = 0; j < 4; ++j) acc[i][j] = fmaf(a[i], b[j], acc[i][j]);
    }
    __syncthreads();
  }
#pragma unroll
  for (int i = 0; i < 4; ++i) {
    int mo = m0 + tr * 4 + i;
#pragma unroll
    for (int j = 0; j < 4; ++j) {
      int n = n0 + tc * 4 + j;
      C[(size_t)mo * N + n] = acc[i][j] + bias[n];
    }
  }
}

// ---------------- small elementwise / router kernels ----------------
__global__ void k_mean7(const u16* __restrict__ y3, u16* __restrict__ hb) {
  int idx = blockIdx.x * 256 + threadIdx.x;
  if (idx >= BATCH * 1024) return;
  int b = idx >> 10, o = idx & 1023;
  const u16* p = y3 + (size_t)b * 7 * 1024 + o;
  float s = 0.f;
#pragma unroll
  for (int t = 0; t < 7; ++t) s += b2f(p[(size_t)t * 1024]);
  hb[idx] = f2b(s * (1.f / 7.f));
}

__global__ void k_z(const float* __restrict__ e3, const float* __restrict__ noise,
                    float* __restrict__ z) {
  int idx = blockIdx.x * 256 + threadIdx.x;
  if (idx >= BATCH * 64) return;
  int b = idx >> 6, j = idx & 63;
  float mu = e3[(size_t)b * 128 + j];
  float lv = e3[(size_t)b * 128 + 64 + j];
  z[idx] = mu + expf(0.5f * lv) * noise[idx];
}

__global__ void k_router(const float* __restrict__ logits, int* __restrict__ tidA,
                         float* __restrict__ twA, int* __restrict__ posA,
                         int* __restrict__ counts) {
  int b = blockIdx.x * 256 + threadIdx.x;
  if (b >= BATCH) return;
  float s[16];
#pragma unroll
  for (int e = 0; e < 16; ++e)
    s[e] = 1.f / (1.f + expf(-logits[(size_t)b * 16 + e]));
  float gsc[4];
#pragma unroll
  for (int g = 0; g < 4; ++g) {
    float m1 = -1e30f; int i1 = -1;
    for (int i = 0; i < 4; ++i) { float v = s[g * 4 + i]; if (v > m1) { m1 = v; i1 = i; } }
    float m2 = -1e30f;
    for (int i = 0; i < 4; ++i) { if (i == i1) continue; float v = s[g * 4 + i]; if (v > m2) m2 = v; }
    gsc[g] = m1 + m2;
  }
  int g1 = 0; float b1 = gsc[0];
  for (int g = 1; g < 4; ++g) if (gsc[g] > b1) { b1 = gsc[g]; g1 = g; }
  int g2 = -1; float b2 = -1e30f;
  for (int g = 0; g < 4; ++g) { if (g == g1) continue; if (gsc[g] > b2) { b2 = gsc[g]; g2 = g; } }
  float ms[16]; bool used[16];
#pragma unroll
  for (int e = 0; e < 16; ++e) {
    int g = e >> 2;
    ms[e] = (g == g1 || g == g2) ? s[e] : 0.f;
    used[e] = false;
  }
  int te[4]; float tv[4]; float tsum = 0.f;
  for (int t = 0; t < 4; ++t) {
    float best = -1.f; int bi = 0;
    for (int e = 0; e < 16; ++e)
      if (!used[e] && ms[e] > best) { best = ms[e]; bi = e; }
    used[bi] = true;
    te[t] = bi;
    tv[t] = s[bi];
    tsum += s[bi];
  }
  float inv = 1.f / (tsum + 1e-20f);
  for (int t = 0; t < 4; ++t) {
    int e = te[t];
    tidA[b * 4 + t] = e;
    twA[b * 4 + t] = tv[t] * inv;  // ROUTE_SCALE = 1.0
    posA[b * 4 + t] = atomicAdd(&counts[e], 1);
  }
}

__global__ void k_offsets(const int* __restrict__ counts, int* __restrict__ offs) {
  if (threadIdx.x == 0 && blockIdx.x == 0) {
    int a = 0;
    for (int e = 0; e < 16; ++e) { offs[e] = a; a += counts[e]; }
    offs[16] = a;
  }
}

__global__ void k_build(const int* __restrict__ tidA, const float* __restrict__ twA,
                        const int* __restrict__ posA, const int* __restrict__ offs,
                        int* __restrict__ rowlist, float* __restrict__ wlist) {
  int idx = blockIdx.x * 256 + threadIdx.x;
  if (idx >= BATCH * 4) return;
  int e = tidA[idx];
  int p = offs[e] + posA[idx];
  rowlist[p] = idx >> 2;
  wlist[p] = twA[idx];
}

// ============================================================================
extern "C" void kernel_launch(void* const* d_in, const int* in_sizes, int n_in,
                              void* d_out, int out_size, void* d_ws, size_t ws_size,
                              hipStream_t stream) {
  const float* cur_obs  = (const float*)d_in[0];
  const float* hist_seq = (const float*)d_in[1];
  const float* fut_ref  = (const float*)d_in[2];
  const float* noise    = (const float*)d_in[3];
  const float* conv1_w  = (const float*)d_in[4];
  const float* conv1_b  = (const float*)d_in[5];
  const float* conv2_w  = (const float*)d_in[6];
  const float* conv2_b  = (const float*)d_in[7];
  const float* conv3_w  = (const float*)d_in[8];
  const float* conv3_b  = (const float*)d_in[9];
  const float* hlin1_w  = (const float*)d_in[10];
  const float* hlin1_b  = (const float*)d_in[11];
  const float* hlin2_w  = (const float*)d_in[12];
  const float* hlin2_b  = (const float*)d_in[13];
  const float* enc1_w   = (const float*)d_in[14];
  const float* enc1_b   = (const float*)d_in[15];
  const float* enc2_w   = (const float*)d_in[16];
  const float* enc2_b   = (const float*)d_in[17];
  const float* enc3_w   = (const float*)d_in[18];
  const float* enc3_b   = (const float*)d_in[19];
  const float* proj_w   = (const float*)d_in[20];
  const float* proj_b   = (const float*)d_in[21];
  const float* router_w = (const float*)d_in[22];
  const float* router_b = (const float*)d_in[23];
  const float* Wg       = (const float*)d_in[24];
  const float* bg       = (const float*)d_in[25];
  const float* Wu       = (const float*)d_in[26];
  const float* bu       = (const float*)d_in[27];
  const float* Wd       = (const float*)d_in[28];
  const float* bd       = (const float*)d_in[29];
  const float* shg_w    = (const float*)d_in[30];
  const float* shg_b    = (const float*)d_in[31];
  const float* shu_w    = (const float*)d_in[32];
  const float* shu_b    = (const float*)d_in[33];
  const float* shd_w    = (const float*)d_in[34];
  const float* shd_b    = (const float*)d_in[35];
  const float* out1_w   = (const float*)d_in[36];
  const float* out1_b   = (const float*)d_in[37];
  const float* out2_w   = (const float*)d_in[38];
  const float* out2_b   = (const float*)d_in[39];
  const float* head_w   = (const float*)d_in[40];
  const float* head_b   = (const float*)d_in[41];
  (void)in_sizes; (void)n_in; (void)out_size; (void)ws_size;

  char* wsb = (char*)d_ws;
  u16* wt1T  = (u16*)(wsb + WT1T_B);
  u16* wt2T  = (u16*)(wsb + WT2T_B);
  u16* wt3T  = (u16*)(wsb + WT3T_B);
  u16* hl1T  = (u16*)(wsb + HL1T_B);
  u16* frh   = (u16*)(wsb + FRH_B);
  u16* frl   = (u16*)(wsb + FRL_B);
  u16* e1h   = (u16*)(wsb + E1H_B);
  u16* e1l   = (u16*)(wsb + E1L_B);
  u16* y1b   = (u16*)(wsb + Y1_B);
  u16* y2b   = (u16*)(wsb + Y2_B);
  u16* y3b   = (u16*)(wsb + Y3_B);
  u16* wgT   = (u16*)(wsb + WGT_B);
  u16* wuT   = (u16*)(wsb + WUT_B);
  u16* wdT   = (u16*)(wsb + WDT_B);
  float* x   = (float*)(wsb + X_B);
  u16* shgTh = (u16*)(wsb + SHGTH_B);
  u16* shgTl = (u16*)(wsb + SHGTL_B);
  u16* shuTh = (u16*)(wsb + SHUTH_B);
  u16* shuTl = (u16*)(wsb + SHUTL_B);
  u16* shdTh = (u16*)(wsb + SHDTH_B);
  u16* shdTl = (u16*)(wsb + SHDTL_B);
  u16* o1Th  = (u16*)(wsb + O1TH_B);
  u16* o1Tl  = (u16*)(wsb + O1TL_B);
  u16* o2Th  = (u16*)(wsb + O2TH_B);
  u16* o2Tl  = (u16*)(wsb + O2TL_B);
  float* h2  = (float*)(wsb + H2_B);
  u16* h2h   = (u16*)(wsb + H2H_B);
  u16* h2l   = (u16*)(wsb + H2L_B);
  u16* e1Th  = (u16*)(wsb + E1TH_B);
  u16* e1Tl  = (u16*)(wsb + E1TL_B);
  u16* e2Th  = (u16*)(wsb + E2TH_B);
  u16* e2Tl  = (u16*)(wsb + E2TL_B);
  float* e2f = (float*)(wsb + E2F_B);
  u16* hsb   = (u16*)(wsb + HSB_B);
  u16* hb    = (u16*)(wsb + HB_B);
  u16* hi1b  = (u16*)(wsb + HI1_B);
  u16* xh    = (u16*)(wsb + XH_B);
  u16* xl    = (u16*)(wsb + XL_B);
  u16* tmoeb = (u16*)(wsb + TM_B);
  u16* stb   = (u16*)(wsb + STB_B);
  u16* o1h   = (u16*)(wsb + O1H_B);
  u16* o1l   = (u16*)(wsb + O1L_B);
  float* o2f = (float*)(wsb + O2F_B);
  float* hlat = (float*)(wsb + HLAT_B);
  float* e3   = (float*)(wsb + E3P_B);
  float* z    = (float*)(wsb + Z_B);
  float* logitsb = (float*)(wsb + LOG_B);
  int*   tidA  = (int*)(wsb + TID_B);
  float* twA   = (float*)(wsb + TW_B);
  int*   posA  = (int*)(wsb + POS_B);
  int*   counts = (int*)(wsb + CNT_B);
  int*   offs  = (int*)(wsb + OFS_B);
  int*   rowlist = (int*)(wsb + ROWL_B);
  float* wlist = (float*)(wsb + WL_B);
  u16*   zp    = (u16*)(wsb + ZP_B);

  k_zero_i<<<dim3(1), 64, 0, stream>>>(counts, 16);
  k_zero_i<<<dim3(16), 64, 0, stream>>>((int*)zp, 1024);

  // ---- weight prep (prefix + enc pairs) ----
  k_wt_conv<<<dim3(288), 256, 0, stream>>>(conv1_w, wt1T, 96, 256);
  k_wt_conv<<<dim3(1536), 256, 0, stream>>>(conv2_w, wt2T, 256, 512);
  k_wt_conv<<<dim3(6144), 256, 0, stream>>>(conv3_w, wt3T, 512, 1024);
  k_transpose_bf<<<dim3(32, 32), 256, 0, stream>>>(hlin1_w, hl1T, 1024, 1024);
  k_transpose_hilo<<<dim3(32, 80), 256, 0, stream>>>(enc1_w, e1Th, e1Tl, 2560, 1024);
  k_transpose_hilo<<<dim3(32, 32), 256, 0, stream>>>(enc2_w, e2Th, e2Tl, 1024, 1024);

  // ---- VAE encoder (hi/lo pairs) + reparameterize ----
  k_split_x<<<dim3(10240), 256, 0, stream>>>(fut_ref, frh, frl, BATCH * 2560 / 4);
  k_gg<1, 3, 2, 2><<<dim3(256), 256, 0, stream>>>(frh, frl, e1Th, e1Tl, enc1_b,
      nullptr, e1h, e1l, 1024, 2560, 2560, 2560, 8);
  k_gg<1, 0, 2, 2><<<dim3(256), 256, 0, stream>>>(e1h, e1l, e2Th, e2Tl, enc2_b,
      e2f, nullptr, nullptr, 1024, 1024, 1024, 1024, 8);
  k_gemm<0, false, float><<<dim3(64, 2), 256, 0, stream>>>(e2f, enc3_w, enc3_b, e3, 128, 1024);
  k_z<<<dim3(1024), 256, 0, stream>>>(e3, noise, z);

  // ---- history conv encoder (gll im2col) ----
  k_f32_to_bf4<<<dim3(9600), 256, 0, stream>>>(hist_seq, hsb, BATCH * 25 * 96 / 4);
  k_gconv<96, 25, 25, 1><<<dim3(1600), 256, 0, stream>>>(hsb, wt1T, conv1_b, y1b, zp, 256, 2);
  k_gconv<256, 25, 13, 2><<<dim3(1664), 256, 0, stream>>>(y1b, wt2T, conv2_b, y2b, zp, 512, 4);
  k_gconv<512, 13, 7, 2><<<dim3(1792), 256, 0, stream>>>(y2b, wt3T, conv3_b, y3b, zp, 1024, 8);
  k_mean7<<<dim3(16384), 256, 0, stream>>>(y3b, hb);
  k_gg<1, 1, 1, 1><<<dim3(256), 256, 0, stream>>>(hb, nullptr, hl1T, nullptr, hlin1_b,
      nullptr, hi1b, nullptr, 1024, 1024, 1024, 1024, 8);
  k_gemm<0, false, u16><<<dim3(64, 1), 256, 0, stream>>>(hi1b, hlin2_w, hlin2_b, hlat, 64, 1024);

  // ---- expert weight transposes (y3 dead) ----
  k_transpose_bf_b<<<dim3(32, 16, 16), 256, 0, stream>>>(Wg, wgT, 512, 1024);
  k_transpose_bf_b<<<dim3(32, 16, 16), 256, 0, stream>>>(Wu, wuT, 512, 1024);
  k_transpose_bf_b<<<dim3(16, 32, 16), 256, 0, stream>>>(Wd, wdT, 1024, 512);

  // ---- projection (fp32) + router ----
  k_gemm_proj<<<dim3(64, 8), 256, 0, stream>>>(cur_obs, hlat, z, proj_w, proj_b, x);
  k_gemm<0, true, float><<<dim3(64, 1), 256, 0, stream>>>(x, router_w, router_b, logitsb, 16, 512);
  k_router<<<dim3(16), 256, 0, stream>>>(logitsb, tidA, twA, posA, counts);
  k_offsets<<<dim3(1), 64, 0, stream>>>(counts, offs);
  k_build<<<dim3(64), 256, 0, stream>>>(tidA, twA, posA, offs, rowlist, wlist);
  k_split_x<<<dim3(2048), 256, 0, stream>>>(x, xh, xl, BATCH * 512 / 4);

  // ---- MoE up (expert->XCD swizzled) ----
  k_gmoeup<<<dim3(4096), 256, 0, stream>>>(xh, xl, wgT, wuT, bg, bu,
                                           rowlist, counts, offs, zp, tmoeb);

  // ---- sh/out hi/lo weights into dead wg/wu region; zero h2 ----
  k_transpose_hilo<<<dim3(64, 16), 256, 0, stream>>>(shg_w, shgTh, shgTl, 512, 2048);
  k_transpose_hilo<<<dim3(64, 16), 256, 0, stream>>>(shu_w, shuTh, shuTl, 512, 2048);
  k_transpose_hilo<<<dim3(16, 64), 256, 0, stream>>>(shd_w, shdTh, shdTl, 2048, 512);
  k_transpose_hilo<<<dim3(32, 16), 256, 0, stream>>>(out1_w, o1Th, o1Tl, 512, 1024);
  k_transpose_hilo<<<dim3(32, 32), 256, 0, stream>>>(out2_w, o2Th, o2Tl, 1024, 1024);
  k_zero_f4<<<dim3(2048), 256, 0, stream>>>((float4*)h2, BATCH * 512 / 4);

  // ---- MoE down (atomic scatter into h2) ----
  k_gmoedown<<<dim3(2048), 256, 0, stream>>>(tmoeb, wdT, bd, rowlist, wlist,
                                             counts, offs, zp, h2);

  // ---- shared experts (full hi/lo dual), += into h2 ----
  k_gdual<<<dim3(512), 256, 0, stream>>>(xh, xl, shgTh, shgTl, shuTh, shuTl,
                                         shg_b, shu_b, stb, 2048, 512, 512, 512, 16);
  k_gg<0, 2, 1, 2><<<dim3(128), 256, 0, stream>>>(stb, nullptr, shdTh, shdTl, shd_b,
      h2, nullptr, nullptr, 512, 2048, 2048, 2048, 4);

  // ---- output MLP (hi/lo) + head (fp32) ----
  k_split_x<<<dim3(2048), 256, 0, stream>>>(h2, h2h, h2l, BATCH * 512 / 4);
  k_gg<1, 3, 2, 2><<<dim3(256), 256, 0, stream>>>(h2h, h2l, o1Th, o1Tl, out1_b,
      nullptr, o1h, o1l, 1024, 512, 512, 512, 8);
  k_gg<0, 0, 2, 2><<<dim3(256), 256, 0, stream>>>(o1h, o1l, o2Th, o2Tl, out2_b,
      o2f, nullptr, nullptr, 1024, 1024, 1024, 1024, 8);
  k_gemm<0, true, float><<<dim3(64, 1), 256, 0, stream>>>(o2f, head_w, head_b, (float*)d_out, 23, 1024);
}

// Round 9
// 1225.730 us; speedup vs baseline: 4.0403x; 1.0807x over previous
//
#include <hip/hip_runtime.h>
#include <hip/hip_bf16.h>

// ============================================================================
// EstVAEStudent forward, round 9: round 8 + precision-targeted FLOP cuts.
//  - enc1/enc2 keep 3-term hi/lo (router-critical z path).
//  - MoE up: pure bf16 (1-term). Shared dual/down: 1-term.
//  - out1/out2: 2-term (exact-A pair x bf16 W).
//  MFMA FLOPs 430 -> 332 GF. Error budget: +~1e-4 worst case, ~3x margin.
// ============================================================================

#define BATCH 4096
typedef unsigned short u16;
typedef unsigned int u32;
using bf16x8 = __attribute__((ext_vector_type(8))) __bf16;
using f32x4  = __attribute__((ext_vector_type(4))) float;

__device__ __forceinline__ float silu_f(float v) { return v / (1.f + __expf(-v)); }

__device__ __forceinline__ float b2f(u16 u) {
  union { u32 i; float f; } c; c.i = ((u32)u) << 16; return c.f;
}
__device__ __forceinline__ u16 f2b(float f) {
  union { float f; u32 i; } c; c.f = f;
  u32 r = c.i + 0x7FFFu + ((c.i >> 16) & 1u);
  return (u16)(r >> 16);
}
__device__ __forceinline__ float4 ld4(const float* p) { return *(const float4*)p; }
__device__ __forceinline__ float4 ld4(const u16* p) {
  ushort4 v = *(const ushort4*)p;
  return make_float4(b2f(v.x), b2f(v.y), b2f(v.z), b2f(v.w));
}

// global_load_lds, 16B per lane, wave-uniform LDS base (lane l -> base+l*16B).
__device__ __forceinline__ void gll16(const u16* g, u16* l) {
  __attribute__((address_space(3))) u32* lp =
      reinterpret_cast<__attribute__((address_space(3))) u32*>(
          reinterpret_cast<uintptr_t>(l));
  __builtin_amdgcn_global_load_lds(reinterpret_cast<const u32*>(g), lp, 16, 0, 0);
}

union U8 { uint4 u; bf16x8 b; };

// ---------------- workspace layout (BYTE offsets) ----------------
static constexpr size_t WT1T_B = 0;               // 256x288 bf16
static constexpr size_t WT2T_B = 147456;          // 512x768
static constexpr size_t WT3T_B = 933888;          // 1024x1536
static constexpr size_t HL1T_B = 4079616;         // 1024x1024 -> ends 6176768
static constexpr size_t RA_B   = 6176768;         // 58,720,256 B
static constexpr size_t RB_B   = 64897024;        // 54,525,952 B
static constexpr size_t P_B    = 119422976;
// RA phases:
static constexpr size_t FRH_B  = RA_B;                    // fut_ref hi bf16 20,971,520
static constexpr size_t FRL_B  = RA_B + 20971520;
static constexpr size_t E1H_B  = RA_B + 41943040;         // e1 pair bf16 8,388,608 ea
static constexpr size_t E1L_B  = RA_B + 50331648;
static constexpr size_t Y1_B   = RA_B;                    // conv1 out (52,428,800)
static constexpr size_t Y3_B   = RA_B;                    // conv3 out (58,720,256)
static constexpr size_t WGT_B  = RA_B;                    // experts bf16
static constexpr size_t WUT_B  = RA_B + 16777216;
static constexpr size_t WDT_B  = RA_B + 33554432;
static constexpr size_t X_B    = RA_B + 50331648;         // x f32 8,388,608
static constexpr size_t SHGT_B = RA_B;                    // after moe_up (wg/wu dead)
static constexpr size_t SHUT_B = RA_B + 2097152;
static constexpr size_t SHDT_B = RA_B + 4194304;
static constexpr size_t O1T_B  = RA_B + 6291456;
static constexpr size_t O2T_B  = RA_B + 7340032;          // ends RA+9,437,184
static constexpr size_t H2_B   = RA_B + 25165824;         // f32 8,388,608
static constexpr size_t H2H_B  = RA_B + 33554432;         // pair bf16 (wdT dead)
static constexpr size_t H2L_B  = RA_B + 37748736;
// RB phases:
static constexpr size_t E1TH_B = RB_B;                    // enc1 WT pair 5,242,880 ea
static constexpr size_t E1TL_B = RB_B + 5242880;
static constexpr size_t E2TH_B = RB_B + 10485760;         // enc2 WT pair 2,097,152 ea
static constexpr size_t E2TL_B = RB_B + 12582912;
static constexpr size_t E2F_B  = RB_B + 14680064;         // e2 f32 16,777,216
static constexpr size_t HSB_B  = RB_B;                    // hist_seq bf16 19,660,800
static constexpr size_t Y2_B   = RB_B;                    // conv2 out 54,525,952
static constexpr size_t HB_B   = RB_B;                    // hb bf16 8,388,608
static constexpr size_t HI1_B  = RB_B + 8388608;          // hi1b bf16 8,388,608
static constexpr size_t XH_B   = RB_B;                    // x bf16 4,194,304
static constexpr size_t TM_B   = RB_B + 8388608;          // t_moe bf16 33,554,432
static constexpr size_t STB_B  = RB_B + 8388608;          // stb bf16 16,777,216 (tm dead)
static constexpr size_t O1H_B  = RB_B;                    // o1 pair (xh dead)
static constexpr size_t O1L_B  = RB_B + 8388608;
static constexpr size_t O2F_B  = RB_B + 16777216;         // o2 f32 16,777,216
// P smalls:
static constexpr size_t HLAT_B = P_B;
static constexpr size_t E3P_B  = P_B + 1048576;
static constexpr size_t Z_B    = P_B + 3145728;
static constexpr size_t LOG_B  = P_B + 4194304;
static constexpr size_t TID_B  = P_B + 4456448;
static constexpr size_t TW_B   = P_B + 4521984;
static constexpr size_t POS_B  = P_B + 4587520;
static constexpr size_t CNT_B  = P_B + 4653056;
static constexpr size_t OFS_B  = P_B + 4653184;
static constexpr size_t ROWL_B = P_B + 4653312;
static constexpr size_t WL_B   = P_B + 4718848;
static constexpr size_t ZP_B   = P_B + 4784384;           // 4096 B zero page

// XCD-coherent tile decode: nm % 8 == 0 required.
#define TILE_DECODE(nn_)                         \
  const int bid = blockIdx.x;                    \
  const int xcd = bid & 7;                       \
  const int tt_ = bid >> 3;                      \
  const int n0 = (tt_ % (nn_)) * 128;            \
  const int m0 = ((tt_ / (nn_)) * 8 + xcd) * 128;

// ---------------- prep kernels ----------------
__global__ void k_zero_i(int* __restrict__ p, int n) {
  int i = blockIdx.x * 64 + threadIdx.x;
  if (i < n) p[i] = 0;
}
__global__ void k_zero_f4(float4* __restrict__ p, int n4) {
  int i = blockIdx.x * 256 + threadIdx.x;
  if (i < n4) p[i] = make_float4(0.f, 0.f, 0.f, 0.f);
}
__global__ void k_f32_to_bf4(const float* __restrict__ s, u16* __restrict__ d, int n4) {
  int i = blockIdx.x * 256 + threadIdx.x;
  if (i >= n4) return;
  float4 v = *(const float4*)(s + (size_t)i * 4);
  *(ushort4*)(d + (size_t)i * 4) = make_ushort4(f2b(v.x), f2b(v.y), f2b(v.z), f2b(v.w));
}
// f32 -> (hi, lo) bf16 pair
__global__ void k_split_x(const float* __restrict__ s, u16* __restrict__ dh,
                          u16* __restrict__ dl, int n4) {
  int i = blockIdx.x * 256 + threadIdx.x;
  if (i >= n4) return;
  float4 v = *(const float4*)(s + (size_t)i * 4);
  float a[4] = {v.x, v.y, v.z, v.w};
  ushort4 h, l;
  u16* hp = (u16*)&h; u16* lp = (u16*)&l;
#pragma unroll
  for (int j = 0; j < 4; ++j) {
    u16 hh = f2b(a[j]);
    hp[j] = hh;
    lp[j] = f2b(a[j] - b2f(hh));
  }
  *(ushort4*)(dh + (size_t)i * 4) = h;
  *(ushort4*)(dl + (size_t)i * 4) = l;
}
// conv weight: [O][I][3] fp32 -> WT[o][k*CIN+i] bf16
__global__ void k_wt_conv(const float* __restrict__ w, u16* __restrict__ wt,
                          int CIN, int COUT) {
  int idx = blockIdx.x * 256 + threadIdx.x;
  int Kc = CIN * 3;
  if (idx >= COUT * Kc) return;
  int o = idx / Kc, c = idx - o * Kc;
  int k = c / CIN, i = c - k * CIN;
  wt[idx] = f2b(w[(size_t)o * Kc + i * 3 + k]);
}
// dense weight: W[K][N] fp32 -> WT[N][K] bf16
__global__ __launch_bounds__(256) void k_transpose_bf(const float* __restrict__ W,
                                                      u16* __restrict__ WT,
                                                      int K, int N) {
  __shared__ float t[32][33];
  int n0 = blockIdx.x * 32, k0 = blockIdx.y * 32;
  int lx = threadIdx.x & 31, ly = threadIdx.x >> 5;
#pragma unroll
  for (int r = 0; r < 32; r += 8)
    t[ly + r][lx] = W[(size_t)(k0 + ly + r) * N + n0 + lx];
  __syncthreads();
#pragma unroll
  for (int r = 0; r < 32; r += 8)
    WT[(size_t)(n0 + ly + r) * K + k0 + lx] = f2b(t[lx][ly + r]);
}
// batched per-expert transpose
__global__ __launch_bounds__(256) void k_transpose_bf_b(const float* __restrict__ W,
                                                        u16* __restrict__ WT,
                                                        int K, int N) {
  const size_t eo = (size_t)blockIdx.z * K * N;
  __shared__ float t[32][33];
  int n0 = blockIdx.x * 32, k0 = blockIdx.y * 32;
  int lx = threadIdx.x & 31, ly = threadIdx.x >> 5;
#pragma unroll
  for (int r = 0; r < 32; r += 8)
    t[ly + r][lx] = W[eo + (size_t)(k0 + ly + r) * N + n0 + lx];
  __syncthreads();
#pragma unroll
  for (int r = 0; r < 32; r += 8)
    WT[eo + (size_t)(n0 + ly + r) * K + k0 + lx] = f2b(t[lx][ly + r]);
}
// hi/lo split transpose (enc path only)
__global__ __launch_bounds__(256) void k_transpose_hilo(const float* __restrict__ W,
                                                        u16* __restrict__ WTh,
                                                        u16* __restrict__ WTl,
                                                        int K, int N) {
  __shared__ float t[32][33];
  int n0 = blockIdx.x * 32, k0 = blockIdx.y * 32;
  int lx = threadIdx.x & 31, ly = threadIdx.x >> 5;
#pragma unroll
  for (int r = 0; r < 32; r += 8)
    t[ly + r][lx] = W[(size_t)(k0 + ly + r) * N + n0 + lx];
  __syncthreads();
#pragma unroll
  for (int r = 0; r < 32; r += 8) {
    float f = t[lx][ly + r];
    u16 h = f2b(f);
    size_t o = (size_t)(n0 + ly + r) * K + k0 + lx;
    WTh[o] = h;
    WTl[o] = f2b(f - b2f(h));
  }
}

// ============================================================================
// gll GEMM cores: 128x128 tile, BK=32, 4 waves (2x2 of 64x64), 16x16x32 bf16.
// LDS per tensor tile: 4096 u16; wave wid at wid*1024, call i at +i*512.
// Slot swizzle f(r) = (r>>1)&3; f(r+16)=f(r).
// ============================================================================
#define PRO128 \
  const int tid = threadIdx.x; \
  const int lane = tid & 63; \
  const int wid = tid >> 6; \
  const int wr = (wid >> 1) * 64, wc = (wid & 1) * 64; \
  const int l15 = lane & 15, lsub = lane >> 4;

#define MFMA_BF16(a, b, c) __builtin_amdgcn_mfma_f32_16x16x32_bf16(a, b, c, 0, 0, 0)

// generic GEMM: AP/BP = hi/lo parts of A/B (1 or 2); 3-term when 2x2,
// 2-term when 2x1 (exact-A x bf16-W) or 1x2; 1-term when 1x1.
// EPI: 0 f32 store, 1 bf16 store, 2 f32 +=, 3 bf16 pair store.
template<int ACT, int EPI, int AP, int BP>
__global__ __launch_bounds__(256) void k_gg(
    const u16* __restrict__ A0, const u16* __restrict__ A1,
    const u16* __restrict__ B0, const u16* __restrict__ B1,
    const float* __restrict__ bias,
    float* __restrict__ Cf, u16* __restrict__ Ch, u16* __restrict__ Cl,
    int N, int K, int lda, int ldb, int nn) {
  constexpr int NT = AP + BP;
  __shared__ u16 lds[NT * 4096];
  PRO128
  TILE_DECODE(nn)
  const int r0 = wid * 32 + (lane >> 2);
  const int sl = ((lane & 3) ^ ((r0 >> 1) & 3)) * 8;
  const u16* sA0 = A0 + (size_t)(m0 + r0) * lda + sl;
  const u16* sA1 = (AP == 2) ? A1 + (size_t)(m0 + r0) * lda + sl : nullptr;
  const u16* sB0 = B0 + (size_t)(n0 + r0) * ldb + sl;
  const u16* sB1 = (BP == 2) ? B1 + (size_t)(n0 + r0) * ldb + sl : nullptr;
  const size_t stepA = (size_t)16 * lda, stepB = (size_t)16 * ldb;
  const int wb = wid * 1024;

  f32x4 acc[4][4];
  const f32x4 zf = {0.f, 0.f, 0.f, 0.f};
#pragma unroll
  for (int i = 0; i < 4; ++i)
#pragma unroll
    for (int j = 0; j < 4; ++j) acc[i][j] = zf;

  for (int k0 = 0; k0 < K; k0 += 32) {
    {
      int t = 0;
      gll16(sA0 + k0, &lds[t * 4096 + wb]);
      gll16(sA0 + stepA + k0, &lds[t * 4096 + wb + 512]);
      ++t;
      if (AP == 2) {
        gll16(sA1 + k0, &lds[t * 4096 + wb]);
        gll16(sA1 + stepA + k0, &lds[t * 4096 + wb + 512]);
        ++t;
      }
      gll16(sB0 + k0, &lds[t * 4096 + wb]);
      gll16(sB0 + stepB + k0, &lds[t * 4096 + wb + 512]);
      ++t;
      if (BP == 2) {
        gll16(sB1 + k0, &lds[t * 4096 + wb]);
        gll16(sB1 + stepB + k0, &lds[t * 4096 + wb + 512]);
      }
    }
    __syncthreads();
    U8 fah[4], fal[4];
#pragma unroll
    for (int i = 0; i < 4; ++i) {
      int ra = wr + i * 16 + l15;
      int ao = ra * 32 + ((lsub ^ ((ra >> 1) & 3))) * 8;
      fah[i].u = *(const uint4*)&lds[ao];
      if (AP == 2) fal[i].u = *(const uint4*)&lds[4096 + ao];
    }
#pragma unroll
    for (int ni = 0; ni < 4; ++ni) {
      int rb = wc + ni * 16 + l15;
      int bo = AP * 4096 + rb * 32 + ((lsub ^ ((rb >> 1) & 3))) * 8;
      U8 fbh, fbl;
      fbh.u = *(const uint4*)&lds[bo];
      if (BP == 2) fbl.u = *(const uint4*)&lds[4096 + bo];
#pragma unroll
      for (int mi = 0; mi < 4; ++mi) {
        acc[mi][ni] = MFMA_BF16(fah[mi].b, fbh.b, acc[mi][ni]);
        if (BP == 2) acc[mi][ni] = MFMA_BF16(fah[mi].b, fbl.b, acc[mi][ni]);
        if (AP == 2) acc[mi][ni] = MFMA_BF16(fal[mi].b, fbh.b, acc[mi][ni]);
      }
    }
    __syncthreads();
  }
  const int row4 = lsub * 4;
#pragma unroll
  for (int mi = 0; mi < 4; ++mi)
#pragma unroll
    for (int ni = 0; ni < 4; ++ni) {
      int col = n0 + wc + ni * 16 + l15;
      float bv = bias[col];
#pragma unroll
      for (int j = 0; j < 4; ++j) {
        int row = m0 + wr + mi * 16 + row4 + j;
        float v = acc[mi][ni][j] + bv;
        if (ACT) v = silu_f(v);
        if (EPI == 0) Cf[(size_t)row * N + col] = v;
        else if (EPI == 1) Ch[(size_t)row * N + col] = f2b(v);
        else if (EPI == 2) Cf[(size_t)row * N + col] += v;
        else {
          u16 vh = f2b(v);
          Ch[(size_t)row * N + col] = vh;
          Cl[(size_t)row * N + col] = f2b(v - b2f(vh));
        }
      }
    }
}

// shared-expert dual, pure bf16 1-term: C bf16 = silu(A@G+bg)*(A@U+bu)
__global__ __launch_bounds__(256) void k_gdual1(
    const u16* __restrict__ A0, const u16* __restrict__ G0,
    const u16* __restrict__ U0,
    const float* __restrict__ bg, const float* __restrict__ bu,
    u16* __restrict__ C, int N, int K, int lda, int ldb, int nn) {
  __shared__ u16 lds[3 * 4096];
  PRO128
  TILE_DECODE(nn)
  const int r0 = wid * 32 + (lane >> 2);
  const int sl = ((lane & 3) ^ ((r0 >> 1) & 3)) * 8;
  const u16* sA = A0 + (size_t)(m0 + r0) * lda + sl;
  const u16* sG = G0 + (size_t)(n0 + r0) * ldb + sl;
  const u16* sU = U0 + (size_t)(n0 + r0) * ldb + sl;
  const size_t stepA = (size_t)16 * lda, stepB = (size_t)16 * ldb;
  const int wb = wid * 1024;
  f32x4 ag[4][4], au[4][4];
  const f32x4 zf = {0.f, 0.f, 0.f, 0.f};
#pragma unroll
  for (int i = 0; i < 4; ++i)
#pragma unroll
    for (int j = 0; j < 4; ++j) { ag[i][j] = zf; au[i][j] = zf; }

  for (int k0 = 0; k0 < K; k0 += 32) {
    gll16(sA + k0, &lds[wb]);
    gll16(sA + stepA + k0, &lds[wb + 512]);
    gll16(sG + k0, &lds[4096 + wb]);
    gll16(sG + stepB + k0, &lds[4096 + wb + 512]);
    gll16(sU + k0, &lds[2 * 4096 + wb]);
    gll16(sU + stepB + k0, &lds[2 * 4096 + wb + 512]);
    __syncthreads();
    U8 fa[4];
#pragma unroll
    for (int i = 0; i < 4; ++i) {
      int ra = wr + i * 16 + l15;
      fa[i].u = *(const uint4*)&lds[ra * 32 + ((lsub ^ ((ra >> 1) & 3))) * 8];
    }
#pragma unroll
    for (int ni = 0; ni < 4; ++ni) {
      int rb = wc + ni * 16 + l15;
      int bo = rb * 32 + ((lsub ^ ((rb >> 1) & 3))) * 8;
      U8 fg, fu;
      fg.u = *(const uint4*)&lds[4096 + bo];
      fu.u = *(const uint4*)&lds[2 * 4096 + bo];
#pragma unroll
      for (int mi = 0; mi < 4; ++mi) {
        ag[mi][ni] = MFMA_BF16(fa[mi].b, fg.b, ag[mi][ni]);
        au[mi][ni] = MFMA_BF16(fa[mi].b, fu.b, au[mi][ni]);
      }
    }
    __syncthreads();
  }
  const int row4 = lsub * 4;
#pragma unroll
  for (int mi = 0; mi < 4; ++mi)
#pragma unroll
    for (int ni = 0; ni < 4; ++ni) {
      int col = n0 + wc + ni * 16 + l15;
      float bgv = bg[col], buv = bu[col];
#pragma unroll
      for (int j = 0; j < 4; ++j) {
        int row = m0 + wr + mi * 16 + row4 + j;
        float v = silu_f(ag[mi][ni][j] + bgv) * (au[mi][ni][j] + buv);
        C[(size_t)row * N + col] = f2b(v);
      }
    }
}

// conv as implicit-im2col gll GEMM; zero-page for pad/OOB.
template<int CIN, int TIN, int TOUT, int STRIDE>
__global__ __launch_bounds__(256) void k_gconv(
    const u16* __restrict__ X, const u16* __restrict__ WT,
    const float* __restrict__ bias, u16* __restrict__ Y,
    const u16* __restrict__ zp, int COUT, int nn) {
  constexpr int K = CIN * 3;
  __shared__ u16 lds[2 * 4096];
  PRO128
  TILE_DECODE(nn)
  int bA_[2], tb_[2], sl_[2];
  const u16* sB[2];
#pragma unroll
  for (int i = 0; i < 2; ++i) {
    int r = wid * 32 + i * 16 + (lane >> 2);
    int sl = ((lane & 3) ^ ((r >> 1) & 3)) * 8;
    sl_[i] = sl;
    int m = m0 + r;
    int bb = m / TOUT;
    int tt = m - bb * TOUT;
    bA_[i] = bb;
    tb_[i] = tt * STRIDE - 1;
    sB[i] = WT + (size_t)(n0 + r) * K + sl;
  }
  const int wb = wid * 1024;
  f32x4 acc[4][4];
  const f32x4 zf = {0.f, 0.f, 0.f, 0.f};
#pragma unroll
  for (int i = 0; i < 4; ++i)
#pragma unroll
    for (int j = 0; j < 4; ++j) acc[i][j] = zf;

  for (int k0 = 0; k0 < K; k0 += 32) {
#pragma unroll
    for (int i = 0; i < 2; ++i) {
      int kk = k0 + sl_[i];
      int ker = kk / CIN;
      int i0 = kk - ker * CIN;
      int tin = tb_[i] + ker;
      const u16* sa = (tin >= 0 && tin < TIN)
          ? X + ((size_t)bA_[i] * TIN + tin) * CIN + i0 : zp;
      gll16(sa, &lds[wb + i * 512]);
      gll16(sB[i] + k0, &lds[4096 + wb + i * 512]);
    }
    __syncthreads();
    U8 fa[4], fb[4];
#pragma unroll
    for (int i = 0; i < 4; ++i) {
      int ra = wr + i * 16 + l15;
      fa[i].u = *(const uint4*)&lds[ra * 32 + ((lsub ^ ((ra >> 1) & 3))) * 8];
      int rb = wc + i * 16 + l15;
      fb[i].u = *(const uint4*)&lds[4096 + rb * 32 + ((lsub ^ ((rb >> 1) & 3))) * 8];
    }
#pragma unroll
    for (int mi = 0; mi < 4; ++mi)
#pragma unroll
      for (int ni = 0; ni < 4; ++ni)
        acc[mi][ni] = MFMA_BF16(fa[mi].b, fb[ni].b, acc[mi][ni]);
    __syncthreads();
  }
  const int row4 = lsub * 4;
#pragma unroll
  for (int mi = 0; mi < 4; ++mi)
#pragma unroll
    for (int ni = 0; ni < 4; ++ni) {
      int col = n0 + wc + ni * 16 + l15;
      float bv = bias[col];
#pragma unroll
      for (int j = 0; j < 4; ++j) {
        int row = m0 + wr + mi * 16 + row4 + j;
        Y[(size_t)row * COUT + col] = f2b(silu_f(acc[mi][ni][j] + bv));
      }
    }
}

// MoE up: expert->XCD swizzled 1D grid; gathered bf16 x (1-term) dual.
__global__ __launch_bounds__(256) void k_gmoeup(
    const u16* __restrict__ xh,
    const u16* __restrict__ WgT, const u16* __restrict__ WuT,
    const float* __restrict__ bg, const float* __restrict__ bu,
    const int* __restrict__ rowlist, const int* __restrict__ counts,
    const int* __restrict__ offs, const u16* __restrict__ zp,
    u16* __restrict__ t_moe) {
  const int bid = blockIdx.x;
  const int xcd = bid & 7, sidx = bid >> 3;
  const int eo = sidx >> 8, r2 = sidx & 255;
  const int mt = r2 >> 3, nt = r2 & 7;
  const int e = xcd + 8 * eo;
  const int ne = counts[e];
  const int m0 = mt * 128;
  if (m0 >= ne) return;
  const int n0 = nt * 128;
  const int base = offs[e];
  constexpr int K = 512, N = 1024;
  const u16* Wge = WgT + (size_t)e * N * K;
  const u16* Wue = WuT + (size_t)e * N * K;
  const float* bge = bg + (size_t)e * N;
  const float* bue = bu + (size_t)e * N;
  __shared__ u16 lds[3 * 4096];
  PRO128
  const u16* sA[2]; const u16* sG[2]; const u16* sU[2];
#pragma unroll
  for (int i = 0; i < 2; ++i) {
    int r = wid * 32 + i * 16 + (lane >> 2);
    int sl = ((lane & 3) ^ ((r >> 1) & 3)) * 8;
    int grow = m0 + r;
    int xr = (grow < ne) ? rowlist[base + grow] : -1;
    sA[i] = (xr >= 0) ? xh + (size_t)xr * K + sl : zp;
    sG[i] = Wge + (size_t)(n0 + r) * K + sl;
    sU[i] = Wue + (size_t)(n0 + r) * K + sl;
  }
  const int wb = wid * 1024;
  f32x4 ag[4][4], au[4][4];
  const f32x4 zf = {0.f, 0.f, 0.f, 0.f};
#pragma unroll
  for (int i = 0; i < 4; ++i)
#pragma unroll
    for (int j = 0; j < 4; ++j) { ag[i][j] = zf; au[i][j] = zf; }

  for (int k0 = 0; k0 < K; k0 += 32) {
#pragma unroll
    for (int i = 0; i < 2; ++i) {
      gll16(sA[i] + k0, &lds[0 * 4096 + wb + i * 512]);
      gll16(sG[i] + k0, &lds[1 * 4096 + wb + i * 512]);
      gll16(sU[i] + k0, &lds[2 * 4096 + wb + i * 512]);
    }
    __syncthreads();
    U8 fa[4];
#pragma unroll
    for (int i = 0; i < 4; ++i) {
      int ra = wr + i * 16 + l15;
      fa[i].u = *(const uint4*)&lds[ra * 32 + ((lsub ^ ((ra >> 1) & 3))) * 8];
    }
#pragma unroll
    for (int ni = 0; ni < 4; ++ni) {
      int rb = wc + ni * 16 + l15;
      int bo = rb * 32 + ((lsub ^ ((rb >> 1) & 3))) * 8;
      U8 fg, fu;
      fg.u = *(const uint4*)&lds[1 * 4096 + bo];
      fu.u = *(const uint4*)&lds[2 * 4096 + bo];
#pragma unroll
      for (int mi = 0; mi < 4; ++mi) {
        ag[mi][ni] = MFMA_BF16(fa[mi].b, fg.b, ag[mi][ni]);
        au[mi][ni] = MFMA_BF16(fa[mi].b, fu.b, au[mi][ni]);
      }
    }
    __syncthreads();
  }
  const int row4 = lsub * 4;
#pragma unroll
  for (int mi = 0; mi < 4; ++mi)
#pragma unroll
    for (int ni = 0; ni < 4; ++ni) {
      int col = n0 + wc + ni * 16 + l15;
      float bgv = bge[col], buv = bue[col];
#pragma unroll
      for (int j = 0; j < 4; ++j) {
        int row = m0 + wr + mi * 16 + row4 + j;
        if (row >= ne) continue;
        float v = silu_f(ag[mi][ni][j] + bgv) * (au[mi][ni][j] + buv);
        t_moe[(size_t)(base + row) * N + col] = f2b(v);
      }
    }
}

// MoE down: expert->XCD swizzled; t_moe x WdT -> weighted atomic scatter.
__global__ __launch_bounds__(256) void k_gmoedown(
    const u16* __restrict__ t_moe, const u16* __restrict__ WdT,
    const float* __restrict__ bd, const int* __restrict__ rowlist,
    const float* __restrict__ wlist, const int* __restrict__ counts,
    const int* __restrict__ offs, const u16* __restrict__ zp,
    float* __restrict__ h2) {
  const int bid = blockIdx.x;
  const int xcd = bid & 7, sidx = bid >> 3;
  const int eo = sidx >> 7, r2 = sidx & 127;
  const int mt = r2 >> 2, nt = r2 & 3;
  const int e = xcd + 8 * eo;
  const int ne = counts[e];
  const int m0 = mt * 128;
  if (m0 >= ne) return;
  const int n0 = nt * 128;
  const int base = offs[e];
  constexpr int K = 1024, N = 512;
  const u16* Wde = WdT + (size_t)e * N * K;
  const float* bde = bd + (size_t)e * N;
  __shared__ u16 lds[2 * 4096];
  PRO128
  const u16* sA[2]; const u16* sB[2];
#pragma unroll
  for (int i = 0; i < 2; ++i) {
    int r = wid * 32 + i * 16 + (lane >> 2);
    int sl = ((lane & 3) ^ ((r >> 1) & 3)) * 8;
    sA[i] = (m0 + r < ne) ? t_moe + (size_t)(base + m0 + r) * K + sl : zp;
    sB[i] = Wde + (size_t)(n0 + r) * K + sl;
  }
  const int wb = wid * 1024;
  f32x4 acc[4][4];
  const f32x4 zf = {0.f, 0.f, 0.f, 0.f};
#pragma unroll
  for (int i = 0; i < 4; ++i)
#pragma unroll
    for (int j = 0; j < 4; ++j) acc[i][j] = zf;

  for (int k0 = 0; k0 < K; k0 += 32) {
#pragma unroll
    for (int i = 0; i < 2; ++i) {
      gll16(sA[i] + k0, &lds[wb + i * 512]);
      gll16(sB[i] + k0, &lds[4096 + wb + i * 512]);
    }
    __syncthreads();
    U8 fa[4], fb[4];
#pragma unroll
    for (int i = 0; i < 4; ++i) {
      int ra = wr + i * 16 + l15;
      fa[i].u = *(const uint4*)&lds[ra * 32 + ((lsub ^ ((ra >> 1) & 3))) * 8];
      int rb = wc + i * 16 + l15;
      fb[i].u = *(const uint4*)&lds[4096 + rb * 32 + ((lsub ^ ((rb >> 1) & 3))) * 8];
    }
#pragma unroll
    for (int mi = 0; mi < 4; ++mi)
#pragma unroll
      for (int ni = 0; ni < 4; ++ni)
        acc[mi][ni] = MFMA_BF16(fa[mi].b, fb[ni].b, acc[mi][ni]);
    __syncthreads();
  }
  const int row4 = lsub * 4;
#pragma unroll
  for (int mi = 0; mi < 4; ++mi)
#pragma unroll
    for (int j = 0; j < 4; ++j) {
      int row = m0 + wr + mi * 16 + row4 + j;
      if (row >= ne) continue;
      int r = rowlist[base + row];
      float wl = wlist[base + row];
#pragma unroll
      for (int ni = 0; ni < 4; ++ni) {
        int col = n0 + wc + ni * 16 + l15;
        atomicAdd(&h2[(size_t)r * 512 + col], wl * (acc[mi][ni][j] + bde[col]));
      }
    }
}

// ---------------- fp32 64x64 GEMM (hlin2 / enc3 / router / head) ----------------
template<int ACT, bool NG, typename TA>
__global__ __launch_bounds__(256) void k_gemm(const TA* __restrict__ A,
                                              const float* __restrict__ W,
                                              const float* __restrict__ bias,
                                              float* __restrict__ C,
                                              int N, int K) {
  __shared__ float As[16][64];
  __shared__ float Bs[16][64];
  const int tid = threadIdx.x;
  const int m0 = blockIdx.x * 64;
  const int n0 = blockIdx.y * 64;
  const int tr = tid >> 4, tc = tid & 15;
  const int lm = tid >> 2, lk = (tid & 3) * 4;
  const int ln = tid & 63, lkb = (tid >> 6) * 4;
  float acc[4][4] = {};
  for (int k0 = 0; k0 < K; k0 += 16) {
    float4 av = ld4(A + (size_t)(m0 + lm) * K + k0 + lk);
    As[lk + 0][lm] = av.x; As[lk + 1][lm] = av.y;
    As[lk + 2][lm] = av.z; As[lk + 3][lm] = av.w;
#pragma unroll
    for (int s = 0; s < 4; ++s) {
      int kk = lkb + s;
      float v = 0.f;
      if (!NG || (n0 + ln) < N) v = W[(size_t)(k0 + kk) * N + n0 + ln];
      Bs[kk][ln] = v;
    }
    __syncthreads();
#pragma unroll
    for (int kk = 0; kk < 16; ++kk) {
      float4 a4 = *(const float4*)&As[kk][tr * 4];
      float4 b4 = *(const float4*)&Bs[kk][tc * 4];
      float a[4] = {a4.x, a4.y, a4.z, a4.w};
      float b[4] = {b4.x, b4.y, b4.z, b4.w};
#pragma unroll
      for (int i = 0; i < 4; ++i)
#pragma unroll
        for (int j = 0; j < 4; ++j) acc[i][j] = fmaf(a[i], b[j], acc[i][j]);
    }
    __syncthreads();
  }
#pragma unroll
  for (int i = 0; i < 4; ++i) {
    int m = m0 + tr * 4 + i;
#pragma unroll
    for (int j = 0; j < 4; ++j) {
      int n = n0 + tc * 4 + j;
      if (NG && n >= N) continue;
      float v = acc[i][j] + bias[n];
      if (ACT == 1) v = silu_f(v);
      C[(size_t)m * N + n] = v;
    }
  }
}

// concat projection GEMM (fp32, routing-safe)
__global__ __launch_bounds__(256) void k_gemm_proj(const float* __restrict__ obs,
                                                   const float* __restrict__ hl,
                                                   const float* __restrict__ z,
                                                   const float* __restrict__ W,
                                                   const float* __restrict__ bias,
                                                   float* __restrict__ C) {
  const int N = 512, K = 384;
  __shared__ float As[16][64];
  __shared__ float Bs[16][64];
  const int tid = threadIdx.x;
  const int m0 = blockIdx.x * 64;
  const int n0 = blockIdx.y * 64;
  const int tr = tid >> 4, tc = tid & 15;
  const int lm = tid >> 2, lk = (tid & 3) * 4;
  const int ln = tid & 63, lkb = (tid >> 6) * 4;
  const int m = m0 + lm;
  float acc[4][4] = {};
  for (int k0 = 0; k0 < K; k0 += 16) {
#pragma unroll
    for (int j = 0; j < 4; ++j) {
      int c = k0 + lk + j;
      float v;
      if (c < 256)      v = obs[(size_t)m * 256 + c];
      else if (c < 320) v = hl[(size_t)m * 64 + (c - 256)];
      else              v = z[(size_t)m * 64 + (c - 320)];
      As[lk + j][lm] = v;
    }
#pragma unroll
    for (int s = 0; s < 4; ++s) {
      int kk = lkb + s;
      Bs[kk][ln] = W[(size_t)(k0 + kk) * N + n0 + ln];
    }
    __syncthreads();
#pragma unroll
    for (int kk = 0; kk < 16; ++kk) {
      float4 a4 = *(const float4*)&As[kk][tr * 4];
      float4 b4 = *(const float4*)&Bs[kk][tc * 4];
      float a[4] = {a4.x, a4.y, a4.z, a4.w};
      float b[4] = {b4.x, b4.y, b4.z, b4.w};
#pragma unroll
      for (int i = 0; i < 4; ++i)
#pragma unroll
        for (int j = 0; j < 4; ++j) acc[i][j] = fmaf(a[i], b[j], acc[i][j]);
    }
    __syncthreads();
  }
#pragma unroll
  for (int i = 0; i < 4; ++i) {
    int mo = m0 + tr * 4 + i;
#pragma unroll
    for (int j = 0; j < 4; ++j) {
      int n = n0 + tc * 4 + j;
      C[(size_t)mo * N + n] = acc[i][j] + bias[n];
    }
  }
}

// ---------------- small elementwise / router kernels ----------------
__global__ void k_mean7(const u16* __restrict__ y3, u16* __restrict__ hb) {
  int idx = blockIdx.x * 256 + threadIdx.x;
  if (idx >= BATCH * 1024) return;
  int b = idx >> 10, o = idx & 1023;
  const u16* p = y3 + (size_t)b * 7 * 1024 + o;
  float s = 0.f;
#pragma unroll
  for (int t = 0; t < 7; ++t) s += b2f(p[(size_t)t * 1024]);
  hb[idx] = f2b(s * (1.f / 7.f));
}

__global__ void k_z(const float* __restrict__ e3, const float* __restrict__ noise,
                    float* __restrict__ z) {
  int idx = blockIdx.x * 256 + threadIdx.x;
  if (idx >= BATCH * 64) return;
  int b = idx >> 6, j = idx & 63;
  float mu = e3[(size_t)b * 128 + j];
  float lv = e3[(size_t)b * 128 + 64 + j];
  z[idx] = mu + expf(0.5f * lv) * noise[idx];
}

__global__ void k_router(const float* __restrict__ logits, int* __restrict__ tidA,
                         float* __restrict__ twA, int* __restrict__ posA,
                         int* __restrict__ counts) {
  int b = blockIdx.x * 256 + threadIdx.x;
  if (b >= BATCH) return;
  float s[16];
#pragma unroll
  for (int e = 0; e < 16; ++e)
    s[e] = 1.f / (1.f + expf(-logits[(size_t)b * 16 + e]));
  float gsc[4];
#pragma unroll
  for (int g = 0; g < 4; ++g) {
    float m1 = -1e30f; int i1 = -1;
    for (int i = 0; i < 4; ++i) { float v = s[g * 4 + i]; if (v > m1) { m1 = v; i1 = i; } }
    float m2 = -1e30f;
    for (int i = 0; i < 4; ++i) { if (i == i1) continue; float v = s[g * 4 + i]; if (v > m2) m2 = v; }
    gsc[g] = m1 + m2;
  }
  int g1 = 0; float b1 = gsc[0];
  for (int g = 1; g < 4; ++g) if (gsc[g] > b1) { b1 = gsc[g]; g1 = g; }
  int g2 = -1; float b2 = -1e30f;
  for (int g = 0; g < 4; ++g) { if (g == g1) continue; if (gsc[g] > b2) { b2 = gsc[g]; g2 = g; } }
  float ms[16]; bool used[16];
#pragma unroll
  for (int e = 0; e < 16; ++e) {
    int g = e >> 2;
    ms[e] = (g == g1 || g == g2) ? s[e] : 0.f;
    used[e] = false;
  }
  int te[4]; float tv[4]; float tsum = 0.f;
  for (int t = 0; t < 4; ++t) {
    float best = -1.f; int bi = 0;
    for (int e = 0; e < 16; ++e)
      if (!used[e] && ms[e] > best) { best = ms[e]; bi = e; }
    used[bi] = true;
    te[t] = bi;
    tv[t] = s[bi];
    tsum += s[bi];
  }
  float inv = 1.f / (tsum + 1e-20f);
  for (int t = 0; t < 4; ++t) {
    int e = te[t];
    tidA[b * 4 + t] = e;
    twA[b * 4 + t] = tv[t] * inv;  // ROUTE_SCALE = 1.0
    posA[b * 4 + t] = atomicAdd(&counts[e], 1);
  }
}

__global__ void k_offsets(const int* __restrict__ counts, int* __restrict__ offs) {
  if (threadIdx.x == 0 && blockIdx.x == 0) {
    int a = 0;
    for (int e = 0; e < 16; ++e) { offs[e] = a; a += counts[e]; }
    offs[16] = a;
  }
}

__global__ void k_build(const int* __restrict__ tidA, const float* __restrict__ twA,
                        const int* __restrict__ posA, const int* __restrict__ offs,
                        int* __restrict__ rowlist, float* __restrict__ wlist) {
  int idx = blockIdx.x * 256 + threadIdx.x;
  if (idx >= BATCH * 4) return;
  int e = tidA[idx];
  int p = offs[e] + posA[idx];
  rowlist[p] = idx >> 2;
  wlist[p] = twA[idx];
}

// ============================================================================
extern "C" void kernel_launch(void* const* d_in, const int* in_sizes, int n_in,
                              void* d_out, int out_size, void* d_ws, size_t ws_size,
                              hipStream_t stream) {
  const float* cur_obs  = (const float*)d_in[0];
  const float* hist_seq = (const float*)d_in[1];
  const float* fut_ref  = (const float*)d_in[2];
  const float* noise    = (const float*)d_in[3];
  const float* conv1_w  = (const float*)d_in[4];
  const float* conv1_b  = (const float*)d_in[5];
  const float* conv2_w  = (const float*)d_in[6];
  const float* conv2_b  = (const float*)d_in[7];
  const float* conv3_w  = (const float*)d_in[8];
  const float* conv3_b  = (const float*)d_in[9];
  const float* hlin1_w  = (const float*)d_in[10];
  const float* hlin1_b  = (const float*)d_in[11];
  const float* hlin2_w  = (const float*)d_in[12];
  const float* hlin2_b  = (const float*)d_in[13];
  const float* enc1_w   = (const float*)d_in[14];
  const float* enc1_b   = (const float*)d_in[15];
  const float* enc2_w   = (const float*)d_in[16];
  const float* enc2_b   = (const float*)d_in[17];
  const float* enc3_w   = (const float*)d_in[18];
  const float* enc3_b   = (const float*)d_in[19];
  const float* proj_w   = (const float*)d_in[20];
  const float* proj_b   = (const float*)d_in[21];
  const float* router_w = (const float*)d_in[22];
  const float* router_b = (const float*)d_in[23];
  const float* Wg       = (const float*)d_in[24];
  const float* bg       = (const float*)d_in[25];
  const float* Wu       = (const float*)d_in[26];
  const float* bu       = (const float*)d_in[27];
  const float* Wd       = (const float*)d_in[28];
  const float* bd       = (const float*)d_in[29];
  const float* shg_w    = (const float*)d_in[30];
  const float* shg_b    = (const float*)d_in[31];
  const float* shu_w    = (const float*)d_in[32];
  const float* shu_b    = (const float*)d_in[33];
  const float* shd_w    = (const float*)d_in[34];
  const float* shd_b    = (const float*)d_in[35];
  const float* out1_w   = (const float*)d_in[36];
  const float* out1_b   = (const float*)d_in[37];
  const float* out2_w   = (const float*)d_in[38];
  const float* out2_b   = (const float*)d_in[39];
  const float* head_w   = (const float*)d_in[40];
  const float* head_b   = (const float*)d_in[41];
  (void)in_sizes; (void)n_in; (void)out_size; (void)ws_size;

  char* wsb = (char*)d_ws;
  u16* wt1T  = (u16*)(wsb + WT1T_B);
  u16* wt2T  = (u16*)(wsb + WT2T_B);
  u16* wt3T  = (u16*)(wsb + WT3T_B);
  u16* hl1T  = (u16*)(wsb + HL1T_B);
  u16* frh   = (u16*)(wsb + FRH_B);
  u16* frl   = (u16*)(wsb + FRL_B);
  u16* e1h   = (u16*)(wsb + E1H_B);
  u16* e1l   = (u16*)(wsb + E1L_B);
  u16* y1b   = (u16*)(wsb + Y1_B);
  u16* y2b   = (u16*)(wsb + Y2_B);
  u16* y3b   = (u16*)(wsb + Y3_B);
  u16* wgT   = (u16*)(wsb + WGT_B);
  u16* wuT   = (u16*)(wsb + WUT_B);
  u16* wdT   = (u16*)(wsb + WDT_B);
  float* x   = (float*)(wsb + X_B);
  u16* shgT  = (u16*)(wsb + SHGT_B);
  u16* shuT  = (u16*)(wsb + SHUT_B);
  u16* shdT  = (u16*)(wsb + SHDT_B);
  u16* o1T   = (u16*)(wsb + O1T_B);
  u16* o2T   = (u16*)(wsb + O2T_B);
  float* h2  = (float*)(wsb + H2_B);
  u16* h2h   = (u16*)(wsb + H2H_B);
  u16* h2l   = (u16*)(wsb + H2L_B);
  u16* e1Th  = (u16*)(wsb + E1TH_B);
  u16* e1Tl  = (u16*)(wsb + E1TL_B);
  u16* e2Th  = (u16*)(wsb + E2TH_B);
  u16* e2Tl  = (u16*)(wsb + E2TL_B);
  float* e2f = (float*)(wsb + E2F_B);
  u16* hsb   = (u16*)(wsb + HSB_B);
  u16* hb    = (u16*)(wsb + HB_B);
  u16* hi1b  = (u16*)(wsb + HI1_B);
  u16* xh    = (u16*)(wsb + XH_B);
  u16* tmoeb = (u16*)(wsb + TM_B);
  u16* stb   = (u16*)(wsb + STB_B);
  u16* o1h   = (u16*)(wsb + O1H_B);
  u16* o1l   = (u16*)(wsb + O1L_B);
  float* o2f = (float*)(wsb + O2F_B);
  float* hlat = (float*)(wsb + HLAT_B);
  float* e3   = (float*)(wsb + E3P_B);
  float* z    = (float*)(wsb + Z_B);
  float* logitsb = (float*)(wsb + LOG_B);
  int*   tidA  = (int*)(wsb + TID_B);
  float* twA   = (float*)(wsb + TW_B);
  int*   posA  = (int*)(wsb + POS_B);
  int*   counts = (int*)(wsb + CNT_B);
  int*   offs  = (int*)(wsb + OFS_B);
  int*   rowlist = (int*)(wsb + ROWL_B);
  float* wlist = (float*)(wsb + WL_B);
  u16*   zp    = (u16*)(wsb + ZP_B);

  k_zero_i<<<dim3(1), 64, 0, stream>>>(counts, 16);
  k_zero_i<<<dim3(16), 64, 0, stream>>>((int*)zp, 1024);

  // ---- weight prep (prefix + enc pairs) ----
  k_wt_conv<<<dim3(288), 256, 0, stream>>>(conv1_w, wt1T, 96, 256);
  k_wt_conv<<<dim3(1536), 256, 0, stream>>>(conv2_w, wt2T, 256, 512);
  k_wt_conv<<<dim3(6144), 256, 0, stream>>>(conv3_w, wt3T, 512, 1024);
  k_transpose_bf<<<dim3(32, 32), 256, 0, stream>>>(hlin1_w, hl1T, 1024, 1024);
  k_transpose_hilo<<<dim3(32, 80), 256, 0, stream>>>(enc1_w, e1Th, e1Tl, 2560, 1024);
  k_transpose_hilo<<<dim3(32, 32), 256, 0, stream>>>(enc2_w, e2Th, e2Tl, 1024, 1024);

  // ---- VAE encoder (hi/lo 3-term) + reparameterize ----
  k_split_x<<<dim3(10240), 256, 0, stream>>>(fut_ref, frh, frl, BATCH * 2560 / 4);
  k_gg<1, 3, 2, 2><<<dim3(256), 256, 0, stream>>>(frh, frl, e1Th, e1Tl, enc1_b,
      nullptr, e1h, e1l, 1024, 2560, 2560, 2560, 8);
  k_gg<1, 0, 2, 2><<<dim3(256), 256, 0, stream>>>(e1h, e1l, e2Th, e2Tl, enc2_b,
      e2f, nullptr, nullptr, 1024, 1024, 1024, 1024, 8);
  k_gemm<0, false, float><<<dim3(64, 2), 256, 0, stream>>>(e2f, enc3_w, enc3_b, e3, 128, 1024);
  k_z<<<dim3(1024), 256, 0, stream>>>(e3, noise, z);

  // ---- history conv encoder (gll im2col) ----
  k_f32_to_bf4<<<dim3(9600), 256, 0, stream>>>(hist_seq, hsb, BATCH * 25 * 96 / 4);
  k_gconv<96, 25, 25, 1><<<dim3(1600), 256, 0, stream>>>(hsb, wt1T, conv1_b, y1b, zp, 256, 2);
  k_gconv<256, 25, 13, 2><<<dim3(1664), 256, 0, stream>>>(y1b, wt2T, conv2_b, y2b, zp, 512, 4);
  k_gconv<512, 13, 7, 2><<<dim3(1792), 256, 0, stream>>>(y2b, wt3T, conv3_b, y3b, zp, 1024, 8);
  k_mean7<<<dim3(16384), 256, 0, stream>>>(y3b, hb);
  k_gg<1, 1, 1, 1><<<dim3(256), 256, 0, stream>>>(hb, nullptr, hl1T, nullptr, hlin1_b,
      nullptr, hi1b, nullptr, 1024, 1024, 1024, 1024, 8);
  k_gemm<0, false, u16><<<dim3(64, 1), 256, 0, stream>>>(hi1b, hlin2_w, hlin2_b, hlat, 64, 1024);

  // ---- expert weight transposes (y3 dead) ----
  k_transpose_bf_b<<<dim3(32, 16, 16), 256, 0, stream>>>(Wg, wgT, 512, 1024);
  k_transpose_bf_b<<<dim3(32, 16, 16), 256, 0, stream>>>(Wu, wuT, 512, 1024);
  k_transpose_bf_b<<<dim3(16, 32, 16), 256, 0, stream>>>(Wd, wdT, 1024, 512);

  // ---- projection (fp32) + router ----
  k_gemm_proj<<<dim3(64, 8), 256, 0, stream>>>(cur_obs, hlat, z, proj_w, proj_b, x);
  k_gemm<0, true, float><<<dim3(64, 1), 256, 0, stream>>>(x, router_w, router_b, logitsb, 16, 512);
  k_router<<<dim3(16), 256, 0, stream>>>(logitsb, tidA, twA, posA, counts);
  k_offsets<<<dim3(1), 64, 0, stream>>>(counts, offs);
  k_build<<<dim3(64), 256, 0, stream>>>(tidA, twA, posA, offs, rowlist, wlist);
  k_f32_to_bf4<<<dim3(2048), 256, 0, stream>>>(x, xh, BATCH * 512 / 4);

  // ---- MoE up (expert->XCD swizzled, pure bf16) ----
  k_gmoeup<<<dim3(4096), 256, 0, stream>>>(xh, wgT, wuT, bg, bu,
                                           rowlist, counts, offs, zp, tmoeb);

  // ---- sh/out bf16 weights into dead wg/wu region; zero h2 ----
  k_transpose_bf<<<dim3(64, 16), 256, 0, stream>>>(shg_w, shgT, 512, 2048);
  k_transpose_bf<<<dim3(64, 16), 256, 0, stream>>>(shu_w, shuT, 512, 2048);
  k_transpose_bf<<<dim3(16, 64), 256, 0, stream>>>(shd_w, shdT, 2048, 512);
  k_transpose_bf<<<dim3(32, 16), 256, 0, stream>>>(out1_w, o1T, 512, 1024);
  k_transpose_bf<<<dim3(32, 32), 256, 0, stream>>>(out2_w, o2T, 1024, 1024);
  k_zero_f4<<<dim3(2048), 256, 0, stream>>>((float4*)h2, BATCH * 512 / 4);

  // ---- MoE down (atomic scatter into h2) ----
  k_gmoedown<<<dim3(2048), 256, 0, stream>>>(tmoeb, wdT, bd, rowlist, wlist,
                                             counts, offs, zp, h2);

  // ---- shared experts (1-term dual), += into h2 (1-term down) ----
  k_gdual1<<<dim3(512), 256, 0, stream>>>(xh, shgT, shuT, shg_b, shu_b,
                                          stb, 2048, 512, 512, 512, 16);
  k_gg<0, 2, 1, 1><<<dim3(128), 256, 0, stream>>>(stb, nullptr, shdT, nullptr, shd_b,
      h2, nullptr, nullptr, 512, 2048, 2048, 2048, 4);

  // ---- output MLP (2-term: exact-A pair x bf16 W) + head (fp32) ----
  k_split_x<<<dim3(2048), 256, 0, stream>>>(h2, h2h, h2l, BATCH * 512 / 4);
  k_gg<1, 3, 2, 1><<<dim3(256), 256, 0, stream>>>(h2h, h2l, o1T, nullptr, out1_b,
      nullptr, o1h, o1l, 1024, 512, 512, 512, 8);
  k_gg<0, 0, 2, 1><<<dim3(256), 256, 0, stream>>>(o1h, o1l, o2T, nullptr, out2_b,
      o2f, nullptr, nullptr, 1024, 1024, 1024, 1024, 8);
  k_gemm<0, true, float><<<dim3(64, 1), 256, 0, stream>>>(o2f, head_w, head_b, (float*)d_out, 23, 1024);
}